// Round 7
// baseline (1374.370 us; speedup 1.0000x reference)
//
#include <hip/hip_runtime.h>
#include <hip/hip_bf16.h>
#include <math.h>

typedef unsigned short u16;
typedef unsigned int u32;
typedef __attribute__((ext_vector_type(8))) short bf16x8;
typedef __attribute__((ext_vector_type(4))) float f32x4;

#define DEV __device__ __forceinline__

DEV float gelu_f(float x) { return 0.5f * x * (1.0f + erff(x * 0.70710678118654752f)); }
DEV u16 f2bf(float f) { u32 u = __builtin_bit_cast(u32, f); u = (u + 0x7FFFu + ((u >> 16) & 1u)) >> 16; return (u16)u; }
DEV float bf2f(u16 h) { return __builtin_bit_cast(float, (u32)h << 16); }
DEV u32 fbits(float f) { return __builtin_bit_cast(u32, f); }
DEV float ubits(u32 u) { return __builtin_bit_cast(float, u); }
// packed format: p = hi_u16 | (lo_u16 << 16), v ~= bf(hi) + bf(lo), trunc split (2^-16)
DEV u32 psplit(float v) {
  u32 u = fbits(v);
  float lo = v - ubits(u & 0xFFFF0000u);
  return (u >> 16) | (fbits(lo) & 0xFFFF0000u);
}
DEV float punp(u32 p) { return ubits(p << 16) + ubits(p & 0xFFFF0000u); }
// 3-term split product: a*b ~= ah*bh + ah*bl + al*bh
DEV f32x4 mfma3(bf16x8 ah, bf16x8 al, bf16x8 bh, bf16x8 bl, f32x4 c) {
  c = __builtin_amdgcn_mfma_f32_16x16x32_bf16(al, bh, c, 0, 0, 0);
  c = __builtin_amdgcn_mfma_f32_16x16x32_bf16(ah, bl, c, 0, 0, 0);
  c = __builtin_amdgcn_mfma_f32_16x16x32_bf16(ah, bh, c, 0, 0, 0);
  return c;
}

// ---------------- zero stats ----------------
__global__ void k_zero(float* p, int n) {
  int i = blockIdx.x * blockDim.x + threadIdx.x;
  if (i < n) p[i] = 0.f;
}

// ---------------- conv weight frag preps: layout [((oct*NS + s)*64 + lane)*8 + j] ----------------
__global__ void k_wprep1(const float* __restrict__ w, u16* __restrict__ wh, u16* __restrict__ wl) {
  int idx = blockIdx.x * 256 + threadIdx.x; if (idx >= 8192) return;
  int j = idx & 7, lane = (idx >> 3) & 63, s = (idx >> 9) & 7, oct = idx >> 12;
  int oc = oct * 16 + (lane & 15);
  int kl = ((lane >> 4) << 3) + j;
  int kw = kl >> 2, c = kl & 3, kh = s;
  float v = w[((oc * 4 + c) * 8 + kh) * 8 + kw];
  u16 h = f2bf(v); wh[idx] = h; wl[idx] = f2bf(v - bf2f(h));
}
__global__ void k_wprep2(const float* __restrict__ w, u16* __restrict__ wh, u16* __restrict__ wl) {
  int idx = blockIdx.x * 256 + threadIdx.x; if (idx >= 32768) return;
  int j = idx & 7, lane = (idx >> 3) & 63, s = (idx >> 9) & 15, oct = idx >> 13;
  int oc = oct * 16 + (lane & 15);
  int k = s * 32 + ((lane >> 4) << 3) + j;
  int kh = k >> 7, kw = (k >> 5) & 3, c = k & 31;
  float v = w[((oc * 32 + c) * 4 + kh) * 4 + kw];
  u16 h = f2bf(v); wh[idx] = h; wl[idx] = f2bf(v - bf2f(h));
}
__global__ void k_wprep3(const float* __restrict__ w, u16* __restrict__ wh, u16* __restrict__ wl) {
  int idx = blockIdx.x * 256 + threadIdx.x; if (idx >= 73728) return;
  int j = idx & 7, lane = (idx >> 3) & 63, rest = idx >> 9;
  int s = rest % 18, oct = rest / 18;
  int oc = oct * 16 + (lane & 15);
  int k = s * 32 + ((lane >> 4) << 3) + j;
  int kh = k / 192, r = k - kh * 192;
  int kw = r >> 6, c = r & 63;
  float v = w[((oc * 64 + c) * 3 + kh) * 3 + kw];
  u16 h = f2bf(v); wh[idx] = h; wl[idx] = f2bf(v - bf2f(h));
}
// proj weight prep, LDS-transpose tiled
__global__ __launch_bounds__(256) void k_wprepP(const float* __restrict__ w,
    u16* __restrict__ wh, u16* __restrict__ wl)
{
  __shared__ float tile[16][4][225];
  int q = blockIdx.x, oct = blockIdx.y, tid = threadIdx.x;
  for (int i = tid; i < 3584; i += 256) {
    int n = i / 224, rem = i % 224, e = rem / 56, f4 = rem % 56;
    float4 v = *(const float4*)(w + (long)(oct * 16 + n) * 28672 + (4 * q + e) * 224 + f4 * 4);
    tile[n][e][f4 * 4 + 0] = v.x; tile[n][e][f4 * 4 + 1] = v.y;
    tile[n][e][f4 * 4 + 2] = v.z; tile[n][e][f4 * 4 + 3] = v.w;
  }
  __syncthreads();
  int g = (q >> 1) & 3, j0 = 4 * (q & 1), sgb = q >> 3;
  for (int o = tid; o < 3584; o += 256) {
    int pix = o >> 4, ln = o & 15;
    u16 hs[4], ls[4];
#pragma unroll
    for (int e = 0; e < 4; ++e) {
      float v = tile[ln][e][pix];
      u16 h = f2bf(v); hs[e] = h; ls[e] = f2bf(v - bf2f(h));
    }
    long base = (((long)oct * 896 + pix * 4 + sgb) * 64 + g * 16 + ln) * 8 + j0;
    *(uint2*)(wh + base) = make_uint2((u32)hs[0] | ((u32)hs[1] << 16), (u32)hs[2] | ((u32)hs[3] << 16));
    *(uint2*)(wl + base) = make_uint2((u32)ls[0] | ((u32)ls[1] << 16), (u32)ls[2] | ((u32)ls[3] << 16));
  }
}
// generic plain-bf16 frag prep for expert/shared weights W[Z][N][K]
__global__ void k_wprepG(const float* __restrict__ w, u16* __restrict__ wf,
                         int N, int K, long total)
{
  long idx = (long)blockIdx.x * 256 + threadIdx.x; if (idx >= total) return;
  int j = (int)(idx & 7); int lane = (int)((idx >> 3) & 63); long rest = idx >> 9;
  int kn = K >> 5;
  int s = (int)(rest % kn); long rest2 = rest / kn;
  int noct = N >> 4;
  int oct = (int)(rest2 % noct); int z = (int)(rest2 / noct);
  int n = oct * 16 + (lane & 15);
  int k = s * 32 + ((lane >> 4) << 3) + j;
  wf[idx] = f2bf(w[((long)z * N + n) * K + k]);
}

// ---------------- conv1 MFMA: x[1024,4,144,160] s4 8x8 -> y1p[1024][1365][32] packed
__global__ __launch_bounds__(256, 5) void k_conv1m(const float* __restrict__ x,
    const u16* __restrict__ wfh, const u16* __restrict__ wfl,
    const float* __restrict__ bias, u32* __restrict__ y1p)
{
  __shared__ __align__(16) u16 sin0[7680], sin1[7680];   // [12 rows][160 cols][4 c]
  int ohp = blockIdx.x, b = blockIdx.y, tid = threadIdx.x;
  int row0 = ohp * 8;
  for (int i = tid; i < 960; i += 256) {
    int cp = i / 480, rem = i - cp * 480, r = rem / 40, q = rem - r * 40;
    int grow = row0 + r;
    float4 v0 = make_float4(0.f, 0.f, 0.f, 0.f), v1 = v0;
    if (grow < 144) {
      long base = ((long)b * 4 + 2 * cp) * 23040 + (long)grow * 160 + q * 4;
      v0 = *(const float4*)(x + base);
      v1 = *(const float4*)(x + base + 23040);
    }
    const float* a0 = (const float*)&v0;
    const float* a1 = (const float*)&v1;
#pragma unroll
    for (int m = 0; m < 4; ++m) {
      float f0 = a0[m], f1 = a1[m];
      u32 u0 = fbits(f0), u1 = fbits(f1);
      u32 hh = (u0 >> 16) | (u1 & 0xFFFF0000u);
      float l0 = f0 - ubits(u0 & 0xFFFF0000u);
      float l1 = f1 - ubits(u1 & 0xFFFF0000u);
      u32 ll = (fbits(l0) >> 16) | (fbits(l1) & 0xFFFF0000u);
      int col = q * 4 + m;
      ((u32*)sin0)[r * 320 + col * 2 + cp] = hh;
      ((u32*)sin1)[r * 320 + col * 2 + cp] = ll;
    }
  }
  __syncthreads();
  int w = tid >> 6, lane = tid & 63, g = lane >> 4, ln = lane & 15;
  int ohls[2], owcs[2];
  {
    int j0 = w;          ohls[0] = j0 / 3; owcs[0] = (j0 % 3) * 16 + ln; if (owcs[0] > 38) owcs[0] = 38;
    int j1 = w + 4;      int oh1 = j1 / 3, ow1 = (j1 % 3) * 16 + ln; if (ow1 > 38) ow1 = 38;
    ohls[1] = (j1 < 6) ? oh1 : 0; owcs[1] = (j1 < 6) ? ow1 : 0;
  }
  f32x4 z4 = {0.f, 0.f, 0.f, 0.f};
  f32x4 acc[2][2];
  acc[0][0] = z4; acc[0][1] = z4; acc[1][0] = z4; acc[1][1] = z4;
#pragma unroll
  for (int kh = 0; kh < 8; ++kh) {
    bf16x8 bh0 = *(const bf16x8*)&wfh[kh * 512 + lane * 8];
    bf16x8 bl0 = *(const bf16x8*)&wfl[kh * 512 + lane * 8];
    bf16x8 bh1 = *(const bf16x8*)&wfh[4096 + kh * 512 + lane * 8];
    bf16x8 bl1 = *(const bf16x8*)&wfl[4096 + kh * 512 + lane * 8];
#pragma unroll
    for (int jj = 0; jj < 2; ++jj) {
      if (jj == 1 && w >= 2) continue;
      int off = (4 * ohls[jj] + kh) * 640 + owcs[jj] * 16 + g * 8;
      bf16x8 ah = *(const bf16x8*)&sin0[off];
      bf16x8 al = *(const bf16x8*)&sin1[off];
      acc[jj][0] = mfma3(ah, al, bh0, bl0, acc[jj][0]);
      acc[jj][1] = mfma3(ah, al, bh1, bl1, acc[jj][1]);
    }
  }
#pragma unroll
  for (int jj = 0; jj < 2; ++jj) {
    if (jj == 1 && w >= 2) continue;
    int j = w + jj * 4;
    int ohl = j / 3, owt = j % 3;
    int oh = 2 * ohp + ohl;
    if (oh >= 35) continue;
#pragma unroll
    for (int oct = 0; oct < 2; ++oct) {
      int oc = oct * 16 + ln;
      float bv = bias[oc];
#pragma unroll
      for (int r = 0; r < 4; ++r) {
        int owo = owt * 16 + g * 4 + r;
        if (owo < 39) {
          long oi = ((long)b * 1365 + oh * 39 + owo) * 32 + oc;
          y1p[oi] = psplit(acc[jj][oct][r] + bv);
        }
      }
    }
  }
}

// ---------------- conv2 MFMA (fused BN1+GELU on staging): y1p -> y2p[1024][288][64]
// LDS XOR-swizzled: byte ^= ((colpair&7)<<4), colpair = colpix>>1 (64B cols paired to 128B)
__global__ __launch_bounds__(256, 3) void k_conv2m(const u32* __restrict__ y1p,
    const u16* __restrict__ wfh, const u16* __restrict__ wfl,
    const float* __restrict__ scale, const float* __restrict__ shift,
    const float* __restrict__ bias, u32* __restrict__ y2p)
{
  __shared__ __align__(16) u16 sin0[12480], sin1[12480];  // [10 rows][39 cols][32 c]
  __shared__ float sc[32], shf[32];
  int ohq = blockIdx.x, b = blockIdx.y, tid = threadIdx.x;
  if (tid < 32) { sc[tid] = scale[tid]; shf[tid] = shift[tid]; }
  __syncthreads();
  long sb = ((long)b * 1365 + (long)ohq * 312) * 32;
  const uint4* srcP = (const uint4*)(y1p + sb);
  for (int i = tid; i < 3120; i += 256) {
    uint4 p4 = srcP[i];
    int cb = (i & 7) * 4;
    u32 hw[2], lw[2];
    u32 pe[4] = { p4.x, p4.y, p4.z, p4.w };
#pragma unroll
    for (int half = 0; half < 2; ++half) {
      float va = punp(pe[half * 2 + 0]);
      float vb = punp(pe[half * 2 + 1]);
      float aa = gelu_f(va * sc[cb + half * 2 + 0] + shf[cb + half * 2 + 0]);
      float ab = gelu_f(vb * sc[cb + half * 2 + 1] + shf[cb + half * 2 + 1]);
      u32 ua = fbits(aa), ub = fbits(ab);
      float la = aa - ubits(ua & 0xFFFF0000u);
      float lb = ab - ubits(ub & 0xFFFF0000u);
      hw[half] = (ua >> 16) | (ub & 0xFFFF0000u);
      lw[half] = (fbits(la) >> 16) | (fbits(lb) & 0xFFFF0000u);
    }
    int iw = i ^ (((i >> 4) & 7) << 1);   // swizzle (uint2 idx bits 1-3 ^= colpair)
    ((uint2*)sin0)[iw] = make_uint2(hw[0], hw[1]);
    ((uint2*)sin1)[iw] = make_uint2(lw[0], lw[1]);
  }
  __syncthreads();
  int w = tid >> 6, lane = tid & 63, g = lane >> 4, ln = lane & 15;
  int rowb[2], colb[2];
#pragma unroll
  for (int jj = 0; jj < 2; ++jj) {
    int pt = jj ? 4 : w;
    int p = pt * 16 + ln; if (p > 71) p = 71;
    int ohl = p / 18, ow = p - 18 * ohl;
    rowb[jj] = 2 * ohl; colb[jj] = 2 * ow;
  }
  for (int oct = 0; oct < 4; ++oct) {
    f32x4 z4 = {0.f, 0.f, 0.f, 0.f};
    f32x4 acc[2]; acc[0] = z4; acc[1] = z4;
#pragma unroll
    for (int s = 0; s < 16; ++s) {
      int kh = s >> 2, kw = s & 3;
      bf16x8 bh = *(const bf16x8*)&wfh[oct * 8192 + s * 512 + lane * 8];
      bf16x8 bl = *(const bf16x8*)&wfl[oct * 8192 + s * 512 + lane * 8];
#pragma unroll
      for (int jj = 0; jj < 2; ++jj) {
        if (jj == 1 && w != 0) continue;
        int colpix = (rowb[jj] + kh) * 39 + colb[jj] + kw;
        int off = colpix * 32 + g * 8;
        off ^= ((colpix >> 1) & 7) << 3;   // swizzle
        bf16x8 ah = *(const bf16x8*)&sin0[off];
        bf16x8 al = *(const bf16x8*)&sin1[off];
        acc[jj] = mfma3(ah, al, bh, bl, acc[jj]);
      }
    }
    int oc = oct * 16 + ln;
    float bv = bias[oc];
#pragma unroll
    for (int jj = 0; jj < 2; ++jj) {
      if (jj == 1 && w != 0) continue;
      int pt = jj ? 4 : w;
#pragma unroll
      for (int r = 0; r < 4; ++r) {
        int po = pt * 16 + g * 4 + r;
        if (po < 72) {
          long oi = ((long)b * 288 + (long)ohq * 72 + po) * 64 + oc;
          y2p[oi] = psplit(acc[jj][r] + bv);
        }
      }
    }
  }
}

// ---------------- conv3 MFMA (fused BN2+GELU on staging): y2p -> y3p[1024][224][128]
// LDS XOR-swizzled: byte ^= ((colpix&7)<<4) within each 128B column
__global__ __launch_bounds__(256, 3) void k_conv3m(const u32* __restrict__ y2p,
    const u16* __restrict__ wfh, const u16* __restrict__ wfl,
    const float* __restrict__ scale, const float* __restrict__ shift,
    const float* __restrict__ bias, u32* __restrict__ y3p)
{
  __shared__ __align__(16) u16 sin0[10368], sin1[10368];  // [9 rows][18 cols][64 c]
  __shared__ float sc[64], shf[64];
  int hh = blockIdx.x, b = blockIdx.y, tid = threadIdx.x;
  if (tid < 64) { sc[tid] = scale[tid]; shf[tid] = shift[tid]; }
  __syncthreads();
  long sb = ((long)b * 288 + (long)hh * 126) * 64;
  const uint4* srcP = (const uint4*)(y2p + sb);
  for (int i = tid; i < 2592; i += 256) {
    uint4 p4 = srcP[i];
    int cb = (i & 15) * 4;
    u32 hw[2], lw[2];
    u32 pe[4] = { p4.x, p4.y, p4.z, p4.w };
#pragma unroll
    for (int half = 0; half < 2; ++half) {
      float va = punp(pe[half * 2 + 0]);
      float vb = punp(pe[half * 2 + 1]);
      float aa = gelu_f(va * sc[cb + half * 2 + 0] + shf[cb + half * 2 + 0]);
      float ab = gelu_f(vb * sc[cb + half * 2 + 1] + shf[cb + half * 2 + 1]);
      u32 ua = fbits(aa), ub = fbits(ab);
      float la = aa - ubits(ua & 0xFFFF0000u);
      float lb = ab - ubits(ub & 0xFFFF0000u);
      hw[half] = (ua >> 16) | (ub & 0xFFFF0000u);
      lw[half] = (fbits(la) >> 16) | (fbits(lb) & 0xFFFF0000u);
    }
    int iw = i ^ (((i >> 4) & 7) << 1);   // swizzle (uint2 idx bits 1-3 ^= colpix)
    ((uint2*)sin0)[iw] = make_uint2(hw[0], hw[1]);
    ((uint2*)sin1)[iw] = make_uint2(lw[0], lw[1]);
  }
  __syncthreads();
  int w = tid >> 6, lane = tid & 63, g = lane >> 4, ln = lane & 15;
  for (int oct = 0; oct < 8; ++oct) {
    f32x4 z4 = {0.f, 0.f, 0.f, 0.f};
    f32x4 acc[2]; acc[0] = z4; acc[1] = z4;
#pragma unroll
    for (int s = 0; s < 18; ++s) {
      const int kh = s / 6, rm = s % 6;
      const int kw = rm >> 1, ch = rm & 1;
      bf16x8 bh = *(const bf16x8*)&wfh[oct * 9216 + s * 512 + lane * 8];
      bf16x8 bl = *(const bf16x8*)&wfl[oct * 9216 + s * 512 + lane * 8];
#pragma unroll
      for (int jj = 0; jj < 2; ++jj) {
        if (jj == 1 && w == 3) continue;
        int ohl = w + jj * 4;
        int colpix = (ohl + kh) * 18 + ln + kw;
        int off = colpix * 64 + ch * 32 + g * 8;
        off ^= (colpix & 7) << 3;   // swizzle
        bf16x8 ah = *(const bf16x8*)&sin0[off];
        bf16x8 al = *(const bf16x8*)&sin1[off];
        acc[jj] = mfma3(ah, al, bh, bl, acc[jj]);
      }
    }
    int oc = oct * 16 + ln;
    float bv = bias[oc];
#pragma unroll
    for (int jj = 0; jj < 2; ++jj) {
      if (jj == 1 && w == 3) continue;
      int ohl = w + jj * 4;
#pragma unroll
      for (int r = 0; r < 4; ++r) {
        int owo = g * 4 + r;
        long oi = ((long)b * 224 + (hh * 7 + ohl) * 16 + owo) * 128 + oc;
        y3p[oi] = psplit(acc[jj][r] + bv);
      }
    }
  }
}

// ---------------- BN stats over packed channels-last ----------------
__global__ __launch_bounds__(256) void k_bnstat(const u32* __restrict__ pk,
    float* __restrict__ sums, int C, long npix)
{
  int half = C >> 1;
  int cp = threadIdx.x % half;
  int rl = threadIdx.x / half;
  int rpi = 256 / half;
  long chunk = (npix + gridDim.x - 1) / gridDim.x;
  long p0 = (long)blockIdx.x * chunk;
  long p1 = p0 + chunk; if (p1 > npix) p1 = npix;
  float s1a = 0.f, s1b = 0.f, s2a = 0.f, s2b = 0.f;
  for (long p = p0 + rl; p < p1; p += rpi) {
    uint2 pu = *(const uint2*)(pk + p * C + cp * 2);
    float v0 = punp(pu.x);
    float v1 = punp(pu.y);
    s1a += v0; s2a += v0 * v0; s1b += v1; s2b += v1 * v1;
  }
  __shared__ float bs1[128], bs2[128];
  for (int i = threadIdx.x; i < C; i += 256) { bs1[i] = 0.f; bs2[i] = 0.f; }
  __syncthreads();
  atomicAdd(&bs1[2 * cp], s1a); atomicAdd(&bs1[2 * cp + 1], s1b);
  atomicAdd(&bs2[2 * cp], s2a); atomicAdd(&bs2[2 * cp + 1], s2b);
  __syncthreads();
  if (threadIdx.x < C) {
    atomicAdd(&sums[threadIdx.x], bs1[threadIdx.x]);
    atomicAdd(&sums[C + threadIdx.x], bs2[threadIdx.x]);
  }
}

__global__ void k_bn_finalize(const float* __restrict__ sums, const float* __restrict__ g,
    const float* __restrict__ b, float* __restrict__ scale, float* __restrict__ shift,
    int C, float invN)
{
  int c = threadIdx.x;
  if (c < C) {
    float m = sums[c] * invN;
    float var = sums[C + c] * invN - m * m;
    float sc = g[c] * rsqrtf(var + 1e-5f);
    scale[c] = sc;
    shift[c] = b[c] - m * sc;
  }
}

// ---------------- BN apply + GELU in-place on packed (y3) ----------------
__global__ __launch_bounds__(256) void k_bnapplyP(u32* __restrict__ pk,
    const float* __restrict__ scale, const float* __restrict__ shift, int C, long nelem)
{
  __shared__ float sc[128], sh[128];
  for (int i = threadIdx.x; i < C; i += 256) { sc[i] = scale[i]; sh[i] = shift[i]; }
  __syncthreads();
  long i0 = ((long)blockIdx.x * 256 + threadIdx.x) * 4;
  long stride = (long)gridDim.x * 1024;
  for (long i = i0; i < nelem; i += stride) {
    uint4 v4 = *(uint4*)(pk + i);
    int cb = (int)(i & (long)(C - 1));
    u32 src[4] = { v4.x, v4.y, v4.z, v4.w };
    u32 r[4];
#pragma unroll
    for (int j = 0; j < 4; ++j) {
      float v = punp(src[j]);
      float a = gelu_f(v * sc[cb + j] + sh[cb + j]);
      r[j] = psplit(a);
    }
    *(uint4*)(pk + i) = make_uint4(r[0], r[1], r[2], r[3]);
  }
}

// ---------------- proj MFMA split-K: y3p tokens x wfp -> part[32][1024][256]
__global__ __launch_bounds__(256, 2) void k_projm(const u32* __restrict__ y3p,
    const u16* __restrict__ bh_g, const u16* __restrict__ bl_g, float* __restrict__ part)
{
  __shared__ __align__(16) u16 Ah[2048], Al[2048];   // [64 tok][32 k]
  __shared__ __align__(16) u16 Bh[8192], Bl[8192];   // [16 oct][512]
  int m0 = blockIdx.x * 64, by = blockIdx.y, tid = threadIdx.x;
  int w = tid >> 6, lane = tid & 63, g = lane >> 4, ln = lane & 15;
  f32x4 z4 = {0.f, 0.f, 0.f, 0.f};
  f32x4 acc[16];
#pragma unroll
  for (int o = 0; o < 16; ++o) acc[o] = z4;
  for (int ks = 0; ks < 28; ++ks) {
    __syncthreads();
    long k0 = ((long)by * 28 + ks) * 32;
    {
      for (int ii = 0; ii < 2; ++ii) {
        int i = tid + ii * 256;
        int row = i >> 3, q = i & 7;
        uint4 p4 = *((const uint4*)(y3p + (long)(m0 + row) * 28672 + k0) + q);
        u32 h01 = (p4.x & 0xFFFFu) | (p4.y << 16);
        u32 l01 = (p4.x >> 16) | (p4.y & 0xFFFF0000u);
        u32 h23 = (p4.z & 0xFFFFu) | (p4.w << 16);
        u32 l23 = (p4.z >> 16) | (p4.w & 0xFFFF0000u);
        ((uint2*)Ah)[i] = make_uint2(h01, h23);
        ((uint2*)Al)[i] = make_uint2(l01, l23);
      }
    }
    int ksg = by * 28 + ks;
#pragma unroll
    for (int ii = 0; ii < 8; ++ii) {
      int i = tid + ii * 256;
      int arr = i >> 10, idx = i & 1023, oct = idx >> 6, r2 = idx & 63;
      const u16* src = arr ? bl_g : bh_g;
      u16* dst = arr ? Bl : Bh;
      ((uint4*)dst)[idx] = *((const uint4*)(src + ((long)oct * 896 + ksg) * 512) + r2);
    }
    __syncthreads();
    bf16x8 a_h = *(const bf16x8*)&Ah[(w * 16 + ln) * 32 + g * 8];
    bf16x8 a_l = *(const bf16x8*)&Al[(w * 16 + ln) * 32 + g * 8];
#pragma unroll
    for (int oct = 0; oct < 16; ++oct) {
      bf16x8 bh = *(const bf16x8*)&Bh[oct * 512 + lane * 8];
      bf16x8 bl = *(const bf16x8*)&Bl[oct * 512 + lane * 8];
      acc[oct] = mfma3(a_h, a_l, bh, bl, acc[oct]);
    }
  }
#pragma unroll
  for (int oct = 0; oct < 16; ++oct) {
    int oc = oct * 16 + ln;
#pragma unroll
    for (int r = 0; r < 4; ++r) {
      int tok = m0 + w * 16 + g * 4 + r;
      part[((long)by * 1024 + tok) * 256 + oc] = acc[oct][r];
    }
  }
}

// ---------------- split-K reduce + bias + LN + GELU (writes f32 h and bf16 h) ----------------
__global__ __launch_bounds__(256) void k_lnred(const float* __restrict__ part,
    const float* __restrict__ pb, const float* __restrict__ g, const float* __restrict__ be,
    float* __restrict__ h, u16* __restrict__ hb)
{
  int b = blockIdx.x, d = threadIdx.x;
  float s = pb[d];
#pragma unroll
  for (int ks = 0; ks < 32; ++ks) s += part[((long)ks * 1024 + b) * 256 + d];
  __shared__ float red[4];
  float t = s;
  for (int o = 32; o; o >>= 1) t += __shfl_xor(t, o);
  if ((d & 63) == 0) red[d >> 6] = t;
  __syncthreads();
  float mean = (red[0] + red[1] + red[2] + red[3]) * (1.f / 256.f);
  __syncthreads();
  float dv = s - mean;
  t = dv * dv;
  for (int o = 32; o; o >>= 1) t += __shfl_xor(t, o);
  if ((d & 63) == 0) red[d >> 6] = t;
  __syncthreads();
  float var = (red[0] + red[1] + red[2] + red[3]) * (1.f / 256.f);
  float hv = gelu_f(g[d] * dv * rsqrtf(var + 1e-5f) + be[d]);
  h[b * 256 + d] = hv;
  hb[b * 256 + d] = f2bf(hv);
}

// ---------------- generic plain-bf16 MFMA GEMM: C[z][M][N] = A[z][M][K] @ Bfrag + bias
__global__ __launch_bounds__(256, 2) void k_gemmb(const u16* __restrict__ A, long aZ, int K,
    const u16* __restrict__ Bf, int noct_tot,
    const float* __restrict__ bias, int biasZ,
    void* __restrict__ C, long cZ, int ldc, int outbf, int act)
{
  __shared__ __align__(16) u16 As[2048];
  __shared__ __align__(16) u16 Bs[8192];
  int m0 = blockIdx.x * 64, nb = blockIdx.y, z = blockIdx.z, tid = threadIdx.x;
  int w = tid >> 6, lane = tid & 63, g = lane >> 4, ln = lane & 15;
  const u16* Az = A + (long)z * aZ;
  int kn = K >> 5;
  f32x4 z4 = {0.f, 0.f, 0.f, 0.f};
  f32x4 acc[16];
#pragma unroll
  for (int o = 0; o < 16; ++o) acc[o] = z4;
  for (int ks = 0; ks < kn; ++ks) {
    __syncthreads();
    {
      int row = tid >> 2, q = tid & 3;
      ((uint4*)As)[tid] = *((const uint4*)(Az + (long)(m0 + row) * K + ks * 32) + q);
    }
#pragma unroll
    for (int ii = 0; ii < 4; ++ii) {
      int i = tid + ii * 256;
      int oct = i >> 6, r2 = i & 63;
      const u16* src = Bf + (((long)z * noct_tot + nb * 16 + oct) * kn + ks) * 512;
      ((uint4*)Bs)[i] = ((const uint4*)src)[r2];
    }
    __syncthreads();
    bf16x8 a = *(const bf16x8*)&As[(w * 16 + ln) * 32 + g * 8];
#pragma unroll
    for (int oct = 0; oct < 16; ++oct) {
      bf16x8 bb = *(const bf16x8*)&Bs[oct * 512 + lane * 8];
      acc[oct] = __builtin_amdgcn_mfma_f32_16x16x32_bf16(a, bb, acc[oct], 0, 0, 0);
    }
  }
#pragma unroll
  for (int oct = 0; oct < 16; ++oct) {
    int n = nb * 256 + oct * 16 + ln;
    float bv = bias[z * biasZ + n];
#pragma unroll
    for (int r = 0; r < 4; ++r) {
      int tok = m0 + w * 16 + g * 4 + r;
      float v = acc[oct][r] + bv;
      if (act) v = gelu_f(v);
      long off = (long)z * cZ + (long)tok * ldc + n;
      if (outbf) ((u16*)C)[off] = f2bf(v);
      else ((float*)C)[off] = v;
    }
  }
}

// ---------------- router ----------------
__global__ __launch_bounds__(64) void k_router(const float* __restrict__ h,
    const float* __restrict__ rw, const float* __restrict__ eb,
    float* __restrict__ wts, int* __restrict__ idx,
    float* __restrict__ pm_sum, float* __restrict__ z_sum)
{
  int b = blockIdx.x, lane = threadIdx.x;
  float4 hv = *(const float4*)(h + b * 256 + lane * 4);
  float logit[8];
#pragma unroll
  for (int e = 0; e < 8; ++e) {
    float4 wv = *(const float4*)(rw + e * 256 + lane * 4);
    float p = hv.x * wv.x + hv.y * wv.y + hv.z * wv.z + hv.w * wv.w;
    for (int o = 32; o; o >>= 1) p += __shfl_xor(p, o);
    logit[e] = p + eb[e];
  }
  float mx = logit[0];
#pragma unroll
  for (int e = 1; e < 8; ++e) mx = fmaxf(mx, logit[e]);
  float pr[8]; float se = 0.f;
#pragma unroll
  for (int e = 0; e < 8; ++e) { pr[e] = expf(logit[e] - mx); se += pr[e]; }
  float inv = 1.f / se;
#pragma unroll
  for (int e = 0; e < 8; ++e) pr[e] *= inv;
  int i0 = 0; float v0 = pr[0];
#pragma unroll
  for (int e = 1; e < 8; ++e) if (pr[e] > v0) { v0 = pr[e]; i0 = e; }
  int i1 = -1; float v1 = -1.f;
#pragma unroll
  for (int e = 0; e < 8; ++e) if (e != i0 && pr[e] > v1) { v1 = pr[e]; i1 = e; }
  if (lane == 0) {
    float ssum = v0 + v1 + 1e-8f;
    wts[2 * b] = v0 / ssum; wts[2 * b + 1] = v1 / ssum;
    idx[2 * b] = i0; idx[2 * b + 1] = i1;
    float zz = 0.f;
#pragma unroll
    for (int e = 0; e < 8; ++e) zz += logit[e] * logit[e];
    atomicAdd(z_sum, zz);
  }
  if (lane < 8) atomicAdd(&pm_sum[lane], pr[lane]);
}

// ---------------- combine + 0.5*shared + final LN ----------------
__global__ __launch_bounds__(256) void k_combine_ln(const float* __restrict__ eout,
    const float* __restrict__ sharedB, const float* __restrict__ wts, const int* __restrict__ idx,
    const float* __restrict__ g, const float* __restrict__ bb, float* __restrict__ out)
{
  int b = blockIdx.x, d = threadIdx.x;
  float w0 = wts[2 * b], w1 = wts[2 * b + 1];
  int i0 = idx[2 * b], i1 = idx[2 * b + 1];
  float val = w0 * eout[(long)i0 * 262144 + b * 256 + d]
            + w1 * eout[(long)i1 * 262144 + b * 256 + d]
            + 0.5f * sharedB[b * 256 + d];
  __shared__ float red[4];
  float s = val;
  for (int o = 32; o; o >>= 1) s += __shfl_xor(s, o);
  if ((d & 63) == 0) red[d >> 6] = s;
  __syncthreads();
  float mean = (red[0] + red[1] + red[2] + red[3]) * (1.f / 256.f);
  __syncthreads();
  float dv = val - mean;
  s = dv * dv;
  for (int o = 32; o; o >>= 1) s += __shfl_xor(s, o);
  if ((d & 63) == 0) red[d >> 6] = s;
  __syncthreads();
  float var = (red[0] + red[1] + red[2] + red[3]) * (1.f / 256.f);
  out[b * 256 + d] = g[d] * dv * rsqrtf(var + 1e-5f) + bb[d];
}

// ---------------- aux losses ----------------
__global__ void k_losses(const float* __restrict__ pm_sum, const float* __restrict__ z_sum,
                         float* __restrict__ out)
{
  if (threadIdx.x == 0 && blockIdx.x == 0) {
    float lb = 0.f;
    for (int e = 0; e < 8; ++e) {
      float pm = pm_sum[e] * (1.f / 1024.f);
      float dd = pm - 0.125f;
      lb += dd * dd;
    }
    out[262144] = lb * 8.f;
    out[262145] = z_sum[0] * (1.f / 8192.f) * 0.001f;
  }
}

extern "C" void kernel_launch(void* const* d_in, const int* in_sizes, int n_in,
                              void* d_out, int out_size, void* d_ws, size_t ws_size,
                              hipStream_t stream)
{
  const float* x     = (const float*)d_in[0];
  const float* c1w   = (const float*)d_in[1];
  const float* c1b   = (const float*)d_in[2];
  const float* bn1g  = (const float*)d_in[3];
  const float* bn1b  = (const float*)d_in[4];
  const float* c2w   = (const float*)d_in[5];
  const float* c2b   = (const float*)d_in[6];
  const float* bn2g  = (const float*)d_in[7];
  const float* bn2b  = (const float*)d_in[8];
  const float* c3w   = (const float*)d_in[9];
  const float* c3b   = (const float*)d_in[10];
  const float* bn3g  = (const float*)d_in[11];
  const float* bn3b  = (const float*)d_in[12];
  const float* projw = (const float*)d_in[13];
  const float* projb = (const float*)d_in[14];
  const float* lng   = (const float*)d_in[15];
  const float* lnb   = (const float*)d_in[16];
  const float* rw    = (const float*)d_in[17];
  const float* ebias = (const float*)d_in[18];
  const float* ew1   = (const float*)d_in[19];
  const float* eb1   = (const float*)d_in[20];
  const float* ew2   = (const float*)d_in[21];
  const float* eb2   = (const float*)d_in[22];
  const float* sw1   = (const float*)d_in[23];
  const float* sb1   = (const float*)d_in[24];
  const float* sw2   = (const float*)d_in[25];
  const float* sb2   = (const float*)d_in[26];
  const float* mlng  = (const float*)d_in[27];
  const float* mlnb  = (const float*)d_in[28];
  float* out = (float*)d_out;

  char* W = (char*)d_ws;
  u32* y1p = (u32*)(W + 0);              // 178,913,280 B
  u32* y2p = (u32*)(W + 178913280L);     // 75,497,472 B
  u32* y3p = (u32*)(W + 0);              // 117,440,512 B (alias dead y1)
  u16* wfph = (u16*)(W + 254410752L);
  u16* wfpl = (u16*)(W + 269090816L);
  u16* wf1h = (u16*)(W + 283770880L);
  u16* wf1l = (u16*)(W + 283787264L);
  u16* wf2h = (u16*)(W + 283803648L);
  u16* wf2l = (u16*)(W + 283869184L);
  u16* wf3h = (u16*)(W + 283934720L);
  u16* wf3l = (u16*)(W + 284082176L);
  float* stats = (float*)(W + 284229632L);
  float* wtsb  = (float*)(W + 284233728L);
  int*   idxb  = (int*)(W + 284241920L);
  float* hbuf  = (float*)(W + 284250112L);
  float* shB   = (float*)(W + 286347264L);
  // tail region inside the y2p span — all used only after conv3m completes
  float* part  = (float*)(W + 178913280L);  // 33,554,432 B
  u16* hid     = (u16*)(W + 212467712L);    // 8,388,608 B
  u16* ewf1    = (u16*)(W + 220856320L);    // 2,097,152 B
  u16* ewf2    = (u16*)(W + 222953472L);    // 2,097,152 B
  u16* swf1    = (u16*)(W + 225050624L);    // 131,072 B
  u16* swf2    = (u16*)(W + 225181696L);    // 131,072 B
  float* eoutB = (float*)(W + 225312768L);  // 8,388,608 B
  u16* hbufb   = (u16*)(W + 233701376L);    // 524,288 B
  u16* sh1b    = (u16*)(W + 234225664L);    // 524,288 B

  float* sums1 = stats;        float* scale1 = stats + 512; float* shift1 = stats + 544;
  float* sums2 = stats + 64;   float* scale2 = stats + 576; float* shift2 = stats + 640;
  float* sums3 = stats + 192;  float* scale3 = stats + 704; float* shift3 = stats + 832;
  float* pm    = stats + 448;  float* zsum   = stats + 456;

  dim3 blk(256);
  k_zero<<<dim3(2), blk, 0, stream>>>(stats, 512);
  k_wprep1<<<dim3(32), blk, 0, stream>>>(c1w, wf1h, wf1l);
  k_wprep2<<<dim3(128), blk, 0, stream>>>(c2w, wf2h, wf2l);
  k_wprep3<<<dim3(288), blk, 0, stream>>>(c3w, wf3h, wf3l);
  k_wprepP<<<dim3(32, 16), blk, 0, stream>>>(projw, wfph, wfpl);

  k_conv1m<<<dim3(18, 1024), blk, 0, stream>>>(x, wf1h, wf1l, c1b, y1p);
  k_bnstat<<<dim3(512), blk, 0, stream>>>(y1p, sums1, 32, 1397760L);
  k_bn_finalize<<<1, 32, 0, stream>>>(sums1, bn1g, bn1b, scale1, shift1, 32, 1.f / 1397760.f);

  k_conv2m<<<dim3(4, 1024), blk, 0, stream>>>(y1p, wf2h, wf2l, scale1, shift1, c2b, y2p);
  k_bnstat<<<dim3(512), blk, 0, stream>>>(y2p, sums2, 64, 294912L);
  k_bn_finalize<<<1, 64, 0, stream>>>(sums2, bn2g, bn2b, scale2, shift2, 64, 1.f / 294912.f);

  k_conv3m<<<dim3(2, 1024), blk, 0, stream>>>(y2p, wf3h, wf3l, scale2, shift2, c3b, y3p);
  k_bnstat<<<dim3(512), blk, 0, stream>>>(y3p, sums3, 128, 229376L);
  k_bn_finalize<<<1, 128, 0, stream>>>(sums3, bn3g, bn3b, scale3, shift3, 128, 1.f / 229376.f);
  k_bnapplyP<<<dim3(2048), blk, 0, stream>>>(y3p, scale3, shift3, 128, 29360128L);

  // expert/shared weight preps (y2p region is dead now)
  k_wprepG<<<dim3(4096), blk, 0, stream>>>(ew1, ewf1, 512, 256, 1048576L);
  k_wprepG<<<dim3(4096), blk, 0, stream>>>(ew2, ewf2, 256, 512, 1048576L);
  k_wprepG<<<dim3(256), blk, 0, stream>>>(sw1, swf1, 256, 256, 65536L);
  k_wprepG<<<dim3(256), blk, 0, stream>>>(sw2, swf2, 256, 256, 65536L);

  k_projm<<<dim3(16, 32), blk, 0, stream>>>(y3p, wfph, wfpl, part);
  k_lnred<<<dim3(1024), blk, 0, stream>>>(part, projb, lng, lnb, hbuf, hbufb);

  k_router<<<dim3(1024), dim3(64), 0, stream>>>(hbuf, rw, ebias, wtsb, idxb, pm, zsum);

  // experts (dense) + shared, plain bf16 MFMA
  k_gemmb<<<dim3(16, 2, 8), blk, 0, stream>>>(hbufb, 0L, 256, ewf1, 32, eb1, 512,
                                              (void*)hid, 524288L, 512, 1, 1);
  k_gemmb<<<dim3(16, 1, 8), blk, 0, stream>>>(hid, 524288L, 512, ewf2, 16, eb2, 256,
                                              (void*)eoutB, 262144L, 256, 0, 0);
  k_gemmb<<<dim3(16, 1, 1), blk, 0, stream>>>(hbufb, 0L, 256, swf1, 16, sb1, 0,
                                              (void*)sh1b, 0L, 256, 1, 1);
  k_gemmb<<<dim3(16, 1, 1), blk, 0, stream>>>(sh1b, 0L, 256, swf2, 16, sb2, 0,
                                              (void*)shB, 0L, 256, 0, 0);

  k_combine_ln<<<dim3(1024), blk, 0, stream>>>(eoutB, shB, wtsb, idxb, mlng, mlnb, out);
  k_losses<<<1, 64, 0, stream>>>(pm, zsum, out);
}

// Round 8
// 976.977 us; speedup vs baseline: 1.4068x; 1.4068x over previous
//
#include <hip/hip_runtime.h>
#include <hip/hip_bf16.h>
#include <math.h>

typedef unsigned short u16;
typedef unsigned int u32;
typedef __attribute__((ext_vector_type(8))) short bf16x8;
typedef __attribute__((ext_vector_type(4))) float f32x4;

#define DEV __device__ __forceinline__

DEV float gelu_f(float x) { return 0.5f * x * (1.0f + erff(x * 0.70710678118654752f)); }
DEV u16 f2bf(float f) { u32 u = __builtin_bit_cast(u32, f); u = (u + 0x7FFFu + ((u >> 16) & 1u)) >> 16; return (u16)u; }
DEV float bf2f(u16 h) { return __builtin_bit_cast(float, (u32)h << 16); }
DEV u32 fbits(float f) { return __builtin_bit_cast(u32, f); }
DEV float ubits(u32 u) { return __builtin_bit_cast(float, u); }
// packed format: p = hi_u16 | (lo_u16 << 16), v ~= bf(hi) + bf(lo), trunc split (2^-16)
DEV u32 psplit(float v) {
  u32 u = fbits(v);
  float lo = v - ubits(u & 0xFFFF0000u);
  return (u >> 16) | (fbits(lo) & 0xFFFF0000u);
}
DEV float punp(u32 p) { return ubits(p << 16) + ubits(p & 0xFFFF0000u); }
// 3-term split product: a*b ~= ah*bh + ah*bl + al*bh
DEV f32x4 mfma3(bf16x8 ah, bf16x8 al, bf16x8 bh, bf16x8 bl, f32x4 c) {
  c = __builtin_amdgcn_mfma_f32_16x16x32_bf16(al, bh, c, 0, 0, 0);
  c = __builtin_amdgcn_mfma_f32_16x16x32_bf16(ah, bl, c, 0, 0, 0);
  c = __builtin_amdgcn_mfma_f32_16x16x32_bf16(ah, bh, c, 0, 0, 0);
  return c;
}

// ---------------- zero stats ----------------
__global__ void k_zero(float* p, int n) {
  int i = blockIdx.x * blockDim.x + threadIdx.x;
  if (i < n) p[i] = 0.f;
}

// ---------------- conv weight frag preps: layout [((oct*NS + s)*64 + lane)*8 + j] ----------------
__global__ void k_wprep1(const float* __restrict__ w, u16* __restrict__ wh, u16* __restrict__ wl) {
  int idx = blockIdx.x * 256 + threadIdx.x; if (idx >= 8192) return;
  int j = idx & 7, lane = (idx >> 3) & 63, s = (idx >> 9) & 7, oct = idx >> 12;
  int oc = oct * 16 + (lane & 15);
  int kl = ((lane >> 4) << 3) + j;
  int kw = kl >> 2, c = kl & 3, kh = s;
  float v = w[((oc * 4 + c) * 8 + kh) * 8 + kw];
  u16 h = f2bf(v); wh[idx] = h; wl[idx] = f2bf(v - bf2f(h));
}
__global__ void k_wprep2(const float* __restrict__ w, u16* __restrict__ wh, u16* __restrict__ wl) {
  int idx = blockIdx.x * 256 + threadIdx.x; if (idx >= 32768) return;
  int j = idx & 7, lane = (idx >> 3) & 63, s = (idx >> 9) & 15, oct = idx >> 13;
  int oc = oct * 16 + (lane & 15);
  int k = s * 32 + ((lane >> 4) << 3) + j;
  int kh = k >> 7, kw = (k >> 5) & 3, c = k & 31;
  float v = w[((oc * 32 + c) * 4 + kh) * 4 + kw];
  u16 h = f2bf(v); wh[idx] = h; wl[idx] = f2bf(v - bf2f(h));
}
__global__ void k_wprep3(const float* __restrict__ w, u16* __restrict__ wh, u16* __restrict__ wl) {
  int idx = blockIdx.x * 256 + threadIdx.x; if (idx >= 73728) return;
  int j = idx & 7, lane = (idx >> 3) & 63, rest = idx >> 9;
  int s = rest % 18, oct = rest / 18;
  int oc = oct * 16 + (lane & 15);
  int k = s * 32 + ((lane >> 4) << 3) + j;
  int kh = k / 192, r = k - kh * 192;
  int kw = r >> 6, c = r & 63;
  float v = w[((oc * 64 + c) * 3 + kh) * 3 + kw];
  u16 h = f2bf(v); wh[idx] = h; wl[idx] = f2bf(v - bf2f(h));
}
// proj weight prep, LDS-transpose tiled
__global__ __launch_bounds__(256) void k_wprepP(const float* __restrict__ w,
    u16* __restrict__ wh, u16* __restrict__ wl)
{
  __shared__ float tile[16][4][225];
  int q = blockIdx.x, oct = blockIdx.y, tid = threadIdx.x;
  for (int i = tid; i < 3584; i += 256) {
    int n = i / 224, rem = i % 224, e = rem / 56, f4 = rem % 56;
    float4 v = *(const float4*)(w + (long)(oct * 16 + n) * 28672 + (4 * q + e) * 224 + f4 * 4);
    tile[n][e][f4 * 4 + 0] = v.x; tile[n][e][f4 * 4 + 1] = v.y;
    tile[n][e][f4 * 4 + 2] = v.z; tile[n][e][f4 * 4 + 3] = v.w;
  }
  __syncthreads();
  int g = (q >> 1) & 3, j0 = 4 * (q & 1), sgb = q >> 3;
  for (int o = tid; o < 3584; o += 256) {
    int pix = o >> 4, ln = o & 15;
    u16 hs[4], ls[4];
#pragma unroll
    for (int e = 0; e < 4; ++e) {
      float v = tile[ln][e][pix];
      u16 h = f2bf(v); hs[e] = h; ls[e] = f2bf(v - bf2f(h));
    }
    long base = (((long)oct * 896 + pix * 4 + sgb) * 64 + g * 16 + ln) * 8 + j0;
    *(uint2*)(wh + base) = make_uint2((u32)hs[0] | ((u32)hs[1] << 16), (u32)hs[2] | ((u32)hs[3] << 16));
    *(uint2*)(wl + base) = make_uint2((u32)ls[0] | ((u32)ls[1] << 16), (u32)ls[2] | ((u32)ls[3] << 16));
  }
}
// generic plain-bf16 frag prep for expert/shared weights W[Z][N][K]
__global__ void k_wprepG(const float* __restrict__ w, u16* __restrict__ wf,
                         int N, int K, long total)
{
  long idx = (long)blockIdx.x * 256 + threadIdx.x; if (idx >= total) return;
  int j = (int)(idx & 7); int lane = (int)((idx >> 3) & 63); long rest = idx >> 9;
  int kn = K >> 5;
  int s = (int)(rest % kn); long rest2 = rest / kn;
  int noct = N >> 4;
  int oct = (int)(rest2 % noct); int z = (int)(rest2 / noct);
  int n = oct * 16 + (lane & 15);
  int k = s * 32 + ((lane >> 4) << 3) + j;
  wf[idx] = f2bf(w[((long)z * N + n) * K + k]);
}

// ---------------- conv1 MFMA: x[1024,4,144,160] s4 8x8 -> y1p[1024][1365][32] packed
__global__ __launch_bounds__(256, 5) void k_conv1m(const float* __restrict__ x,
    const u16* __restrict__ wfh, const u16* __restrict__ wfl,
    const float* __restrict__ bias, u32* __restrict__ y1p)
{
  __shared__ __align__(16) u16 sin0[7680], sin1[7680];   // [12 rows][160 cols][4 c]
  int ohp = blockIdx.x, b = blockIdx.y, tid = threadIdx.x;
  int row0 = ohp * 8;
  for (int i = tid; i < 960; i += 256) {
    int cp = i / 480, rem = i - cp * 480, r = rem / 40, q = rem - r * 40;
    int grow = row0 + r;
    float4 v0 = make_float4(0.f, 0.f, 0.f, 0.f), v1 = v0;
    if (grow < 144) {
      long base = ((long)b * 4 + 2 * cp) * 23040 + (long)grow * 160 + q * 4;
      v0 = *(const float4*)(x + base);
      v1 = *(const float4*)(x + base + 23040);
    }
    const float* a0 = (const float*)&v0;
    const float* a1 = (const float*)&v1;
#pragma unroll
    for (int m = 0; m < 4; ++m) {
      float f0 = a0[m], f1 = a1[m];
      u32 u0 = fbits(f0), u1 = fbits(f1);
      u32 hh = (u0 >> 16) | (u1 & 0xFFFF0000u);
      float l0 = f0 - ubits(u0 & 0xFFFF0000u);
      float l1 = f1 - ubits(u1 & 0xFFFF0000u);
      u32 ll = (fbits(l0) >> 16) | (fbits(l1) & 0xFFFF0000u);
      int col = q * 4 + m;
      ((u32*)sin0)[r * 320 + col * 2 + cp] = hh;
      ((u32*)sin1)[r * 320 + col * 2 + cp] = ll;
    }
  }
  __syncthreads();
  int w = tid >> 6, lane = tid & 63, g = lane >> 4, ln = lane & 15;
  int ohls[2], owcs[2];
  {
    int j0 = w;          ohls[0] = j0 / 3; owcs[0] = (j0 % 3) * 16 + ln; if (owcs[0] > 38) owcs[0] = 38;
    int j1 = w + 4;      int oh1 = j1 / 3, ow1 = (j1 % 3) * 16 + ln; if (ow1 > 38) ow1 = 38;
    ohls[1] = (j1 < 6) ? oh1 : 0; owcs[1] = (j1 < 6) ? ow1 : 0;
  }
  f32x4 z4 = {0.f, 0.f, 0.f, 0.f};
  f32x4 acc[2][2];
  acc[0][0] = z4; acc[0][1] = z4; acc[1][0] = z4; acc[1][1] = z4;
#pragma unroll
  for (int kh = 0; kh < 8; ++kh) {
    bf16x8 bh0 = *(const bf16x8*)&wfh[kh * 512 + lane * 8];
    bf16x8 bl0 = *(const bf16x8*)&wfl[kh * 512 + lane * 8];
    bf16x8 bh1 = *(const bf16x8*)&wfh[4096 + kh * 512 + lane * 8];
    bf16x8 bl1 = *(const bf16x8*)&wfl[4096 + kh * 512 + lane * 8];
#pragma unroll
    for (int jj = 0; jj < 2; ++jj) {
      if (jj == 1 && w >= 2) continue;
      int off = (4 * ohls[jj] + kh) * 640 + owcs[jj] * 16 + g * 8;
      bf16x8 ah = *(const bf16x8*)&sin0[off];
      bf16x8 al = *(const bf16x8*)&sin1[off];
      acc[jj][0] = mfma3(ah, al, bh0, bl0, acc[jj][0]);
      acc[jj][1] = mfma3(ah, al, bh1, bl1, acc[jj][1]);
    }
  }
#pragma unroll
  for (int jj = 0; jj < 2; ++jj) {
    if (jj == 1 && w >= 2) continue;
    int j = w + jj * 4;
    int ohl = j / 3, owt = j % 3;
    int oh = 2 * ohp + ohl;
    if (oh >= 35) continue;
#pragma unroll
    for (int oct = 0; oct < 2; ++oct) {
      int oc = oct * 16 + ln;
      float bv = bias[oc];
#pragma unroll
      for (int r = 0; r < 4; ++r) {
        int owo = owt * 16 + g * 4 + r;
        if (owo < 39) {
          long oi = ((long)b * 1365 + oh * 39 + owo) * 32 + oc;
          y1p[oi] = psplit(acc[jj][oct][r] + bv);
        }
      }
    }
  }
}

// ---------------- conv2 MFMA (fused BN1+GELU on staging): y1p -> y2p[1024][288][64]
// octile-per-wave: wave w owns octile w; all 5 pixel-tiles per wave.
__global__ __launch_bounds__(256, 3) void k_conv2m(const u32* __restrict__ y1p,
    const u16* __restrict__ wfh, const u16* __restrict__ wfl,
    const float* __restrict__ scale, const float* __restrict__ shift,
    const float* __restrict__ bias, u32* __restrict__ y2p)
{
  __shared__ __align__(16) u16 sin0[12480], sin1[12480];  // [10 rows][39 cols][32 c]
  __shared__ float sc[32], shf[32];
  int ohq = blockIdx.x, b = blockIdx.y, tid = threadIdx.x;
  if (tid < 32) { sc[tid] = scale[tid]; shf[tid] = shift[tid]; }
  __syncthreads();
  long sb = ((long)b * 1365 + (long)ohq * 312) * 32;
  const uint4* srcP = (const uint4*)(y1p + sb);
  for (int i = tid; i < 3120; i += 256) {
    uint4 p4 = srcP[i];
    int cb = (i & 7) * 4;
    u32 hw[2], lw[2];
    u32 pe[4] = { p4.x, p4.y, p4.z, p4.w };
#pragma unroll
    for (int half = 0; half < 2; ++half) {
      float va = punp(pe[half * 2 + 0]);
      float vb = punp(pe[half * 2 + 1]);
      float aa = gelu_f(va * sc[cb + half * 2 + 0] + shf[cb + half * 2 + 0]);
      float ab = gelu_f(vb * sc[cb + half * 2 + 1] + shf[cb + half * 2 + 1]);
      u32 ua = fbits(aa), ub = fbits(ab);
      float la = aa - ubits(ua & 0xFFFF0000u);
      float lb = ab - ubits(ub & 0xFFFF0000u);
      hw[half] = (ua >> 16) | (ub & 0xFFFF0000u);
      lw[half] = (fbits(la) >> 16) | (fbits(lb) & 0xFFFF0000u);
    }
    int iw = i ^ (((i >> 4) & 7) << 1);   // swizzle (uint2 idx bits 1-3 ^= colpair)
    ((uint2*)sin0)[iw] = make_uint2(hw[0], hw[1]);
    ((uint2*)sin1)[iw] = make_uint2(lw[0], lw[1]);
  }
  __syncthreads();
  int w = tid >> 6, lane = tid & 63, g = lane >> 4, ln = lane & 15;
  int oct = w;
  int rowb[5], colb[5];
#pragma unroll
  for (int j = 0; j < 5; ++j) {
    int p = j * 16 + ln; if (p > 71) p = 71;
    int ohl = p / 18, ow = p - 18 * ohl;
    rowb[j] = 2 * ohl; colb[j] = 2 * ow;
  }
  f32x4 z4 = {0.f, 0.f, 0.f, 0.f};
  f32x4 acc[5];
#pragma unroll
  for (int j = 0; j < 5; ++j) acc[j] = z4;
#pragma unroll
  for (int s = 0; s < 16; ++s) {
    int kh = s >> 2, kw = s & 3;
    bf16x8 bh = *(const bf16x8*)&wfh[oct * 8192 + s * 512 + lane * 8];
    bf16x8 bl = *(const bf16x8*)&wfl[oct * 8192 + s * 512 + lane * 8];
#pragma unroll
    for (int j = 0; j < 5; ++j) {
      int colpix = (rowb[j] + kh) * 39 + colb[j] + kw;
      int off = colpix * 32 + g * 8;
      off ^= ((colpix >> 1) & 7) << 3;   // swizzle
      bf16x8 ah = *(const bf16x8*)&sin0[off];
      bf16x8 al = *(const bf16x8*)&sin1[off];
      acc[j] = mfma3(ah, al, bh, bl, acc[j]);
    }
  }
  int oc = oct * 16 + ln;
  float bv = bias[oc];
#pragma unroll
  for (int j = 0; j < 5; ++j) {
#pragma unroll
    for (int r = 0; r < 4; ++r) {
      int po = j * 16 + g * 4 + r;
      if (po < 72) {
        long oi = ((long)b * 288 + (long)ohq * 72 + po) * 64 + oc;
        y2p[oi] = psplit(acc[j][r] + bv);
      }
    }
  }
}

// ---------------- conv3 MFMA (fused BN2+GELU on staging): y2p -> y3p[1024][224][128]
// octile-per-wave: wave w owns octiles 2w, 2w+1; all 7 row-jobs per wave.
__global__ __launch_bounds__(256, 3) void k_conv3m(const u32* __restrict__ y2p,
    const u16* __restrict__ wfh, const u16* __restrict__ wfl,
    const float* __restrict__ scale, const float* __restrict__ shift,
    const float* __restrict__ bias, u32* __restrict__ y3p)
{
  __shared__ __align__(16) u16 sin0[10368], sin1[10368];  // [9 rows][18 cols][64 c]
  __shared__ float sc[64], shf[64];
  int hh = blockIdx.x, b = blockIdx.y, tid = threadIdx.x;
  if (tid < 64) { sc[tid] = scale[tid]; shf[tid] = shift[tid]; }
  __syncthreads();
  long sb = ((long)b * 288 + (long)hh * 126) * 64;
  const uint4* srcP = (const uint4*)(y2p + sb);
  for (int i = tid; i < 2592; i += 256) {
    uint4 p4 = srcP[i];
    int cb = (i & 15) * 4;
    u32 hw[2], lw[2];
    u32 pe[4] = { p4.x, p4.y, p4.z, p4.w };
#pragma unroll
    for (int half = 0; half < 2; ++half) {
      float va = punp(pe[half * 2 + 0]);
      float vb = punp(pe[half * 2 + 1]);
      float aa = gelu_f(va * sc[cb + half * 2 + 0] + shf[cb + half * 2 + 0]);
      float ab = gelu_f(vb * sc[cb + half * 2 + 1] + shf[cb + half * 2 + 1]);
      u32 ua = fbits(aa), ub = fbits(ab);
      float la = aa - ubits(ua & 0xFFFF0000u);
      float lb = ab - ubits(ub & 0xFFFF0000u);
      hw[half] = (ua >> 16) | (ub & 0xFFFF0000u);
      lw[half] = (fbits(la) >> 16) | (fbits(lb) & 0xFFFF0000u);
    }
    int iw = i ^ (((i >> 4) & 7) << 1);   // swizzle (uint2 idx bits 1-3 ^= colpix)
    ((uint2*)sin0)[iw] = make_uint2(hw[0], hw[1]);
    ((uint2*)sin1)[iw] = make_uint2(lw[0], lw[1]);
  }
  __syncthreads();
  int w = tid >> 6, lane = tid & 63, g = lane >> 4, ln = lane & 15;
  int oct0 = w * 2;
  f32x4 z4 = {0.f, 0.f, 0.f, 0.f};
  f32x4 acc[7][2];
#pragma unroll
  for (int j = 0; j < 7; ++j) { acc[j][0] = z4; acc[j][1] = z4; }
#pragma unroll 6
  for (int s = 0; s < 18; ++s) {
    const int kh = s / 6, rm = s % 6;
    const int kw = rm >> 1, ch = rm & 1;
    bf16x8 bh0 = *(const bf16x8*)&wfh[oct0 * 9216 + s * 512 + lane * 8];
    bf16x8 bl0 = *(const bf16x8*)&wfl[oct0 * 9216 + s * 512 + lane * 8];
    bf16x8 bh1 = *(const bf16x8*)&wfh[(oct0 + 1) * 9216 + s * 512 + lane * 8];
    bf16x8 bl1 = *(const bf16x8*)&wfl[(oct0 + 1) * 9216 + s * 512 + lane * 8];
#pragma unroll
    for (int j = 0; j < 7; ++j) {
      int colpix = (j + kh) * 18 + ln + kw;
      int off = colpix * 64 + ch * 32 + g * 8;
      off ^= (colpix & 7) << 3;   // swizzle
      bf16x8 ah = *(const bf16x8*)&sin0[off];
      bf16x8 al = *(const bf16x8*)&sin1[off];
      acc[j][0] = mfma3(ah, al, bh0, bl0, acc[j][0]);
      acc[j][1] = mfma3(ah, al, bh1, bl1, acc[j][1]);
    }
  }
#pragma unroll
  for (int j = 0; j < 7; ++j) {
#pragma unroll
    for (int o2 = 0; o2 < 2; ++o2) {
      int oc = (oct0 + o2) * 16 + ln;
      float bv = bias[oc];
#pragma unroll
      for (int r = 0; r < 4; ++r) {
        int owo = g * 4 + r;
        long oi = ((long)b * 224 + (hh * 7 + j) * 16 + owo) * 128 + oc;
        y3p[oi] = psplit(acc[j][o2][r] + bv);
      }
    }
  }
}

// ---------------- BN stats over packed channels-last ----------------
__global__ __launch_bounds__(256) void k_bnstat(const u32* __restrict__ pk,
    float* __restrict__ sums, int C, long npix)
{
  int half = C >> 1;
  int cp = threadIdx.x % half;
  int rl = threadIdx.x / half;
  int rpi = 256 / half;
  long chunk = (npix + gridDim.x - 1) / gridDim.x;
  long p0 = (long)blockIdx.x * chunk;
  long p1 = p0 + chunk; if (p1 > npix) p1 = npix;
  float s1a = 0.f, s1b = 0.f, s2a = 0.f, s2b = 0.f;
  for (long p = p0 + rl; p < p1; p += rpi) {
    uint2 pu = *(const uint2*)(pk + p * C + cp * 2);
    float v0 = punp(pu.x);
    float v1 = punp(pu.y);
    s1a += v0; s2a += v0 * v0; s1b += v1; s2b += v1 * v1;
  }
  __shared__ float bs1[128], bs2[128];
  for (int i = threadIdx.x; i < C; i += 256) { bs1[i] = 0.f; bs2[i] = 0.f; }
  __syncthreads();
  atomicAdd(&bs1[2 * cp], s1a); atomicAdd(&bs1[2 * cp + 1], s1b);
  atomicAdd(&bs2[2 * cp], s2a); atomicAdd(&bs2[2 * cp + 1], s2b);
  __syncthreads();
  if (threadIdx.x < C) {
    atomicAdd(&sums[threadIdx.x], bs1[threadIdx.x]);
    atomicAdd(&sums[C + threadIdx.x], bs2[threadIdx.x]);
  }
}

__global__ void k_bn_finalize(const float* __restrict__ sums, const float* __restrict__ g,
    const float* __restrict__ b, float* __restrict__ scale, float* __restrict__ shift,
    int C, float invN)
{
  int c = threadIdx.x;
  if (c < C) {
    float m = sums[c] * invN;
    float var = sums[C + c] * invN - m * m;
    float sc = g[c] * rsqrtf(var + 1e-5f);
    scale[c] = sc;
    shift[c] = b[c] - m * sc;
  }
}

// ---------------- BN apply + GELU in-place on packed (y3) ----------------
__global__ __launch_bounds__(256) void k_bnapplyP(u32* __restrict__ pk,
    const float* __restrict__ scale, const float* __restrict__ shift, int C, long nelem)
{
  __shared__ float sc[128], sh[128];
  for (int i = threadIdx.x; i < C; i += 256) { sc[i] = scale[i]; sh[i] = shift[i]; }
  __syncthreads();
  long i0 = ((long)blockIdx.x * 256 + threadIdx.x) * 4;
  long stride = (long)gridDim.x * 1024;
  for (long i = i0; i < nelem; i += stride) {
    uint4 v4 = *(uint4*)(pk + i);
    int cb = (int)(i & (long)(C - 1));
    u32 src[4] = { v4.x, v4.y, v4.z, v4.w };
    u32 r[4];
#pragma unroll
    for (int j = 0; j < 4; ++j) {
      float v = punp(src[j]);
      float a = gelu_f(v * sc[cb + j] + sh[cb + j]);
      r[j] = psplit(a);
    }
    *(uint4*)(pk + i) = make_uint4(r[0], r[1], r[2], r[3]);
  }
}

// ---------------- proj MFMA split-K: y3p tokens x wfp -> part[32][1024][256]
__global__ __launch_bounds__(256, 2) void k_projm(const u32* __restrict__ y3p,
    const u16* __restrict__ bh_g, const u16* __restrict__ bl_g, float* __restrict__ part)
{
  __shared__ __align__(16) u16 Ah[2048], Al[2048];   // [64 tok][32 k]
  __shared__ __align__(16) u16 Bh[8192], Bl[8192];   // [16 oct][512]
  int m0 = blockIdx.x * 64, by = blockIdx.y, tid = threadIdx.x;
  int w = tid >> 6, lane = tid & 63, g = lane >> 4, ln = lane & 15;
  f32x4 z4 = {0.f, 0.f, 0.f, 0.f};
  f32x4 acc[16];
#pragma unroll
  for (int o = 0; o < 16; ++o) acc[o] = z4;
  for (int ks = 0; ks < 28; ++ks) {
    __syncthreads();
    long k0 = ((long)by * 28 + ks) * 32;
    {
      for (int ii = 0; ii < 2; ++ii) {
        int i = tid + ii * 256;
        int row = i >> 3, q = i & 7;
        uint4 p4 = *((const uint4*)(y3p + (long)(m0 + row) * 28672 + k0) + q);
        u32 h01 = (p4.x & 0xFFFFu) | (p4.y << 16);
        u32 l01 = (p4.x >> 16) | (p4.y & 0xFFFF0000u);
        u32 h23 = (p4.z & 0xFFFFu) | (p4.w << 16);
        u32 l23 = (p4.z >> 16) | (p4.w & 0xFFFF0000u);
        ((uint2*)Ah)[i] = make_uint2(h01, h23);
        ((uint2*)Al)[i] = make_uint2(l01, l23);
      }
    }
    int ksg = by * 28 + ks;
#pragma unroll
    for (int ii = 0; ii < 8; ++ii) {
      int i = tid + ii * 256;
      int arr = i >> 10, idx = i & 1023, oct = idx >> 6, r2 = idx & 63;
      const u16* src = arr ? bl_g : bh_g;
      u16* dst = arr ? Bl : Bh;
      ((uint4*)dst)[idx] = *((const uint4*)(src + ((long)oct * 896 + ksg) * 512) + r2);
    }
    __syncthreads();
    bf16x8 a_h = *(const bf16x8*)&Ah[(w * 16 + ln) * 32 + g * 8];
    bf16x8 a_l = *(const bf16x8*)&Al[(w * 16 + ln) * 32 + g * 8];
#pragma unroll
    for (int oct = 0; oct < 16; ++oct) {
      bf16x8 bh = *(const bf16x8*)&Bh[oct * 512 + lane * 8];
      bf16x8 bl = *(const bf16x8*)&Bl[oct * 512 + lane * 8];
      acc[oct] = mfma3(a_h, a_l, bh, bl, acc[oct]);
    }
  }
#pragma unroll
  for (int oct = 0; oct < 16; ++oct) {
    int oc = oct * 16 + ln;
#pragma unroll
    for (int r = 0; r < 4; ++r) {
      int tok = m0 + w * 16 + g * 4 + r;
      part[((long)by * 1024 + tok) * 256 + oc] = acc[oct][r];
    }
  }
}

// ---------------- split-K reduce + bias + LN + GELU (writes f32 h and bf16 h) ----------------
__global__ __launch_bounds__(256) void k_lnred(const float* __restrict__ part,
    const float* __restrict__ pb, const float* __restrict__ g, const float* __restrict__ be,
    float* __restrict__ h, u16* __restrict__ hb)
{
  int b = blockIdx.x, d = threadIdx.x;
  float s = pb[d];
#pragma unroll
  for (int ks = 0; ks < 32; ++ks) s += part[((long)ks * 1024 + b) * 256 + d];
  __shared__ float red[4];
  float t = s;
  for (int o = 32; o; o >>= 1) t += __shfl_xor(t, o);
  if ((d & 63) == 0) red[d >> 6] = t;
  __syncthreads();
  float mean = (red[0] + red[1] + red[2] + red[3]) * (1.f / 256.f);
  __syncthreads();
  float dv = s - mean;
  t = dv * dv;
  for (int o = 32; o; o >>= 1) t += __shfl_xor(t, o);
  if ((d & 63) == 0) red[d >> 6] = t;
  __syncthreads();
  float var = (red[0] + red[1] + red[2] + red[3]) * (1.f / 256.f);
  float hv = gelu_f(g[d] * dv * rsqrtf(var + 1e-5f) + be[d]);
  h[b * 256 + d] = hv;
  hb[b * 256 + d] = f2bf(hv);
}

// ---------------- generic plain-bf16 MFMA GEMM: C[z][M][N] = A[z][M][K] @ Bfrag + bias
__global__ __launch_bounds__(256, 2) void k_gemmb(const u16* __restrict__ A, long aZ, int K,
    const u16* __restrict__ Bf, int noct_tot,
    const float* __restrict__ bias, int biasZ,
    void* __restrict__ C, long cZ, int ldc, int outbf, int act)
{
  __shared__ __align__(16) u16 As[2048];
  __shared__ __align__(16) u16 Bs[8192];
  int m0 = blockIdx.x * 64, nb = blockIdx.y, z = blockIdx.z, tid = threadIdx.x;
  int w = tid >> 6, lane = tid & 63, g = lane >> 4, ln = lane & 15;
  const u16* Az = A + (long)z * aZ;
  int kn = K >> 5;
  f32x4 z4 = {0.f, 0.f, 0.f, 0.f};
  f32x4 acc[16];
#pragma unroll
  for (int o = 0; o < 16; ++o) acc[o] = z4;
  for (int ks = 0; ks < kn; ++ks) {
    __syncthreads();
    {
      int row = tid >> 2, q = tid & 3;
      ((uint4*)As)[tid] = *((const uint4*)(Az + (long)(m0 + row) * K + ks * 32) + q);
    }
#pragma unroll
    for (int ii = 0; ii < 4; ++ii) {
      int i = tid + ii * 256;
      int oct = i >> 6, r2 = i & 63;
      const u16* src = Bf + (((long)z * noct_tot + nb * 16 + oct) * kn + ks) * 512;
      ((uint4*)Bs)[i] = ((const uint4*)src)[r2];
    }
    __syncthreads();
    bf16x8 a = *(const bf16x8*)&As[(w * 16 + ln) * 32 + g * 8];
#pragma unroll
    for (int oct = 0; oct < 16; ++oct) {
      bf16x8 bb = *(const bf16x8*)&Bs[oct * 512 + lane * 8];
      acc[oct] = __builtin_amdgcn_mfma_f32_16x16x32_bf16(a, bb, acc[oct], 0, 0, 0);
    }
  }
#pragma unroll
  for (int oct = 0; oct < 16; ++oct) {
    int n = nb * 256 + oct * 16 + ln;
    float bv = bias[z * biasZ + n];
#pragma unroll
    for (int r = 0; r < 4; ++r) {
      int tok = m0 + w * 16 + g * 4 + r;
      float v = acc[oct][r] + bv;
      if (act) v = gelu_f(v);
      long off = (long)z * cZ + (long)tok * ldc + n;
      if (outbf) ((u16*)C)[off] = f2bf(v);
      else ((float*)C)[off] = v;
    }
  }
}

// ---------------- router ----------------
__global__ __launch_bounds__(64) void k_router(const float* __restrict__ h,
    const float* __restrict__ rw, const float* __restrict__ eb,
    float* __restrict__ wts, int* __restrict__ idx,
    float* __restrict__ pm_sum, float* __restrict__ z_sum)
{
  int b = blockIdx.x, lane = threadIdx.x;
  float4 hv = *(const float4*)(h + b * 256 + lane * 4);
  float logit[8];
#pragma unroll
  for (int e = 0; e < 8; ++e) {
    float4 wv = *(const float4*)(rw + e * 256 + lane * 4);
    float p = hv.x * wv.x + hv.y * wv.y + hv.z * wv.z + hv.w * wv.w;
    for (int o = 32; o; o >>= 1) p += __shfl_xor(p, o);
    logit[e] = p + eb[e];
  }
  float mx = logit[0];
#pragma unroll
  for (int e = 1; e < 8; ++e) mx = fmaxf(mx, logit[e]);
  float pr[8]; float se = 0.f;
#pragma unroll
  for (int e = 0; e < 8; ++e) { pr[e] = expf(logit[e] - mx); se += pr[e]; }
  float inv = 1.f / se;
#pragma unroll
  for (int e = 0; e < 8; ++e) pr[e] *= inv;
  int i0 = 0; float v0 = pr[0];
#pragma unroll
  for (int e = 1; e < 8; ++e) if (pr[e] > v0) { v0 = pr[e]; i0 = e; }
  int i1 = -1; float v1 = -1.f;
#pragma unroll
  for (int e = 0; e < 8; ++e) if (e != i0 && pr[e] > v1) { v1 = pr[e]; i1 = e; }
  if (lane == 0) {
    float ssum = v0 + v1 + 1e-8f;
    wts[2 * b] = v0 / ssum; wts[2 * b + 1] = v1 / ssum;
    idx[2 * b] = i0; idx[2 * b + 1] = i1;
    float zz = 0.f;
#pragma unroll
    for (int e = 0; e < 8; ++e) zz += logit[e] * logit[e];
    atomicAdd(z_sum, zz);
  }
  if (lane < 8) atomicAdd(&pm_sum[lane], pr[lane]);
}

// ---------------- combine + 0.5*shared + final LN ----------------
__global__ __launch_bounds__(256) void k_combine_ln(const float* __restrict__ eout,
    const float* __restrict__ sharedB, const float* __restrict__ wts, const int* __restrict__ idx,
    const float* __restrict__ g, const float* __restrict__ bb, float* __restrict__ out)
{
  int b = blockIdx.x, d = threadIdx.x;
  float w0 = wts[2 * b], w1 = wts[2 * b + 1];
  int i0 = idx[2 * b], i1 = idx[2 * b + 1];
  float val = w0 * eout[(long)i0 * 262144 + b * 256 + d]
            + w1 * eout[(long)i1 * 262144 + b * 256 + d]
            + 0.5f * sharedB[b * 256 + d];
  __shared__ float red[4];
  float s = val;
  for (int o = 32; o; o >>= 1) s += __shfl_xor(s, o);
  if ((d & 63) == 0) red[d >> 6] = s;
  __syncthreads();
  float mean = (red[0] + red[1] + red[2] + red[3]) * (1.f / 256.f);
  __syncthreads();
  float dv = val - mean;
  s = dv * dv;
  for (int o = 32; o; o >>= 1) s += __shfl_xor(s, o);
  if ((d & 63) == 0) red[d >> 6] = s;
  __syncthreads();
  float var = (red[0] + red[1] + red[2] + red[3]) * (1.f / 256.f);
  out[b * 256 + d] = g[d] * dv * rsqrtf(var + 1e-5f) + bb[d];
}

// ---------------- aux losses ----------------
__global__ void k_losses(const float* __restrict__ pm_sum, const float* __restrict__ z_sum,
                         float* __restrict__ out)
{
  if (threadIdx.x == 0 && blockIdx.x == 0) {
    float lb = 0.f;
    for (int e = 0; e < 8; ++e) {
      float pm = pm_sum[e] * (1.f / 1024.f);
      float dd = pm - 0.125f;
      lb += dd * dd;
    }
    out[262144] = lb * 8.f;
    out[262145] = z_sum[0] * (1.f / 8192.f) * 0.001f;
  }
}

extern "C" void kernel_launch(void* const* d_in, const int* in_sizes, int n_in,
                              void* d_out, int out_size, void* d_ws, size_t ws_size,
                              hipStream_t stream)
{
  const float* x     = (const float*)d_in[0];
  const float* c1w   = (const float*)d_in[1];
  const float* c1b   = (const float*)d_in[2];
  const float* bn1g  = (const float*)d_in[3];
  const float* bn1b  = (const float*)d_in[4];
  const float* c2w   = (const float*)d_in[5];
  const float* c2b   = (const float*)d_in[6];
  const float* bn2g  = (const float*)d_in[7];
  const float* bn2b  = (const float*)d_in[8];
  const float* c3w   = (const float*)d_in[9];
  const float* c3b   = (const float*)d_in[10];
  const float* bn3g  = (const float*)d_in[11];
  const float* bn3b  = (const float*)d_in[12];
  const float* projw = (const float*)d_in[13];
  const float* projb = (const float*)d_in[14];
  const float* lng   = (const float*)d_in[15];
  const float* lnb   = (const float*)d_in[16];
  const float* rw    = (const float*)d_in[17];
  const float* ebias = (const float*)d_in[18];
  const float* ew1   = (const float*)d_in[19];
  const float* eb1   = (const float*)d_in[20];
  const float* ew2   = (const float*)d_in[21];
  const float* eb2   = (const float*)d_in[22];
  const float* sw1   = (const float*)d_in[23];
  const float* sb1   = (const float*)d_in[24];
  const float* sw2   = (const float*)d_in[25];
  const float* sb2   = (const float*)d_in[26];
  const float* mlng  = (const float*)d_in[27];
  const float* mlnb  = (const float*)d_in[28];
  float* out = (float*)d_out;

  char* W = (char*)d_ws;
  u32* y1p = (u32*)(W + 0);              // 178,913,280 B
  u32* y2p = (u32*)(W + 178913280L);     // 75,497,472 B
  u32* y3p = (u32*)(W + 0);              // 117,440,512 B (alias dead y1)
  u16* wfph = (u16*)(W + 254410752L);
  u16* wfpl = (u16*)(W + 269090816L);
  u16* wf1h = (u16*)(W + 283770880L);
  u16* wf1l = (u16*)(W + 283787264L);
  u16* wf2h = (u16*)(W + 283803648L);
  u16* wf2l = (u16*)(W + 283869184L);
  u16* wf3h = (u16*)(W + 283934720L);
  u16* wf3l = (u16*)(W + 284082176L);
  float* stats = (float*)(W + 284229632L);
  float* wtsb  = (float*)(W + 284233728L);
  int*   idxb  = (int*)(W + 284241920L);
  float* hbuf  = (float*)(W + 284250112L);
  float* shB   = (float*)(W + 286347264L);
  // tail region inside the y2p span — all used only after conv3m completes
  float* part  = (float*)(W + 178913280L);  // 33,554,432 B
  u16* hid     = (u16*)(W + 212467712L);    // 8,388,608 B
  u16* ewf1    = (u16*)(W + 220856320L);    // 2,097,152 B
  u16* ewf2    = (u16*)(W + 222953472L);    // 2,097,152 B
  u16* swf1    = (u16*)(W + 225050624L);    // 131,072 B
  u16* swf2    = (u16*)(W + 225181696L);    // 131,072 B
  float* eoutB = (float*)(W + 225312768L);  // 8,388,608 B
  u16* hbufb   = (u16*)(W + 233701376L);    // 524,288 B
  u16* sh1b    = (u16*)(W + 234225664L);    // 524,288 B

  float* sums1 = stats;        float* scale1 = stats + 512; float* shift1 = stats + 544;
  float* sums2 = stats + 64;   float* scale2 = stats + 576; float* shift2 = stats + 640;
  float* sums3 = stats + 192;  float* scale3 = stats + 704; float* shift3 = stats + 832;
  float* pm    = stats + 448;  float* zsum   = stats + 456;

  dim3 blk(256);
  k_zero<<<dim3(2), blk, 0, stream>>>(stats, 512);
  k_wprep1<<<dim3(32), blk, 0, stream>>>(c1w, wf1h, wf1l);
  k_wprep2<<<dim3(128), blk, 0, stream>>>(c2w, wf2h, wf2l);
  k_wprep3<<<dim3(288), blk, 0, stream>>>(c3w, wf3h, wf3l);
  k_wprepP<<<dim3(32, 16), blk, 0, stream>>>(projw, wfph, wfpl);

  k_conv1m<<<dim3(18, 1024), blk, 0, stream>>>(x, wf1h, wf1l, c1b, y1p);
  k_bnstat<<<dim3(512), blk, 0, stream>>>(y1p, sums1, 32, 1397760L);
  k_bn_finalize<<<1, 32, 0, stream>>>(sums1, bn1g, bn1b, scale1, shift1, 32, 1.f / 1397760.f);

  k_conv2m<<<dim3(4, 1024), blk, 0, stream>>>(y1p, wf2h, wf2l, scale1, shift1, c2b, y2p);
  k_bnstat<<<dim3(512), blk, 0, stream>>>(y2p, sums2, 64, 294912L);
  k_bn_finalize<<<1, 64, 0, stream>>>(sums2, bn2g, bn2b, scale2, shift2, 64, 1.f / 294912.f);

  k_conv3m<<<dim3(2, 1024), blk, 0, stream>>>(y2p, wf3h, wf3l, scale2, shift2, c3b, y3p);
  k_bnstat<<<dim3(512), blk, 0, stream>>>(y3p, sums3, 128, 229376L);
  k_bn_finalize<<<1, 128, 0, stream>>>(sums3, bn3g, bn3b, scale3, shift3, 128, 1.f / 229376.f);
  k_bnapplyP<<<dim3(2048), blk, 0, stream>>>(y3p, scale3, shift3, 128, 29360128L);

  // expert/shared weight preps (y2p region is dead now)
  k_wprepG<<<dim3(4096), blk, 0, stream>>>(ew1, ewf1, 512, 256, 1048576L);
  k_wprepG<<<dim3(4096), blk, 0, stream>>>(ew2, ewf2, 256, 512, 1048576L);
  k_wprepG<<<dim3(256), blk, 0, stream>>>(sw1, swf1, 256, 256, 65536L);
  k_wprepG<<<dim3(256), blk, 0, stream>>>(sw2, swf2, 256, 256, 65536L);

  k_projm<<<dim3(16, 32), blk, 0, stream>>>(y3p, wfph, wfpl, part);
  k_lnred<<<dim3(1024), blk, 0, stream>>>(part, projb, lng, lnb, hbuf, hbufb);

  k_router<<<dim3(1024), dim3(64), 0, stream>>>(hbuf, rw, ebias, wtsb, idxb, pm, zsum);

  // experts (dense) + shared, plain bf16 MFMA
  k_gemmb<<<dim3(16, 2, 8), blk, 0, stream>>>(hbufb, 0L, 256, ewf1, 32, eb1, 512,
                                              (void*)hid, 524288L, 512, 1, 1);
  k_gemmb<<<dim3(16, 1, 8), blk, 0, stream>>>(hid, 524288L, 512, ewf2, 16, eb2, 256,
                                              (void*)eoutB, 262144L, 256, 0, 0);
  k_gemmb<<<dim3(16, 1, 1), blk, 0, stream>>>(hbufb, 0L, 256, swf1, 16, sb1, 0,
                                              (void*)sh1b, 0L, 256, 1, 1);
  k_gemmb<<<dim3(16, 1, 1), blk, 0, stream>>>(sh1b, 0L, 256, swf2, 16, sb2, 0,
                                              (void*)shB, 0L, 256, 0, 0);

  k_combine_ln<<<dim3(1024), blk, 0, stream>>>(eoutB, shB, wtsb, idxb, mlng, mlnb, out);
  k_losses<<<1, 64, 0, stream>>>(pm, zsum, out);
}

// Round 9
// 967.330 us; speedup vs baseline: 1.4208x; 1.0100x over previous
//
#include <hip/hip_runtime.h>
#include <hip/hip_bf16.h>
#include <math.h>

typedef unsigned short u16;
typedef unsigned int u32;
typedef __attribute__((ext_vector_type(8))) short bf16x8;
typedef __attribute__((ext_vector_type(4))) float f32x4;

#define DEV __device__ __forceinline__

DEV float gelu_f(float x) { return 0.5f * x * (1.0f + erff(x * 0.70710678118654752f)); }
DEV u16 f2bf(float f) { u32 u = __builtin_bit_cast(u32, f); u = (u + 0x7FFFu + ((u >> 16) & 1u)) >> 16; return (u16)u; }
DEV float bf2f(u16 h) { return __builtin_bit_cast(float, (u32)h << 16); }
DEV u32 fbits(float f) { return __builtin_bit_cast(u32, f); }
DEV float ubits(u32 u) { return __builtin_bit_cast(float, u); }
// packed format: p = hi_u16 | (lo_u16 << 16), v ~= bf(hi) + bf(lo), trunc split (2^-16)
DEV u32 psplit(float v) {
  u32 u = fbits(v);
  float lo = v - ubits(u & 0xFFFF0000u);
  return (u >> 16) | (fbits(lo) & 0xFFFF0000u);
}
DEV float punp(u32 p) { return ubits(p << 16) + ubits(p & 0xFFFF0000u); }
// 3-term split product: a*b ~= ah*bh + ah*bl + al*bh
DEV f32x4 mfma3(bf16x8 ah, bf16x8 al, bf16x8 bh, bf16x8 bl, f32x4 c) {
  c = __builtin_amdgcn_mfma_f32_16x16x32_bf16(al, bh, c, 0, 0, 0);
  c = __builtin_amdgcn_mfma_f32_16x16x32_bf16(ah, bl, c, 0, 0, 0);
  c = __builtin_amdgcn_mfma_f32_16x16x32_bf16(ah, bh, c, 0, 0, 0);
  return c;
}

// ---------------- zero stats ----------------
__global__ void k_zero(float* p, int n) {
  int i = blockIdx.x * blockDim.x + threadIdx.x;
  if (i < n) p[i] = 0.f;
}

// ---------------- conv weight frag preps: layout [((oct*NS + s)*64 + lane)*8 + j] ----------------
__global__ void k_wprep1(const float* __restrict__ w, u16* __restrict__ wh, u16* __restrict__ wl) {
  int idx = blockIdx.x * 256 + threadIdx.x; if (idx >= 8192) return;
  int j = idx & 7, lane = (idx >> 3) & 63, s = (idx >> 9) & 7, oct = idx >> 12;
  int oc = oct * 16 + (lane & 15);
  int kl = ((lane >> 4) << 3) + j;
  int kw = kl >> 2, c = kl & 3, kh = s;
  float v = w[((oc * 4 + c) * 8 + kh) * 8 + kw];
  u16 h = f2bf(v); wh[idx] = h; wl[idx] = f2bf(v - bf2f(h));
}
__global__ void k_wprep2(const float* __restrict__ w, u16* __restrict__ wh, u16* __restrict__ wl) {
  int idx = blockIdx.x * 256 + threadIdx.x; if (idx >= 32768) return;
  int j = idx & 7, lane = (idx >> 3) & 63, s = (idx >> 9) & 15, oct = idx >> 13;
  int oc = oct * 16 + (lane & 15);
  int k = s * 32 + ((lane >> 4) << 3) + j;
  int kh = k >> 7, kw = (k >> 5) & 3, c = k & 31;
  float v = w[((oc * 32 + c) * 4 + kh) * 4 + kw];
  u16 h = f2bf(v); wh[idx] = h; wl[idx] = f2bf(v - bf2f(h));
}
__global__ void k_wprep3(const float* __restrict__ w, u16* __restrict__ wh, u16* __restrict__ wl) {
  int idx = blockIdx.x * 256 + threadIdx.x; if (idx >= 73728) return;
  int j = idx & 7, lane = (idx >> 3) & 63, rest = idx >> 9;
  int s = rest % 18, oct = rest / 18;
  int oc = oct * 16 + (lane & 15);
  int k = s * 32 + ((lane >> 4) << 3) + j;
  int kh = k / 192, r = k - kh * 192;
  int kw = r >> 6, c = r & 63;
  float v = w[((oc * 64 + c) * 3 + kh) * 3 + kw];
  u16 h = f2bf(v); wh[idx] = h; wl[idx] = f2bf(v - bf2f(h));
}
// proj weight prep, LDS-transpose tiled
__global__ __launch_bounds__(256) void k_wprepP(const float* __restrict__ w,
    u16* __restrict__ wh, u16* __restrict__ wl)
{
  __shared__ float tile[16][4][225];
  int q = blockIdx.x, oct = blockIdx.y, tid = threadIdx.x;
  for (int i = tid; i < 3584; i += 256) {
    int n = i / 224, rem = i % 224, e = rem / 56, f4 = rem % 56;
    float4 v = *(const float4*)(w + (long)(oct * 16 + n) * 28672 + (4 * q + e) * 224 + f4 * 4);
    tile[n][e][f4 * 4 + 0] = v.x; tile[n][e][f4 * 4 + 1] = v.y;
    tile[n][e][f4 * 4 + 2] = v.z; tile[n][e][f4 * 4 + 3] = v.w;
  }
  __syncthreads();
  int g = (q >> 1) & 3, j0 = 4 * (q & 1), sgb = q >> 3;
  for (int o = tid; o < 3584; o += 256) {
    int pix = o >> 4, ln = o & 15;
    u16 hs[4], ls[4];
#pragma unroll
    for (int e = 0; e < 4; ++e) {
      float v = tile[ln][e][pix];
      u16 h = f2bf(v); hs[e] = h; ls[e] = f2bf(v - bf2f(h));
    }
    long base = (((long)oct * 896 + pix * 4 + sgb) * 64 + g * 16 + ln) * 8 + j0;
    *(uint2*)(wh + base) = make_uint2((u32)hs[0] | ((u32)hs[1] << 16), (u32)hs[2] | ((u32)hs[3] << 16));
    *(uint2*)(wl + base) = make_uint2((u32)ls[0] | ((u32)ls[1] << 16), (u32)ls[2] | ((u32)ls[3] << 16));
  }
}
// generic plain-bf16 frag prep for expert/shared weights W[Z][N][K]
__global__ void k_wprepG(const float* __restrict__ w, u16* __restrict__ wf,
                         int N, int K, long total)
{
  long idx = (long)blockIdx.x * 256 + threadIdx.x; if (idx >= total) return;
  int j = (int)(idx & 7); int lane = (int)((idx >> 3) & 63); long rest = idx >> 9;
  int kn = K >> 5;
  int s = (int)(rest % kn); long rest2 = rest / kn;
  int noct = N >> 4;
  int oct = (int)(rest2 % noct); int z = (int)(rest2 / noct);
  int n = oct * 16 + (lane & 15);
  int k = s * 32 + ((lane >> 4) << 3) + j;
  wf[idx] = f2bf(w[((long)z * N + n) * K + k]);
}

// ---------------- conv1 MFMA: x[1024,4,144,160] s4 8x8 -> y1p[1024][1365][32] packed
// 4 output rows per block (20 staged rows, 51KB LDS), 12 jobs = 3/wave balanced.
// LDS swizzle: byte ^= ((col>>4)&3)<<4 (col = pixel column).
__global__ __launch_bounds__(256, 3) void k_conv1m(const float* __restrict__ x,
    const u16* __restrict__ wfh, const u16* __restrict__ wfl,
    const float* __restrict__ bias, u32* __restrict__ y1p)
{
  __shared__ __align__(16) u16 sin0[12800], sin1[12800];   // [20 rows][160 cols][4 c]
  int ohp = blockIdx.x, b = blockIdx.y, tid = threadIdx.x;
  int row0 = ohp * 16;
  for (int i = tid; i < 1600; i += 256) {
    int cp = i / 800, rem = i - cp * 800, r = rem / 40, q = rem - r * 40;
    int grow = row0 + r;
    float4 v0 = make_float4(0.f, 0.f, 0.f, 0.f), v1 = v0;
    if (grow < 144) {
      long base = ((long)b * 4 + 2 * cp) * 23040 + (long)grow * 160 + q * 4;
      v0 = *(const float4*)(x + base);
      v1 = *(const float4*)(x + base + 23040);
    }
    const float* a0 = (const float*)&v0;
    const float* a1 = (const float*)&v1;
#pragma unroll
    for (int m = 0; m < 4; ++m) {
      float f0 = a0[m], f1 = a1[m];
      u32 u0 = fbits(f0), u1 = fbits(f1);
      u32 hh = (u0 >> 16) | (u1 & 0xFFFF0000u);
      float l0 = f0 - ubits(u0 & 0xFFFF0000u);
      float l1 = f1 - ubits(u1 & 0xFFFF0000u);
      u32 ll = (fbits(l0) >> 16) | (fbits(l1) & 0xFFFF0000u);
      int col = q * 4 + m;
      int idx = r * 320 + col * 2 + cp;
      idx ^= ((col >> 4) & 3) << 2;   // swizzle
      ((u32*)sin0)[idx] = hh;
      ((u32*)sin1)[idx] = ll;
    }
  }
  __syncthreads();
  int w = tid >> 6, lane = tid & 63, g = lane >> 4, ln = lane & 15;
  // 12 jobs: j = w + 4*jj, jj in [0,3); ohl = j/3, owt = j%3
  int ohls[3], owcs[3];
#pragma unroll
  for (int jj = 0; jj < 3; ++jj) {
    int j = w + 4 * jj;
    ohls[jj] = j / 3;
    int owc = (j % 3) * 16 + ln; if (owc > 38) owc = 38;
    owcs[jj] = owc;
  }
  f32x4 z4 = {0.f, 0.f, 0.f, 0.f};
  f32x4 acc[3][2];
#pragma unroll
  for (int jj = 0; jj < 3; ++jj) { acc[jj][0] = z4; acc[jj][1] = z4; }
#pragma unroll
  for (int kh = 0; kh < 8; ++kh) {
    bf16x8 bh0 = *(const bf16x8*)&wfh[kh * 512 + lane * 8];
    bf16x8 bl0 = *(const bf16x8*)&wfl[kh * 512 + lane * 8];
    bf16x8 bh1 = *(const bf16x8*)&wfh[4096 + kh * 512 + lane * 8];
    bf16x8 bl1 = *(const bf16x8*)&wfl[4096 + kh * 512 + lane * 8];
#pragma unroll
    for (int jj = 0; jj < 3; ++jj) {
      int col = owcs[jj] * 4 + g * 2;
      int off = (4 * ohls[jj] + kh) * 640 + col * 4;
      off ^= ((col >> 4) & 3) << 3;   // swizzle
      bf16x8 ah = *(const bf16x8*)&sin0[off];
      bf16x8 al = *(const bf16x8*)&sin1[off];
      acc[jj][0] = mfma3(ah, al, bh0, bl0, acc[jj][0]);
      acc[jj][1] = mfma3(ah, al, bh1, bl1, acc[jj][1]);
    }
  }
#pragma unroll
  for (int jj = 0; jj < 3; ++jj) {
    int j = w + 4 * jj;
    int ohl = j / 3, owt = j % 3;
    int oh = 4 * ohp + ohl;
    if (oh >= 35) continue;
#pragma unroll
    for (int oct = 0; oct < 2; ++oct) {
      int oc = oct * 16 + ln;
      float bv = bias[oc];
#pragma unroll
      for (int r = 0; r < 4; ++r) {
        int owo = owt * 16 + g * 4 + r;
        if (owo < 39) {
          long oi = ((long)b * 1365 + oh * 39 + owo) * 32 + oc;
          y1p[oi] = psplit(acc[jj][oct][r] + bv);
        }
      }
    }
  }
}

// ---------------- conv2 MFMA (fused BN1+GELU on staging): y1p -> y2p[1024][288][64]
// octile-per-wave: wave w owns octile w; all 5 pixel-tiles per wave.
__global__ __launch_bounds__(256, 3) void k_conv2m(const u32* __restrict__ y1p,
    const u16* __restrict__ wfh, const u16* __restrict__ wfl,
    const float* __restrict__ scale, const float* __restrict__ shift,
    const float* __restrict__ bias, u32* __restrict__ y2p)
{
  __shared__ __align__(16) u16 sin0[12480], sin1[12480];  // [10 rows][39 cols][32 c]
  __shared__ float sc[32], shf[32];
  int ohq = blockIdx.x, b = blockIdx.y, tid = threadIdx.x;
  if (tid < 32) { sc[tid] = scale[tid]; shf[tid] = shift[tid]; }
  __syncthreads();
  long sb = ((long)b * 1365 + (long)ohq * 312) * 32;
  const uint4* srcP = (const uint4*)(y1p + sb);
  for (int i = tid; i < 3120; i += 256) {
    uint4 p4 = srcP[i];
    int cb = (i & 7) * 4;
    u32 hw[2], lw[2];
    u32 pe[4] = { p4.x, p4.y, p4.z, p4.w };
#pragma unroll
    for (int half = 0; half < 2; ++half) {
      float va = punp(pe[half * 2 + 0]);
      float vb = punp(pe[half * 2 + 1]);
      float aa = gelu_f(va * sc[cb + half * 2 + 0] + shf[cb + half * 2 + 0]);
      float ab = gelu_f(vb * sc[cb + half * 2 + 1] + shf[cb + half * 2 + 1]);
      u32 ua = fbits(aa), ub = fbits(ab);
      float la = aa - ubits(ua & 0xFFFF0000u);
      float lb = ab - ubits(ub & 0xFFFF0000u);
      hw[half] = (ua >> 16) | (ub & 0xFFFF0000u);
      lw[half] = (fbits(la) >> 16) | (fbits(lb) & 0xFFFF0000u);
    }
    int iw = i ^ (((i >> 4) & 7) << 1);   // swizzle (uint2 idx bits 1-3 ^= colpair)
    ((uint2*)sin0)[iw] = make_uint2(hw[0], hw[1]);
    ((uint2*)sin1)[iw] = make_uint2(lw[0], lw[1]);
  }
  __syncthreads();
  int w = tid >> 6, lane = tid & 63, g = lane >> 4, ln = lane & 15;
  int oct = w;
  int rowb[5], colb[5];
#pragma unroll
  for (int j = 0; j < 5; ++j) {
    int p = j * 16 + ln; if (p > 71) p = 71;
    int ohl = p / 18, ow = p - 18 * ohl;
    rowb[j] = 2 * ohl; colb[j] = 2 * ow;
  }
  f32x4 z4 = {0.f, 0.f, 0.f, 0.f};
  f32x4 acc[5];
#pragma unroll
  for (int j = 0; j < 5; ++j) acc[j] = z4;
#pragma unroll
  for (int s = 0; s < 16; ++s) {
    int kh = s >> 2, kw = s & 3;
    bf16x8 bh = *(const bf16x8*)&wfh[oct * 8192 + s * 512 + lane * 8];
    bf16x8 bl = *(const bf16x8*)&wfl[oct * 8192 + s * 512 + lane * 8];
#pragma unroll
    for (int j = 0; j < 5; ++j) {
      int colpix = (rowb[j] + kh) * 39 + colb[j] + kw;
      int off = colpix * 32 + g * 8;
      off ^= ((colpix >> 1) & 7) << 3;   // swizzle
      bf16x8 ah = *(const bf16x8*)&sin0[off];
      bf16x8 al = *(const bf16x8*)&sin1[off];
      acc[j] = mfma3(ah, al, bh, bl, acc[j]);
    }
  }
  int oc = oct * 16 + ln;
  float bv = bias[oc];
#pragma unroll
  for (int j = 0; j < 5; ++j) {
#pragma unroll
    for (int r = 0; r < 4; ++r) {
      int po = j * 16 + g * 4 + r;
      if (po < 72) {
        long oi = ((long)b * 288 + (long)ohq * 72 + po) * 64 + oc;
        y2p[oi] = psplit(acc[j][r] + bv);
      }
    }
  }
}

// ---------------- conv3 MFMA (fused BN2+GELU on staging): y2p -> y3p[1024][224][128]
// octile-per-wave: wave w owns octiles 2w, 2w+1; all 7 row-jobs per wave.
__global__ __launch_bounds__(256, 3) void k_conv3m(const u32* __restrict__ y2p,
    const u16* __restrict__ wfh, const u16* __restrict__ wfl,
    const float* __restrict__ scale, const float* __restrict__ shift,
    const float* __restrict__ bias, u32* __restrict__ y3p)
{
  __shared__ __align__(16) u16 sin0[10368], sin1[10368];  // [9 rows][18 cols][64 c]
  __shared__ float sc[64], shf[64];
  int hh = blockIdx.x, b = blockIdx.y, tid = threadIdx.x;
  if (tid < 64) { sc[tid] = scale[tid]; shf[tid] = shift[tid]; }
  __syncthreads();
  long sb = ((long)b * 288 + (long)hh * 126) * 64;
  const uint4* srcP = (const uint4*)(y2p + sb);
  for (int i = tid; i < 2592; i += 256) {
    uint4 p4 = srcP[i];
    int cb = (i & 15) * 4;
    u32 hw[2], lw[2];
    u32 pe[4] = { p4.x, p4.y, p4.z, p4.w };
#pragma unroll
    for (int half = 0; half < 2; ++half) {
      float va = punp(pe[half * 2 + 0]);
      float vb = punp(pe[half * 2 + 1]);
      float aa = gelu_f(va * sc[cb + half * 2 + 0] + shf[cb + half * 2 + 0]);
      float ab = gelu_f(vb * sc[cb + half * 2 + 1] + shf[cb + half * 2 + 1]);
      u32 ua = fbits(aa), ub = fbits(ab);
      float la = aa - ubits(ua & 0xFFFF0000u);
      float lb = ab - ubits(ub & 0xFFFF0000u);
      hw[half] = (ua >> 16) | (ub & 0xFFFF0000u);
      lw[half] = (fbits(la) >> 16) | (fbits(lb) & 0xFFFF0000u);
    }
    int iw = i ^ (((i >> 4) & 7) << 1);   // swizzle (uint2 idx bits 1-3 ^= colpix)
    ((uint2*)sin0)[iw] = make_uint2(hw[0], hw[1]);
    ((uint2*)sin1)[iw] = make_uint2(lw[0], lw[1]);
  }
  __syncthreads();
  int w = tid >> 6, lane = tid & 63, g = lane >> 4, ln = lane & 15;
  int oct0 = w * 2;
  f32x4 z4 = {0.f, 0.f, 0.f, 0.f};
  f32x4 acc[7][2];
#pragma unroll
  for (int j = 0; j < 7; ++j) { acc[j][0] = z4; acc[j][1] = z4; }
#pragma unroll 6
  for (int s = 0; s < 18; ++s) {
    const int kh = s / 6, rm = s % 6;
    const int kw = rm >> 1, ch = rm & 1;
    bf16x8 bh0 = *(const bf16x8*)&wfh[oct0 * 9216 + s * 512 + lane * 8];
    bf16x8 bl0 = *(const bf16x8*)&wfl[oct0 * 9216 + s * 512 + lane * 8];
    bf16x8 bh1 = *(const bf16x8*)&wfh[(oct0 + 1) * 9216 + s * 512 + lane * 8];
    bf16x8 bl1 = *(const bf16x8*)&wfl[(oct0 + 1) * 9216 + s * 512 + lane * 8];
#pragma unroll
    for (int j = 0; j < 7; ++j) {
      int colpix = (j + kh) * 18 + ln + kw;
      int off = colpix * 64 + ch * 32 + g * 8;
      off ^= (colpix & 7) << 3;   // swizzle
      bf16x8 ah = *(const bf16x8*)&sin0[off];
      bf16x8 al = *(const bf16x8*)&sin1[off];
      acc[j][0] = mfma3(ah, al, bh0, bl0, acc[j][0]);
      acc[j][1] = mfma3(ah, al, bh1, bl1, acc[j][1]);
    }
  }
#pragma unroll
  for (int j = 0; j < 7; ++j) {
#pragma unroll
    for (int o2 = 0; o2 < 2; ++o2) {
      int oc = (oct0 + o2) * 16 + ln;
      float bv = bias[oc];
#pragma unroll
      for (int r = 0; r < 4; ++r) {
        int owo = g * 4 + r;
        long oi = ((long)b * 224 + (hh * 7 + j) * 16 + owo) * 128 + oc;
        y3p[oi] = psplit(acc[j][o2][r] + bv);
      }
    }
  }
}

// ---------------- BN stats over packed channels-last ----------------
__global__ __launch_bounds__(256) void k_bnstat(const u32* __restrict__ pk,
    float* __restrict__ sums, int C, long npix)
{
  int half = C >> 1;
  int cp = threadIdx.x % half;
  int rl = threadIdx.x / half;
  int rpi = 256 / half;
  long chunk = (npix + gridDim.x - 1) / gridDim.x;
  long p0 = (long)blockIdx.x * chunk;
  long p1 = p0 + chunk; if (p1 > npix) p1 = npix;
  float s1a = 0.f, s1b = 0.f, s2a = 0.f, s2b = 0.f;
  for (long p = p0 + rl; p < p1; p += rpi) {
    uint2 pu = *(const uint2*)(pk + p * C + cp * 2);
    float v0 = punp(pu.x);
    float v1 = punp(pu.y);
    s1a += v0; s2a += v0 * v0; s1b += v1; s2b += v1 * v1;
  }
  __shared__ float bs1[128], bs2[128];
  for (int i = threadIdx.x; i < C; i += 256) { bs1[i] = 0.f; bs2[i] = 0.f; }
  __syncthreads();
  atomicAdd(&bs1[2 * cp], s1a); atomicAdd(&bs1[2 * cp + 1], s1b);
  atomicAdd(&bs2[2 * cp], s2a); atomicAdd(&bs2[2 * cp + 1], s2b);
  __syncthreads();
  if (threadIdx.x < C) {
    atomicAdd(&sums[threadIdx.x], bs1[threadIdx.x]);
    atomicAdd(&sums[C + threadIdx.x], bs2[threadIdx.x]);
  }
}

__global__ void k_bn_finalize(const float* __restrict__ sums, const float* __restrict__ g,
    const float* __restrict__ b, float* __restrict__ scale, float* __restrict__ shift,
    int C, float invN)
{
  int c = threadIdx.x;
  if (c < C) {
    float m = sums[c] * invN;
    float var = sums[C + c] * invN - m * m;
    float sc = g[c] * rsqrtf(var + 1e-5f);
    scale[c] = sc;
    shift[c] = b[c] - m * sc;
  }
}

// ---------------- BN apply + GELU in-place on packed (y3) ----------------
__global__ __launch_bounds__(256) void k_bnapplyP(u32* __restrict__ pk,
    const float* __restrict__ scale, const float* __restrict__ shift, int C, long nelem)
{
  __shared__ float sc[128], sh[128];
  for (int i = threadIdx.x; i < C; i += 256) { sc[i] = scale[i]; sh[i] = shift[i]; }
  __syncthreads();
  long i0 = ((long)blockIdx.x * 256 + threadIdx.x) * 4;
  long stride = (long)gridDim.x * 1024;
  for (long i = i0; i < nelem; i += stride) {
    uint4 v4 = *(uint4*)(pk + i);
    int cb = (int)(i & (long)(C - 1));
    u32 src[4] = { v4.x, v4.y, v4.z, v4.w };
    u32 r[4];
#pragma unroll
    for (int j = 0; j < 4; ++j) {
      float v = punp(src[j]);
      float a = gelu_f(v * sc[cb + j] + sh[cb + j]);
      r[j] = psplit(a);
    }
    *(uint4*)(pk + i) = make_uint4(r[0], r[1], r[2], r[3]);
  }
}

// ---------------- proj MFMA split-K: y3p tokens x wfp -> part[32][1024][256]
__global__ __launch_bounds__(256, 2) void k_projm(const u32* __restrict__ y3p,
    const u16* __restrict__ bh_g, const u16* __restrict__ bl_g, float* __restrict__ part)
{
  __shared__ __align__(16) u16 Ah[2048], Al[2048];   // [64 tok][32 k]
  __shared__ __align__(16) u16 Bh[8192], Bl[8192];   // [16 oct][512]
  int m0 = blockIdx.x * 64, by = blockIdx.y, tid = threadIdx.x;
  int w = tid >> 6, lane = tid & 63, g = lane >> 4, ln = lane & 15;
  f32x4 z4 = {0.f, 0.f, 0.f, 0.f};
  f32x4 acc[16];
#pragma unroll
  for (int o = 0; o < 16; ++o) acc[o] = z4;
  for (int ks = 0; ks < 28; ++ks) {
    __syncthreads();
    long k0 = ((long)by * 28 + ks) * 32;
    {
      for (int ii = 0; ii < 2; ++ii) {
        int i = tid + ii * 256;
        int row = i >> 3, q = i & 7;
        uint4 p4 = *((const uint4*)(y3p + (long)(m0 + row) * 28672 + k0) + q);
        u32 h01 = (p4.x & 0xFFFFu) | (p4.y << 16);
        u32 l01 = (p4.x >> 16) | (p4.y & 0xFFFF0000u);
        u32 h23 = (p4.z & 0xFFFFu) | (p4.w << 16);
        u32 l23 = (p4.z >> 16) | (p4.w & 0xFFFF0000u);
        ((uint2*)Ah)[i] = make_uint2(h01, h23);
        ((uint2*)Al)[i] = make_uint2(l01, l23);
      }
    }
    int ksg = by * 28 + ks;
#pragma unroll
    for (int ii = 0; ii < 8; ++ii) {
      int i = tid + ii * 256;
      int arr = i >> 10, idx = i & 1023, oct = idx >> 6, r2 = idx & 63;
      const u16* src = arr ? bl_g : bh_g;
      u16* dst = arr ? Bl : Bh;
      ((uint4*)dst)[idx] = *((const uint4*)(src + ((long)oct * 896 + ksg) * 512) + r2);
    }
    __syncthreads();
    bf16x8 a_h = *(const bf16x8*)&Ah[(w * 16 + ln) * 32 + g * 8];
    bf16x8 a_l = *(const bf16x8*)&Al[(w * 16 + ln) * 32 + g * 8];
#pragma unroll
    for (int oct = 0; oct < 16; ++oct) {
      bf16x8 bh = *(const bf16x8*)&Bh[oct * 512 + lane * 8];
      bf16x8 bl = *(const bf16x8*)&Bl[oct * 512 + lane * 8];
      acc[oct] = mfma3(a_h, a_l, bh, bl, acc[oct]);
    }
  }
#pragma unroll
  for (int oct = 0; oct < 16; ++oct) {
    int oc = oct * 16 + ln;
#pragma unroll
    for (int r = 0; r < 4; ++r) {
      int tok = m0 + w * 16 + g * 4 + r;
      part[((long)by * 1024 + tok) * 256 + oc] = acc[oct][r];
    }
  }
}

// ---------------- split-K reduce + bias + LN + GELU (writes f32 h and bf16 h) ----------------
__global__ __launch_bounds__(256) void k_lnred(const float* __restrict__ part,
    const float* __restrict__ pb, const float* __restrict__ g, const float* __restrict__ be,
    float* __restrict__ h, u16* __restrict__ hb)
{
  int b = blockIdx.x, d = threadIdx.x;
  float s = pb[d];
#pragma unroll
  for (int ks = 0; ks < 32; ++ks) s += part[((long)ks * 1024 + b) * 256 + d];
  __shared__ float red[4];
  float t = s;
  for (int o = 32; o; o >>= 1) t += __shfl_xor(t, o);
  if ((d & 63) == 0) red[d >> 6] = t;
  __syncthreads();
  float mean = (red[0] + red[1] + red[2] + red[3]) * (1.f / 256.f);
  __syncthreads();
  float dv = s - mean;
  t = dv * dv;
  for (int o = 32; o; o >>= 1) t += __shfl_xor(t, o);
  if ((d & 63) == 0) red[d >> 6] = t;
  __syncthreads();
  float var = (red[0] + red[1] + red[2] + red[3]) * (1.f / 256.f);
  float hv = gelu_f(g[d] * dv * rsqrtf(var + 1e-5f) + be[d]);
  h[b * 256 + d] = hv;
  hb[b * 256 + d] = f2bf(hv);
}

// ---------------- generic plain-bf16 MFMA GEMM: C[z][M][N] = A[z][M][K] @ Bfrag + bias
__global__ __launch_bounds__(256, 2) void k_gemmb(const u16* __restrict__ A, long aZ, int K,
    const u16* __restrict__ Bf, int noct_tot,
    const float* __restrict__ bias, int biasZ,
    void* __restrict__ C, long cZ, int ldc, int outbf, int act)
{
  __shared__ __align__(16) u16 As[2048];
  __shared__ __align__(16) u16 Bs[8192];
  int m0 = blockIdx.x * 64, nb = blockIdx.y, z = blockIdx.z, tid = threadIdx.x;
  int w = tid >> 6, lane = tid & 63, g = lane >> 4, ln = lane & 15;
  const u16* Az = A + (long)z * aZ;
  int kn = K >> 5;
  f32x4 z4 = {0.f, 0.f, 0.f, 0.f};
  f32x4 acc[16];
#pragma unroll
  for (int o = 0; o < 16; ++o) acc[o] = z4;
  for (int ks = 0; ks < kn; ++ks) {
    __syncthreads();
    {
      int row = tid >> 2, q = tid & 3;
      ((uint4*)As)[tid] = *((const uint4*)(Az + (long)(m0 + row) * K + ks * 32) + q);
    }
#pragma unroll
    for (int ii = 0; ii < 4; ++ii) {
      int i = tid + ii * 256;
      int oct = i >> 6, r2 = i & 63;
      const u16* src = Bf + (((long)z * noct_tot + nb * 16 + oct) * kn + ks) * 512;
      ((uint4*)Bs)[i] = ((const uint4*)src)[r2];
    }
    __syncthreads();
    bf16x8 a = *(const bf16x8*)&As[(w * 16 + ln) * 32 + g * 8];
#pragma unroll
    for (int oct = 0; oct < 16; ++oct) {
      bf16x8 bb = *(const bf16x8*)&Bs[oct * 512 + lane * 8];
      acc[oct] = __builtin_amdgcn_mfma_f32_16x16x32_bf16(a, bb, acc[oct], 0, 0, 0);
    }
  }
#pragma unroll
  for (int oct = 0; oct < 16; ++oct) {
    int n = nb * 256 + oct * 16 + ln;
    float bv = bias[z * biasZ + n];
#pragma unroll
    for (int r = 0; r < 4; ++r) {
      int tok = m0 + w * 16 + g * 4 + r;
      float v = acc[oct][r] + bv;
      if (act) v = gelu_f(v);
      long off = (long)z * cZ + (long)tok * ldc + n;
      if (outbf) ((u16*)C)[off] = f2bf(v);
      else ((float*)C)[off] = v;
    }
  }
}

// ---------------- router ----------------
__global__ __launch_bounds__(64) void k_router(const float* __restrict__ h,
    const float* __restrict__ rw, const float* __restrict__ eb,
    float* __restrict__ wts, int* __restrict__ idx,
    float* __restrict__ pm_sum, float* __restrict__ z_sum)
{
  int b = blockIdx.x, lane = threadIdx.x;
  float4 hv = *(const float4*)(h + b * 256 + lane * 4);
  float logit[8];
#pragma unroll
  for (int e = 0; e < 8; ++e) {
    float4 wv = *(const float4*)(rw + e * 256 + lane * 4);
    float p = hv.x * wv.x + hv.y * wv.y + hv.z * wv.z + hv.w * wv.w;
    for (int o = 32; o; o >>= 1) p += __shfl_xor(p, o);
    logit[e] = p + eb[e];
  }
  float mx = logit[0];
#pragma unroll
  for (int e = 1; e < 8; ++e) mx = fmaxf(mx, logit[e]);
  float pr[8]; float se = 0.f;
#pragma unroll
  for (int e = 0; e < 8; ++e) { pr[e] = expf(logit[e] - mx); se += pr[e]; }
  float inv = 1.f / se;
#pragma unroll
  for (int e = 0; e < 8; ++e) pr[e] *= inv;
  int i0 = 0; float v0 = pr[0];
#pragma unroll
  for (int e = 1; e < 8; ++e) if (pr[e] > v0) { v0 = pr[e]; i0 = e; }
  int i1 = -1; float v1 = -1.f;
#pragma unroll
  for (int e = 0; e < 8; ++e) if (e != i0 && pr[e] > v1) { v1 = pr[e]; i1 = e; }
  if (lane == 0) {
    float ssum = v0 + v1 + 1e-8f;
    wts[2 * b] = v0 / ssum; wts[2 * b + 1] = v1 / ssum;
    idx[2 * b] = i0; idx[2 * b + 1] = i1;
    float zz = 0.f;
#pragma unroll
    for (int e = 0; e < 8; ++e) zz += logit[e] * logit[e];
    atomicAdd(z_sum, zz);
  }
  if (lane < 8) atomicAdd(&pm_sum[lane], pr[lane]);
}

// ---------------- combine + 0.5*shared + final LN ----------------
__global__ __launch_bounds__(256) void k_combine_ln(const float* __restrict__ eout,
    const float* __restrict__ sharedB, const float* __restrict__ wts, const int* __restrict__ idx,
    const float* __restrict__ g, const float* __restrict__ bb, float* __restrict__ out)
{
  int b = blockIdx.x, d = threadIdx.x;
  float w0 = wts[2 * b], w1 = wts[2 * b + 1];
  int i0 = idx[2 * b], i1 = idx[2 * b + 1];
  float val = w0 * eout[(long)i0 * 262144 + b * 256 + d]
            + w1 * eout[(long)i1 * 262144 + b * 256 + d]
            + 0.5f * sharedB[b * 256 + d];
  __shared__ float red[4];
  float s = val;
  for (int o = 32; o; o >>= 1) s += __shfl_xor(s, o);
  if ((d & 63) == 0) red[d >> 6] = s;
  __syncthreads();
  float mean = (red[0] + red[1] + red[2] + red[3]) * (1.f / 256.f);
  __syncthreads();
  float dv = val - mean;
  s = dv * dv;
  for (int o = 32; o; o >>= 1) s += __shfl_xor(s, o);
  if ((d & 63) == 0) red[d >> 6] = s;
  __syncthreads();
  float var = (red[0] + red[1] + red[2] + red[3]) * (1.f / 256.f);
  out[b * 256 + d] = g[d] * dv * rsqrtf(var + 1e-5f) + bb[d];
}

// ---------------- aux losses ----------------
__global__ void k_losses(const float* __restrict__ pm_sum, const float* __restrict__ z_sum,
                         float* __restrict__ out)
{
  if (threadIdx.x == 0 && blockIdx.x == 0) {
    float lb = 0.f;
    for (int e = 0; e < 8; ++e) {
      float pm = pm_sum[e] * (1.f / 1024.f);
      float dd = pm - 0.125f;
      lb += dd * dd;
    }
    out[262144] = lb * 8.f;
    out[262145] = z_sum[0] * (1.f / 8192.f) * 0.001f;
  }
}

extern "C" void kernel_launch(void* const* d_in, const int* in_sizes, int n_in,
                              void* d_out, int out_size, void* d_ws, size_t ws_size,
                              hipStream_t stream)
{
  const float* x     = (const float*)d_in[0];
  const float* c1w   = (const float*)d_in[1];
  const float* c1b   = (const float*)d_in[2];
  const float* bn1g  = (const float*)d_in[3];
  const float* bn1b  = (const float*)d_in[4];
  const float* c2w   = (const float*)d_in[5];
  const float* c2b   = (const float*)d_in[6];
  const float* bn2g  = (const float*)d_in[7];
  const float* bn2b  = (const float*)d_in[8];
  const float* c3w   = (const float*)d_in[9];
  const float* c3b   = (const float*)d_in[10];
  const float* bn3g  = (const float*)d_in[11];
  const float* bn3b  = (const float*)d_in[12];
  const float* projw = (const float*)d_in[13];
  const float* projb = (const float*)d_in[14];
  const float* lng   = (const float*)d_in[15];
  const float* lnb   = (const float*)d_in[16];
  const float* rw    = (const float*)d_in[17];
  const float* ebias = (const float*)d_in[18];
  const float* ew1   = (const float*)d_in[19];
  const float* eb1   = (const float*)d_in[20];
  const float* ew2   = (const float*)d_in[21];
  const float* eb2   = (const float*)d_in[22];
  const float* sw1   = (const float*)d_in[23];
  const float* sb1   = (const float*)d_in[24];
  const float* sw2   = (const float*)d_in[25];
  const float* sb2   = (const float*)d_in[26];
  const float* mlng  = (const float*)d_in[27];
  const float* mlnb  = (const float*)d_in[28];
  float* out = (float*)d_out;

  char* W = (char*)d_ws;
  u32* y1p = (u32*)(W + 0);              // 178,913,280 B
  u32* y2p = (u32*)(W + 178913280L);     // 75,497,472 B
  u32* y3p = (u32*)(W + 0);              // 117,440,512 B (alias dead y1)
  u16* wfph = (u16*)(W + 254410752L);
  u16* wfpl = (u16*)(W + 269090816L);
  u16* wf1h = (u16*)(W + 283770880L);
  u16* wf1l = (u16*)(W + 283787264L);
  u16* wf2h = (u16*)(W + 283803648L);
  u16* wf2l = (u16*)(W + 283869184L);
  u16* wf3h = (u16*)(W + 283934720L);
  u16* wf3l = (u16*)(W + 284082176L);
  float* stats = (float*)(W + 284229632L);
  float* wtsb  = (float*)(W + 284233728L);
  int*   idxb  = (int*)(W + 284241920L);
  float* hbuf  = (float*)(W + 284250112L);
  float* shB   = (float*)(W + 286347264L);
  // tail region inside the y2p span — all used only after conv3m completes
  float* part  = (float*)(W + 178913280L);  // 33,554,432 B
  u16* hid     = (u16*)(W + 212467712L);    // 8,388,608 B
  u16* ewf1    = (u16*)(W + 220856320L);    // 2,097,152 B
  u16* ewf2    = (u16*)(W + 222953472L);    // 2,097,152 B
  u16* swf1    = (u16*)(W + 225050624L);    // 131,072 B
  u16* swf2    = (u16*)(W + 225181696L);    // 131,072 B
  float* eoutB = (float*)(W + 225312768L);  // 8,388,608 B
  u16* hbufb   = (u16*)(W + 233701376L);    // 524,288 B
  u16* sh1b    = (u16*)(W + 234225664L);    // 524,288 B

  float* sums1 = stats;        float* scale1 = stats + 512; float* shift1 = stats + 544;
  float* sums2 = stats + 64;   float* scale2 = stats + 576; float* shift2 = stats + 640;
  float* sums3 = stats + 192;  float* scale3 = stats + 704; float* shift3 = stats + 832;
  float* pm    = stats + 448;  float* zsum   = stats + 456;

  dim3 blk(256);
  k_zero<<<dim3(2), blk, 0, stream>>>(stats, 512);
  k_wprep1<<<dim3(32), blk, 0, stream>>>(c1w, wf1h, wf1l);
  k_wprep2<<<dim3(128), blk, 0, stream>>>(c2w, wf2h, wf2l);
  k_wprep3<<<dim3(288), blk, 0, stream>>>(c3w, wf3h, wf3l);
  k_wprepP<<<dim3(32, 16), blk, 0, stream>>>(projw, wfph, wfpl);

  k_conv1m<<<dim3(9, 1024), blk, 0, stream>>>(x, wf1h, wf1l, c1b, y1p);
  k_bnstat<<<dim3(512), blk, 0, stream>>>(y1p, sums1, 32, 1397760L);
  k_bn_finalize<<<1, 32, 0, stream>>>(sums1, bn1g, bn1b, scale1, shift1, 32, 1.f / 1397760.f);

  k_conv2m<<<dim3(4, 1024), blk, 0, stream>>>(y1p, wf2h, wf2l, scale1, shift1, c2b, y2p);
  k_bnstat<<<dim3(512), blk, 0, stream>>>(y2p, sums2, 64, 294912L);
  k_bn_finalize<<<1, 64, 0, stream>>>(sums2, bn2g, bn2b, scale2, shift2, 64, 1.f / 294912.f);

  k_conv3m<<<dim3(2, 1024), blk, 0, stream>>>(y2p, wf3h, wf3l, scale2, shift2, c3b, y3p);
  k_bnstat<<<dim3(512), blk, 0, stream>>>(y3p, sums3, 128, 229376L);
  k_bn_finalize<<<1, 128, 0, stream>>>(sums3, bn3g, bn3b, scale3, shift3, 128, 1.f / 229376.f);
  k_bnapplyP<<<dim3(2048), blk, 0, stream>>>(y3p, scale3, shift3, 128, 29360128L);

  // expert/shared weight preps (y2p region is dead now)
  k_wprepG<<<dim3(4096), blk, 0, stream>>>(ew1, ewf1, 512, 256, 1048576L);
  k_wprepG<<<dim3(4096), blk, 0, stream>>>(ew2, ewf2, 256, 512, 1048576L);
  k_wprepG<<<dim3(256), blk, 0, stream>>>(sw1, swf1, 256, 256, 65536L);
  k_wprepG<<<dim3(256), blk, 0, stream>>>(sw2, swf2, 256, 256, 65536L);

  k_projm<<<dim3(16, 32), blk, 0, stream>>>(y3p, wfph, wfpl, part);
  k_lnred<<<dim3(1024), blk, 0, stream>>>(part, projb, lng, lnb, hbuf, hbufb);

  k_router<<<dim3(1024), dim3(64), 0, stream>>>(hbuf, rw, ebias, wtsb, idxb, pm, zsum);

  // experts (dense) + shared, plain bf16 MFMA
  k_gemmb<<<dim3(16, 2, 8), blk, 0, stream>>>(hbufb, 0L, 256, ewf1, 32, eb1, 512,
                                              (void*)hid, 524288L, 512, 1, 1);
  k_gemmb<<<dim3(16, 1, 8), blk, 0, stream>>>(hid, 524288L, 512, ewf2, 16, eb2, 256,
                                              (void*)eoutB, 262144L, 256, 0, 0);
  k_gemmb<<<dim3(16, 1, 1), blk, 0, stream>>>(hbufb, 0L, 256, swf1, 16, sb1, 0,
                                              (void*)sh1b, 0L, 256, 1, 1);
  k_gemmb<<<dim3(16, 1, 1), blk, 0, stream>>>(sh1b, 0L, 256, swf2, 16, sb2, 0,
                                              (void*)shB, 0L, 256, 0, 0);

  k_combine_ln<<<dim3(1024), blk, 0, stream>>>(eoutB, shB, wtsb, idxb, mlng, mlnb, out);
  k_losses<<<1, 64, 0, stream>>>(pm, zsum, out);
}

// Round 10
// 807.841 us; speedup vs baseline: 1.7013x; 1.1974x over previous
//
#include <hip/hip_runtime.h>
#include <hip/hip_bf16.h>
#include <math.h>

typedef unsigned short u16;
typedef unsigned int u32;
typedef __attribute__((ext_vector_type(8))) short bf16x8;
typedef __attribute__((ext_vector_type(4))) float f32x4;

#define DEV __device__ __forceinline__

DEV float gelu_f(float x) { return 0.5f * x * (1.0f + erff(x * 0.70710678118654752f)); }
DEV u16 f2bf(float f) { u32 u = __builtin_bit_cast(u32, f); u = (u + 0x7FFFu + ((u >> 16) & 1u)) >> 16; return (u16)u; }
DEV float bf2f(u16 h) { return __builtin_bit_cast(float, (u32)h << 16); }
DEV u32 fbits(float f) { return __builtin_bit_cast(u32, f); }
DEV float ubits(u32 u) { return __builtin_bit_cast(float, u); }
// packed format: p = hi_u16 | (lo_u16 << 16), v ~= bf(hi) + bf(lo), trunc split (2^-16)
DEV u32 psplit(float v) {
  u32 u = fbits(v);
  float lo = v - ubits(u & 0xFFFF0000u);
  return (u >> 16) | (fbits(lo) & 0xFFFF0000u);
}
DEV float punp(u32 p) { return ubits(p << 16) + ubits(p & 0xFFFF0000u); }
// 3-term split product: a*b ~= ah*bh + ah*bl + al*bh
DEV f32x4 mfma3(bf16x8 ah, bf16x8 al, bf16x8 bh, bf16x8 bl, f32x4 c) {
  c = __builtin_amdgcn_mfma_f32_16x16x32_bf16(al, bh, c, 0, 0, 0);
  c = __builtin_amdgcn_mfma_f32_16x16x32_bf16(ah, bl, c, 0, 0, 0);
  c = __builtin_amdgcn_mfma_f32_16x16x32_bf16(ah, bh, c, 0, 0, 0);
  return c;
}

// ---------------- zero stats ----------------
__global__ void k_zero(float* p, int n) {
  int i = blockIdx.x * blockDim.x + threadIdx.x;
  if (i < n) p[i] = 0.f;
}

// ---------------- conv weight frag preps: layout [((oct*NS + s)*64 + lane)*8 + j] ----------------
__global__ void k_wprep1(const float* __restrict__ w, u16* __restrict__ wh, u16* __restrict__ wl) {
  int idx = blockIdx.x * 256 + threadIdx.x; if (idx >= 8192) return;
  int j = idx & 7, lane = (idx >> 3) & 63, s = (idx >> 9) & 7, oct = idx >> 12;
  int oc = oct * 16 + (lane & 15);
  int kl = ((lane >> 4) << 3) + j;
  int kw = kl >> 2, c = kl & 3, kh = s;
  float v = w[((oc * 4 + c) * 8 + kh) * 8 + kw];
  u16 h = f2bf(v); wh[idx] = h; wl[idx] = f2bf(v - bf2f(h));
}
__global__ void k_wprep2(const float* __restrict__ w, u16* __restrict__ wh, u16* __restrict__ wl) {
  int idx = blockIdx.x * 256 + threadIdx.x; if (idx >= 32768) return;
  int j = idx & 7, lane = (idx >> 3) & 63, s = (idx >> 9) & 15, oct = idx >> 13;
  int oc = oct * 16 + (lane & 15);
  int k = s * 32 + ((lane >> 4) << 3) + j;
  int kh = k >> 7, kw = (k >> 5) & 3, c = k & 31;
  float v = w[((oc * 32 + c) * 4 + kh) * 4 + kw];
  u16 h = f2bf(v); wh[idx] = h; wl[idx] = f2bf(v - bf2f(h));
}
__global__ void k_wprep3(const float* __restrict__ w, u16* __restrict__ wh, u16* __restrict__ wl) {
  int idx = blockIdx.x * 256 + threadIdx.x; if (idx >= 73728) return;
  int j = idx & 7, lane = (idx >> 3) & 63, rest = idx >> 9;
  int s = rest % 18, oct = rest / 18;
  int oc = oct * 16 + (lane & 15);
  int k = s * 32 + ((lane >> 4) << 3) + j;
  int kh = k / 192, r = k - kh * 192;
  int kw = r >> 6, c = r & 63;
  float v = w[((oc * 64 + c) * 3 + kh) * 3 + kw];
  u16 h = f2bf(v); wh[idx] = h; wl[idx] = f2bf(v - bf2f(h));
}
// proj weight prep, LDS-transpose tiled
__global__ __launch_bounds__(256) void k_wprepP(const float* __restrict__ w,
    u16* __restrict__ wh, u16* __restrict__ wl)
{
  __shared__ float tile[16][4][225];
  int q = blockIdx.x, oct = blockIdx.y, tid = threadIdx.x;
  for (int i = tid; i < 3584; i += 256) {
    int n = i / 224, rem = i % 224, e = rem / 56, f4 = rem % 56;
    float4 v = *(const float4*)(w + (long)(oct * 16 + n) * 28672 + (4 * q + e) * 224 + f4 * 4);
    tile[n][e][f4 * 4 + 0] = v.x; tile[n][e][f4 * 4 + 1] = v.y;
    tile[n][e][f4 * 4 + 2] = v.z; tile[n][e][f4 * 4 + 3] = v.w;
  }
  __syncthreads();
  int g = (q >> 1) & 3, j0 = 4 * (q & 1), sgb = q >> 3;
  for (int o = tid; o < 3584; o += 256) {
    int pix = o >> 4, ln = o & 15;
    u16 hs[4], ls[4];
#pragma unroll
    for (int e = 0; e < 4; ++e) {
      float v = tile[ln][e][pix];
      u16 h = f2bf(v); hs[e] = h; ls[e] = f2bf(v - bf2f(h));
    }
    long base = (((long)oct * 896 + pix * 4 + sgb) * 64 + g * 16 + ln) * 8 + j0;
    *(uint2*)(wh + base) = make_uint2((u32)hs[0] | ((u32)hs[1] << 16), (u32)hs[2] | ((u32)hs[3] << 16));
    *(uint2*)(wl + base) = make_uint2((u32)ls[0] | ((u32)ls[1] << 16), (u32)ls[2] | ((u32)ls[3] << 16));
  }
}
// generic plain-bf16 frag prep for expert/shared weights W[Z][N][K]
__global__ void k_wprepG(const float* __restrict__ w, u16* __restrict__ wf,
                         int N, int K, long total)
{
  long idx = (long)blockIdx.x * 256 + threadIdx.x; if (idx >= total) return;
  int j = (int)(idx & 7); int lane = (int)((idx >> 3) & 63); long rest = idx >> 9;
  int kn = K >> 5;
  int s = (int)(rest % kn); long rest2 = rest / kn;
  int noct = N >> 4;
  int oct = (int)(rest2 % noct); int z = (int)(rest2 / noct);
  int n = oct * 16 + (lane & 15);
  int k = s * 32 + ((lane >> 4) << 3) + j;
  wf[idx] = f2bf(w[((long)z * N + n) * K + k]);
}

// ---------------- conv1 MFMA + fused BN1 stats: x -> y1p[1024][1365][32] packed, sums1
__global__ __launch_bounds__(256, 3) void k_conv1m(const float* __restrict__ x,
    const u16* __restrict__ wfh, const u16* __restrict__ wfl,
    const float* __restrict__ bias, u32* __restrict__ y1p, float* __restrict__ sums)
{
  __shared__ __align__(16) u16 sin0[12800], sin1[12800];   // [20 rows][160 cols][4 c]
  __shared__ float bs1[32], bs2[32];
  int ohp = blockIdx.x, b = blockIdx.y, tid = threadIdx.x;
  int row0 = ohp * 16;
  if (tid < 32) { bs1[tid] = 0.f; bs2[tid] = 0.f; }
  for (int i = tid; i < 1600; i += 256) {
    int cp = i / 800, rem = i - cp * 800, r = rem / 40, q = rem - r * 40;
    int grow = row0 + r;
    float4 v0 = make_float4(0.f, 0.f, 0.f, 0.f), v1 = v0;
    if (grow < 144) {
      long base = ((long)b * 4 + 2 * cp) * 23040 + (long)grow * 160 + q * 4;
      v0 = *(const float4*)(x + base);
      v1 = *(const float4*)(x + base + 23040);
    }
    const float* a0 = (const float*)&v0;
    const float* a1 = (const float*)&v1;
#pragma unroll
    for (int m = 0; m < 4; ++m) {
      float f0 = a0[m], f1 = a1[m];
      u32 u0 = fbits(f0), u1 = fbits(f1);
      u32 hh = (u0 >> 16) | (u1 & 0xFFFF0000u);
      float l0 = f0 - ubits(u0 & 0xFFFF0000u);
      float l1 = f1 - ubits(u1 & 0xFFFF0000u);
      u32 ll = (fbits(l0) >> 16) | (fbits(l1) & 0xFFFF0000u);
      int col = q * 4 + m;
      int idx = r * 320 + col * 2 + cp;
      idx ^= ((col >> 4) & 3) << 2;   // swizzle
      ((u32*)sin0)[idx] = hh;
      ((u32*)sin1)[idx] = ll;
    }
  }
  __syncthreads();
  int w = tid >> 6, lane = tid & 63, g = lane >> 4, ln = lane & 15;
  int ohls[3], owcs[3];
#pragma unroll
  for (int jj = 0; jj < 3; ++jj) {
    int j = w + 4 * jj;
    ohls[jj] = j / 3;
    int owc = (j % 3) * 16 + ln; if (owc > 38) owc = 38;
    owcs[jj] = owc;
  }
  f32x4 z4 = {0.f, 0.f, 0.f, 0.f};
  f32x4 acc[3][2];
#pragma unroll
  for (int jj = 0; jj < 3; ++jj) { acc[jj][0] = z4; acc[jj][1] = z4; }
#pragma unroll
  for (int kh = 0; kh < 8; ++kh) {
    bf16x8 bh0 = *(const bf16x8*)&wfh[kh * 512 + lane * 8];
    bf16x8 bl0 = *(const bf16x8*)&wfl[kh * 512 + lane * 8];
    bf16x8 bh1 = *(const bf16x8*)&wfh[4096 + kh * 512 + lane * 8];
    bf16x8 bl1 = *(const bf16x8*)&wfl[4096 + kh * 512 + lane * 8];
#pragma unroll
    for (int jj = 0; jj < 3; ++jj) {
      int col = owcs[jj] * 4 + g * 2;
      int off = (4 * ohls[jj] + kh) * 640 + col * 4;
      off ^= ((col >> 4) & 3) << 3;   // swizzle
      bf16x8 ah = *(const bf16x8*)&sin0[off];
      bf16x8 al = *(const bf16x8*)&sin1[off];
      acc[jj][0] = mfma3(ah, al, bh0, bl0, acc[jj][0]);
      acc[jj][1] = mfma3(ah, al, bh1, bl1, acc[jj][1]);
    }
  }
  float s1[2] = {0.f, 0.f}, s2[2] = {0.f, 0.f};
#pragma unroll
  for (int jj = 0; jj < 3; ++jj) {
    int j = w + 4 * jj;
    int ohl = j / 3, owt = j % 3;
    int oh = 4 * ohp + ohl;
    if (oh >= 35) continue;
#pragma unroll
    for (int oct = 0; oct < 2; ++oct) {
      int oc = oct * 16 + ln;
      float bv = bias[oc];
#pragma unroll
      for (int r = 0; r < 4; ++r) {
        int owo = owt * 16 + g * 4 + r;
        if (owo < 39) {
          long oi = ((long)b * 1365 + oh * 39 + owo) * 32 + oc;
          float v = acc[jj][oct][r] + bv;
          y1p[oi] = psplit(v);
          s1[oct] += v; s2[oct] += v * v;
        }
      }
    }
  }
#pragma unroll
  for (int o = 16; o <= 32; o <<= 1) {
    s1[0] += __shfl_xor(s1[0], o); s1[1] += __shfl_xor(s1[1], o);
    s2[0] += __shfl_xor(s2[0], o); s2[1] += __shfl_xor(s2[1], o);
  }
  if (g == 0) {
    atomicAdd(&bs1[ln], s1[0]); atomicAdd(&bs1[16 + ln], s1[1]);
    atomicAdd(&bs2[ln], s2[0]); atomicAdd(&bs2[16 + ln], s2[1]);
  }
  __syncthreads();
  if (tid < 32) {
    atomicAdd(&sums[tid], bs1[tid]);
    atomicAdd(&sums[32 + tid], bs2[tid]);
  }
}

// ---------------- conv2 MFMA (fused BN1+GELU staging, fused BN2 stats): y1p -> y2p
__global__ __launch_bounds__(256, 3) void k_conv2m(const u32* __restrict__ y1p,
    const u16* __restrict__ wfh, const u16* __restrict__ wfl,
    const float* __restrict__ scale, const float* __restrict__ shift,
    const float* __restrict__ bias, u32* __restrict__ y2p, float* __restrict__ sums)
{
  __shared__ __align__(16) u16 sin0[12480], sin1[12480];  // [10 rows][39 cols][32 c]
  __shared__ float sc[32], shf[32];
  __shared__ float bs1[64], bs2[64];
  int ohq = blockIdx.x, b = blockIdx.y, tid = threadIdx.x;
  if (tid < 32) { sc[tid] = scale[tid]; shf[tid] = shift[tid]; }
  if (tid < 64) { bs1[tid] = 0.f; bs2[tid] = 0.f; }
  __syncthreads();
  long sb = ((long)b * 1365 + (long)ohq * 312) * 32;
  const uint4* srcP = (const uint4*)(y1p + sb);
  for (int i = tid; i < 3120; i += 256) {
    uint4 p4 = srcP[i];
    int cb = (i & 7) * 4;
    u32 hw[2], lw[2];
    u32 pe[4] = { p4.x, p4.y, p4.z, p4.w };
#pragma unroll
    for (int half = 0; half < 2; ++half) {
      float va = punp(pe[half * 2 + 0]);
      float vb = punp(pe[half * 2 + 1]);
      float aa = gelu_f(va * sc[cb + half * 2 + 0] + shf[cb + half * 2 + 0]);
      float ab = gelu_f(vb * sc[cb + half * 2 + 1] + shf[cb + half * 2 + 1]);
      u32 ua = fbits(aa), ub = fbits(ab);
      float la = aa - ubits(ua & 0xFFFF0000u);
      float lb = ab - ubits(ub & 0xFFFF0000u);
      hw[half] = (ua >> 16) | (ub & 0xFFFF0000u);
      lw[half] = (fbits(la) >> 16) | (fbits(lb) & 0xFFFF0000u);
    }
    int iw = i ^ (((i >> 4) & 7) << 1);   // swizzle
    ((uint2*)sin0)[iw] = make_uint2(hw[0], hw[1]);
    ((uint2*)sin1)[iw] = make_uint2(lw[0], lw[1]);
  }
  __syncthreads();
  int w = tid >> 6, lane = tid & 63, g = lane >> 4, ln = lane & 15;
  int oct = w;
  int rowb[5], colb[5];
#pragma unroll
  for (int j = 0; j < 5; ++j) {
    int p = j * 16 + ln; if (p > 71) p = 71;
    int ohl = p / 18, ow = p - 18 * ohl;
    rowb[j] = 2 * ohl; colb[j] = 2 * ow;
  }
  f32x4 z4 = {0.f, 0.f, 0.f, 0.f};
  f32x4 acc[5];
#pragma unroll
  for (int j = 0; j < 5; ++j) acc[j] = z4;
#pragma unroll
  for (int s = 0; s < 16; ++s) {
    int kh = s >> 2, kw = s & 3;
    bf16x8 bh = *(const bf16x8*)&wfh[oct * 8192 + s * 512 + lane * 8];
    bf16x8 bl = *(const bf16x8*)&wfl[oct * 8192 + s * 512 + lane * 8];
#pragma unroll
    for (int j = 0; j < 5; ++j) {
      int colpix = (rowb[j] + kh) * 39 + colb[j] + kw;
      int off = colpix * 32 + g * 8;
      off ^= ((colpix >> 1) & 7) << 3;   // swizzle
      bf16x8 ah = *(const bf16x8*)&sin0[off];
      bf16x8 al = *(const bf16x8*)&sin1[off];
      acc[j] = mfma3(ah, al, bh, bl, acc[j]);
    }
  }
  int oc = oct * 16 + ln;
  float bv = bias[oc];
  float s1 = 0.f, s2 = 0.f;
#pragma unroll
  for (int j = 0; j < 5; ++j) {
#pragma unroll
    for (int r = 0; r < 4; ++r) {
      int po = j * 16 + g * 4 + r;
      if (po < 72) {
        long oi = ((long)b * 288 + (long)ohq * 72 + po) * 64 + oc;
        float v = acc[j][r] + bv;
        y2p[oi] = psplit(v);
        s1 += v; s2 += v * v;
      }
    }
  }
#pragma unroll
  for (int o = 16; o <= 32; o <<= 1) { s1 += __shfl_xor(s1, o); s2 += __shfl_xor(s2, o); }
  if (g == 0) { atomicAdd(&bs1[oc], s1); atomicAdd(&bs2[oc], s2); }
  __syncthreads();
  if (tid < 64) {
    atomicAdd(&sums[tid], bs1[tid]);
    atomicAdd(&sums[64 + tid], bs2[tid]);
  }
}

// ---------------- conv3 MFMA (fused BN2+GELU staging, fused BN3 stats): y2p -> y3p (raw)
__global__ __launch_bounds__(256, 3) void k_conv3m(const u32* __restrict__ y2p,
    const u16* __restrict__ wfh, const u16* __restrict__ wfl,
    const float* __restrict__ scale, const float* __restrict__ shift,
    const float* __restrict__ bias, u32* __restrict__ y3p, float* __restrict__ sums)
{
  __shared__ __align__(16) u16 sin0[10368], sin1[10368];  // [9 rows][18 cols][64 c]
  __shared__ float sc[64], shf[64];
  __shared__ float bs1[128], bs2[128];
  int hh = blockIdx.x, b = blockIdx.y, tid = threadIdx.x;
  if (tid < 64) { sc[tid] = scale[tid]; shf[tid] = shift[tid]; }
  if (tid < 128) { bs1[tid] = 0.f; bs2[tid] = 0.f; }
  __syncthreads();
  long sb = ((long)b * 288 + (long)hh * 126) * 64;
  const uint4* srcP = (const uint4*)(y2p + sb);
  for (int i = tid; i < 2592; i += 256) {
    uint4 p4 = srcP[i];
    int cb = (i & 15) * 4;
    u32 hw[2], lw[2];
    u32 pe[4] = { p4.x, p4.y, p4.z, p4.w };
#pragma unroll
    for (int half = 0; half < 2; ++half) {
      float va = punp(pe[half * 2 + 0]);
      float vb = punp(pe[half * 2 + 1]);
      float aa = gelu_f(va * sc[cb + half * 2 + 0] + shf[cb + half * 2 + 0]);
      float ab = gelu_f(vb * sc[cb + half * 2 + 1] + shf[cb + half * 2 + 1]);
      u32 ua = fbits(aa), ub = fbits(ab);
      float la = aa - ubits(ua & 0xFFFF0000u);
      float lb = ab - ubits(ub & 0xFFFF0000u);
      hw[half] = (ua >> 16) | (ub & 0xFFFF0000u);
      lw[half] = (fbits(la) >> 16) | (fbits(lb) & 0xFFFF0000u);
    }
    int iw = i ^ (((i >> 4) & 7) << 1);   // swizzle
    ((uint2*)sin0)[iw] = make_uint2(hw[0], hw[1]);
    ((uint2*)sin1)[iw] = make_uint2(lw[0], lw[1]);
  }
  __syncthreads();
  int w = tid >> 6, lane = tid & 63, g = lane >> 4, ln = lane & 15;
  int oct0 = w * 2;
  f32x4 z4 = {0.f, 0.f, 0.f, 0.f};
  f32x4 acc[7][2];
#pragma unroll
  for (int j = 0; j < 7; ++j) { acc[j][0] = z4; acc[j][1] = z4; }
#pragma unroll 6
  for (int s = 0; s < 18; ++s) {
    const int kh = s / 6, rm = s % 6;
    const int kw = rm >> 1, ch = rm & 1;
    bf16x8 bh0 = *(const bf16x8*)&wfh[oct0 * 9216 + s * 512 + lane * 8];
    bf16x8 bl0 = *(const bf16x8*)&wfl[oct0 * 9216 + s * 512 + lane * 8];
    bf16x8 bh1 = *(const bf16x8*)&wfh[(oct0 + 1) * 9216 + s * 512 + lane * 8];
    bf16x8 bl1 = *(const bf16x8*)&wfl[(oct0 + 1) * 9216 + s * 512 + lane * 8];
#pragma unroll
    for (int j = 0; j < 7; ++j) {
      int colpix = (j + kh) * 18 + ln + kw;
      int off = colpix * 64 + ch * 32 + g * 8;
      off ^= (colpix & 7) << 3;   // swizzle
      bf16x8 ah = *(const bf16x8*)&sin0[off];
      bf16x8 al = *(const bf16x8*)&sin1[off];
      acc[j][0] = mfma3(ah, al, bh0, bl0, acc[j][0]);
      acc[j][1] = mfma3(ah, al, bh1, bl1, acc[j][1]);
    }
  }
  float s1[2] = {0.f, 0.f}, s2[2] = {0.f, 0.f};
#pragma unroll
  for (int j = 0; j < 7; ++j) {
#pragma unroll
    for (int o2 = 0; o2 < 2; ++o2) {
      int oc = (oct0 + o2) * 16 + ln;
      float bv = bias[oc];
#pragma unroll
      for (int r = 0; r < 4; ++r) {
        int owo = g * 4 + r;
        long oi = ((long)b * 224 + (hh * 7 + j) * 16 + owo) * 128 + oc;
        float v = acc[j][o2][r] + bv;
        y3p[oi] = psplit(v);
        s1[o2] += v; s2[o2] += v * v;
      }
    }
  }
#pragma unroll
  for (int o = 16; o <= 32; o <<= 1) {
    s1[0] += __shfl_xor(s1[0], o); s1[1] += __shfl_xor(s1[1], o);
    s2[0] += __shfl_xor(s2[0], o); s2[1] += __shfl_xor(s2[1], o);
  }
  if (g == 0) {
    atomicAdd(&bs1[oct0 * 16 + ln], s1[0]); atomicAdd(&bs1[(oct0 + 1) * 16 + ln], s1[1]);
    atomicAdd(&bs2[oct0 * 16 + ln], s2[0]); atomicAdd(&bs2[(oct0 + 1) * 16 + ln], s2[1]);
  }
  __syncthreads();
  if (tid < 128) {
    atomicAdd(&sums[tid], bs1[tid]);
    atomicAdd(&sums[128 + tid], bs2[tid]);
  }
}

__global__ void k_bn_finalize(const float* __restrict__ sums, const float* __restrict__ g,
    const float* __restrict__ b, float* __restrict__ scale, float* __restrict__ shift,
    int C, float invN)
{
  int c = threadIdx.x;
  if (c < C) {
    float m = sums[c] * invN;
    float var = sums[C + c] * invN - m * m;
    float sc = g[c] * rsqrtf(var + 1e-5f);
    scale[c] = sc;
    shift[c] = b[c] - m * sc;
  }
}

// ---------------- proj MFMA split-K (fused BN3+GELU on A-staging): raw y3p x wfp -> part
__global__ __launch_bounds__(256, 2) void k_projm(const u32* __restrict__ y3p,
    const u16* __restrict__ bh_g, const u16* __restrict__ bl_g,
    const float* __restrict__ scale, const float* __restrict__ shift,
    float* __restrict__ part)
{
  __shared__ __align__(16) u16 Ah[2048], Al[2048];   // [64 tok][32 k]
  __shared__ __align__(16) u16 Bh[8192], Bl[8192];   // [16 oct][512]
  __shared__ float sc3[128], sh3[128];
  int m0 = blockIdx.x * 64, by = blockIdx.y, tid = threadIdx.x;
  int w = tid >> 6, lane = tid & 63, g = lane >> 4, ln = lane & 15;
  if (tid < 128) { sc3[tid] = scale[tid]; sh3[tid] = shift[tid]; }
  f32x4 z4 = {0.f, 0.f, 0.f, 0.f};
  f32x4 acc[16];
#pragma unroll
  for (int o = 0; o < 16; ++o) acc[o] = z4;
  for (int ks = 0; ks < 28; ++ks) {
    __syncthreads();
    long k0 = ((long)by * 28 + ks) * 32;
    int cbase = (int)(k0 & 127);
    {
      for (int ii = 0; ii < 2; ++ii) {
        int i = tid + ii * 256;
        int row = i >> 3, q = i & 7;
        uint4 p4 = *((const uint4*)(y3p + (long)(m0 + row) * 28672 + k0) + q);
        u32 pe[4] = { p4.x, p4.y, p4.z, p4.w };
        int c0 = cbase + q * 4;
        u16 hs[4], ls[4];
#pragma unroll
        for (int j = 0; j < 4; ++j) {
          float v = punp(pe[j]);
          float a = gelu_f(v * sc3[c0 + j] + sh3[c0 + j]);
          u32 ua = fbits(a);
          float la = a - ubits(ua & 0xFFFF0000u);
          hs[j] = (u16)(ua >> 16);
          ls[j] = (u16)(fbits(la) >> 16);
        }
        ((uint2*)Ah)[i] = make_uint2((u32)hs[0] | ((u32)hs[1] << 16), (u32)hs[2] | ((u32)hs[3] << 16));
        ((uint2*)Al)[i] = make_uint2((u32)ls[0] | ((u32)ls[1] << 16), (u32)ls[2] | ((u32)ls[3] << 16));
      }
    }
    int ksg = by * 28 + ks;
#pragma unroll
    for (int ii = 0; ii < 8; ++ii) {
      int i = tid + ii * 256;
      int arr = i >> 10, idx = i & 1023, oct = idx >> 6, r2 = idx & 63;
      const u16* src = arr ? bl_g : bh_g;
      u16* dst = arr ? Bl : Bh;
      ((uint4*)dst)[idx] = *((const uint4*)(src + ((long)oct * 896 + ksg) * 512) + r2);
    }
    __syncthreads();
    bf16x8 a_h = *(const bf16x8*)&Ah[(w * 16 + ln) * 32 + g * 8];
    bf16x8 a_l = *(const bf16x8*)&Al[(w * 16 + ln) * 32 + g * 8];
#pragma unroll
    for (int oct = 0; oct < 16; ++oct) {
      bf16x8 bh = *(const bf16x8*)&Bh[oct * 512 + lane * 8];
      bf16x8 bl = *(const bf16x8*)&Bl[oct * 512 + lane * 8];
      acc[oct] = mfma3(a_h, a_l, bh, bl, acc[oct]);
    }
  }
#pragma unroll
  for (int oct = 0; oct < 16; ++oct) {
    int oc = oct * 16 + ln;
#pragma unroll
    for (int r = 0; r < 4; ++r) {
      int tok = m0 + w * 16 + g * 4 + r;
      part[((long)by * 1024 + tok) * 256 + oc] = acc[oct][r];
    }
  }
}

// ---------------- split-K reduce + bias + LN + GELU (writes f32 h and bf16 h) ----------------
__global__ __launch_bounds__(256) void k_lnred(const float* __restrict__ part,
    const float* __restrict__ pb, const float* __restrict__ g, const float* __restrict__ be,
    float* __restrict__ h, u16* __restrict__ hb)
{
  int b = blockIdx.x, d = threadIdx.x;
  float s = pb[d];
#pragma unroll
  for (int ks = 0; ks < 32; ++ks) s += part[((long)ks * 1024 + b) * 256 + d];
  __shared__ float red[4];
  float t = s;
  for (int o = 32; o; o >>= 1) t += __shfl_xor(t, o);
  if ((d & 63) == 0) red[d >> 6] = t;
  __syncthreads();
  float mean = (red[0] + red[1] + red[2] + red[3]) * (1.f / 256.f);
  __syncthreads();
  float dv = s - mean;
  t = dv * dv;
  for (int o = 32; o; o >>= 1) t += __shfl_xor(t, o);
  if ((d & 63) == 0) red[d >> 6] = t;
  __syncthreads();
  float var = (red[0] + red[1] + red[2] + red[3]) * (1.f / 256.f);
  float hv = gelu_f(g[d] * dv * rsqrtf(var + 1e-5f) + be[d]);
  h[b * 256 + d] = hv;
  hb[b * 256 + d] = f2bf(hv);
}

// ---------------- generic plain-bf16 MFMA GEMM: C[z][M][N] = A[z][M][K] @ Bfrag + bias
__global__ __launch_bounds__(256, 2) void k_gemmb(const u16* __restrict__ A, long aZ, int K,
    const u16* __restrict__ Bf, int noct_tot,
    const float* __restrict__ bias, int biasZ,
    void* __restrict__ C, long cZ, int ldc, int outbf, int act)
{
  __shared__ __align__(16) u16 As[2048];
  __shared__ __align__(16) u16 Bs[8192];
  int m0 = blockIdx.x * 64, nb = blockIdx.y, z = blockIdx.z, tid = threadIdx.x;
  int w = tid >> 6, lane = tid & 63, g = lane >> 4, ln = lane & 15;
  const u16* Az = A + (long)z * aZ;
  int kn = K >> 5;
  f32x4 z4 = {0.f, 0.f, 0.f, 0.f};
  f32x4 acc[16];
#pragma unroll
  for (int o = 0; o < 16; ++o) acc[o] = z4;
  for (int ks = 0; ks < kn; ++ks) {
    __syncthreads();
    {
      int row = tid >> 2, q = tid & 3;
      ((uint4*)As)[tid] = *((const uint4*)(Az + (long)(m0 + row) * K + ks * 32) + q);
    }
#pragma unroll
    for (int ii = 0; ii < 4; ++ii) {
      int i = tid + ii * 256;
      int oct = i >> 6, r2 = i & 63;
      const u16* src = Bf + (((long)z * noct_tot + nb * 16 + oct) * kn + ks) * 512;
      ((uint4*)Bs)[i] = ((const uint4*)src)[r2];
    }
    __syncthreads();
    bf16x8 a = *(const bf16x8*)&As[(w * 16 + ln) * 32 + g * 8];
#pragma unroll
    for (int oct = 0; oct < 16; ++oct) {
      bf16x8 bb = *(const bf16x8*)&Bs[oct * 512 + lane * 8];
      acc[oct] = __builtin_amdgcn_mfma_f32_16x16x32_bf16(a, bb, acc[oct], 0, 0, 0);
    }
  }
#pragma unroll
  for (int oct = 0; oct < 16; ++oct) {
    int n = nb * 256 + oct * 16 + ln;
    float bv = bias[z * biasZ + n];
#pragma unroll
    for (int r = 0; r < 4; ++r) {
      int tok = m0 + w * 16 + g * 4 + r;
      float v = acc[oct][r] + bv;
      if (act) v = gelu_f(v);
      long off = (long)z * cZ + (long)tok * ldc + n;
      if (outbf) ((u16*)C)[off] = f2bf(v);
      else ((float*)C)[off] = v;
    }
  }
}

// ---------------- router ----------------
__global__ __launch_bounds__(64) void k_router(const float* __restrict__ h,
    const float* __restrict__ rw, const float* __restrict__ eb,
    float* __restrict__ wts, int* __restrict__ idx,
    float* __restrict__ pm_sum, float* __restrict__ z_sum)
{
  int b = blockIdx.x, lane = threadIdx.x;
  float4 hv = *(const float4*)(h + b * 256 + lane * 4);
  float logit[8];
#pragma unroll
  for (int e = 0; e < 8; ++e) {
    float4 wv = *(const float4*)(rw + e * 256 + lane * 4);
    float p = hv.x * wv.x + hv.y * wv.y + hv.z * wv.z + hv.w * wv.w;
    for (int o = 32; o; o >>= 1) p += __shfl_xor(p, o);
    logit[e] = p + eb[e];
  }
  float mx = logit[0];
#pragma unroll
  for (int e = 1; e < 8; ++e) mx = fmaxf(mx, logit[e]);
  float pr[8]; float se = 0.f;
#pragma unroll
  for (int e = 0; e < 8; ++e) { pr[e] = expf(logit[e] - mx); se += pr[e]; }
  float inv = 1.f / se;
#pragma unroll
  for (int e = 0; e < 8; ++e) pr[e] *= inv;
  int i0 = 0; float v0 = pr[0];
#pragma unroll
  for (int e = 1; e < 8; ++e) if (pr[e] > v0) { v0 = pr[e]; i0 = e; }
  int i1 = -1; float v1 = -1.f;
#pragma unroll
  for (int e = 0; e < 8; ++e) if (e != i0 && pr[e] > v1) { v1 = pr[e]; i1 = e; }
  if (lane == 0) {
    float ssum = v0 + v1 + 1e-8f;
    wts[2 * b] = v0 / ssum; wts[2 * b + 1] = v1 / ssum;
    idx[2 * b] = i0; idx[2 * b + 1] = i1;
    float zz = 0.f;
#pragma unroll
    for (int e = 0; e < 8; ++e) zz += logit[e] * logit[e];
    atomicAdd(z_sum, zz);
  }
  if (lane < 8) atomicAdd(&pm_sum[lane], pr[lane]);
}

// ---------------- combine + 0.5*shared + final LN ----------------
__global__ __launch_bounds__(256) void k_combine_ln(const float* __restrict__ eout,
    const float* __restrict__ sharedB, const float* __restrict__ wts, const int* __restrict__ idx,
    const float* __restrict__ g, const float* __restrict__ bb, float* __restrict__ out)
{
  int b = blockIdx.x, d = threadIdx.x;
  float w0 = wts[2 * b], w1 = wts[2 * b + 1];
  int i0 = idx[2 * b], i1 = idx[2 * b + 1];
  float val = w0 * eout[(long)i0 * 262144 + b * 256 + d]
            + w1 * eout[(long)i1 * 262144 + b * 256 + d]
            + 0.5f * sharedB[b * 256 + d];
  __shared__ float red[4];
  float s = val;
  for (int o = 32; o; o >>= 1) s += __shfl_xor(s, o);
  if ((d & 63) == 0) red[d >> 6] = s;
  __syncthreads();
  float mean = (red[0] + red[1] + red[2] + red[3]) * (1.f / 256.f);
  __syncthreads();
  float dv = val - mean;
  s = dv * dv;
  for (int o = 32; o; o >>= 1) s += __shfl_xor(s, o);
  if ((d & 63) == 0) red[d >> 6] = s;
  __syncthreads();
  float var = (red[0] + red[1] + red[2] + red[3]) * (1.f / 256.f);
  out[b * 256 + d] = g[d] * dv * rsqrtf(var + 1e-5f) + bb[d];
}

// ---------------- aux losses ----------------
__global__ void k_losses(const float* __restrict__ pm_sum, const float* __restrict__ z_sum,
                         float* __restrict__ out)
{
  if (threadIdx.x == 0 && blockIdx.x == 0) {
    float lb = 0.f;
    for (int e = 0; e < 8; ++e) {
      float pm = pm_sum[e] * (1.f / 1024.f);
      float dd = pm - 0.125f;
      lb += dd * dd;
    }
    out[262144] = lb * 8.f;
    out[262145] = z_sum[0] * (1.f / 8192.f) * 0.001f;
  }
}

extern "C" void kernel_launch(void* const* d_in, const int* in_sizes, int n_in,
                              void* d_out, int out_size, void* d_ws, size_t ws_size,
                              hipStream_t stream)
{
  const float* x     = (const float*)d_in[0];
  const float* c1w   = (const float*)d_in[1];
  const float* c1b   = (const float*)d_in[2];
  const float* bn1g  = (const float*)d_in[3];
  const float* bn1b  = (const float*)d_in[4];
  const float* c2w   = (const float*)d_in[5];
  const float* c2b   = (const float*)d_in[6];
  const float* bn2g  = (const float*)d_in[7];
  const float* bn2b  = (const float*)d_in[8];
  const float* c3w   = (const float*)d_in[9];
  const float* c3b   = (const float*)d_in[10];
  const float* bn3g  = (const float*)d_in[11];
  const float* bn3b  = (const float*)d_in[12];
  const float* projw = (const float*)d_in[13];
  const float* projb = (const float*)d_in[14];
  const float* lng   = (const float*)d_in[15];
  const float* lnb   = (const float*)d_in[16];
  const float* rw    = (const float*)d_in[17];
  const float* ebias = (const float*)d_in[18];
  const float* ew1   = (const float*)d_in[19];
  const float* eb1   = (const float*)d_in[20];
  const float* ew2   = (const float*)d_in[21];
  const float* eb2   = (const float*)d_in[22];
  const float* sw1   = (const float*)d_in[23];
  const float* sb1   = (const float*)d_in[24];
  const float* sw2   = (const float*)d_in[25];
  const float* sb2   = (const float*)d_in[26];
  const float* mlng  = (const float*)d_in[27];
  const float* mlnb  = (const float*)d_in[28];
  float* out = (float*)d_out;

  char* W = (char*)d_ws;
  u32* y1p = (u32*)(W + 0);              // 178,913,280 B
  u32* y2p = (u32*)(W + 178913280L);     // 75,497,472 B
  u32* y3p = (u32*)(W + 0);              // 117,440,512 B (alias dead y1)
  u16* wfph = (u16*)(W + 254410752L);
  u16* wfpl = (u16*)(W + 269090816L);
  u16* wf1h = (u16*)(W + 283770880L);
  u16* wf1l = (u16*)(W + 283787264L);
  u16* wf2h = (u16*)(W + 283803648L);
  u16* wf2l = (u16*)(W + 283869184L);
  u16* wf3h = (u16*)(W + 283934720L);
  u16* wf3l = (u16*)(W + 284082176L);
  float* stats = (float*)(W + 284229632L);
  float* wtsb  = (float*)(W + 284233728L);
  int*   idxb  = (int*)(W + 284241920L);
  float* hbuf  = (float*)(W + 284250112L);
  float* shB   = (float*)(W + 286347264L);
  // tail region inside the y2p span — all used only after conv3m completes
  float* part  = (float*)(W + 178913280L);  // 33,554,432 B
  u16* hid     = (u16*)(W + 212467712L);    // 8,388,608 B
  u16* ewf1    = (u16*)(W + 220856320L);    // 2,097,152 B
  u16* ewf2    = (u16*)(W + 222953472L);    // 2,097,152 B
  u16* swf1    = (u16*)(W + 225050624L);    // 131,072 B
  u16* swf2    = (u16*)(W + 225181696L);    // 131,072 B
  float* eoutB = (float*)(W + 225312768L);  // 8,388,608 B
  u16* hbufb   = (u16*)(W + 233701376L);    // 524,288 B
  u16* sh1b    = (u16*)(W + 234225664L);    // 524,288 B

  float* sums1 = stats;        float* scale1 = stats + 512; float* shift1 = stats + 544;
  float* sums2 = stats + 64;   float* scale2 = stats + 576; float* shift2 = stats + 640;
  float* sums3 = stats + 192;  float* scale3 = stats + 704; float* shift3 = stats + 832;
  float* pm    = stats + 448;  float* zsum   = stats + 456;

  dim3 blk(256);
  k_zero<<<dim3(2), blk, 0, stream>>>(stats, 512);
  k_wprep1<<<dim3(32), blk, 0, stream>>>(c1w, wf1h, wf1l);
  k_wprep2<<<dim3(128), blk, 0, stream>>>(c2w, wf2h, wf2l);
  k_wprep3<<<dim3(288), blk, 0, stream>>>(c3w, wf3h, wf3l);
  k_wprepP<<<dim3(32, 16), blk, 0, stream>>>(projw, wfph, wfpl);

  k_conv1m<<<dim3(9, 1024), blk, 0, stream>>>(x, wf1h, wf1l, c1b, y1p, sums1);
  k_bn_finalize<<<1, 32, 0, stream>>>(sums1, bn1g, bn1b, scale1, shift1, 32, 1.f / 1397760.f);

  k_conv2m<<<dim3(4, 1024), blk, 0, stream>>>(y1p, wf2h, wf2l, scale1, shift1, c2b, y2p, sums2);
  k_bn_finalize<<<1, 64, 0, stream>>>(sums2, bn2g, bn2b, scale2, shift2, 64, 1.f / 294912.f);

  k_conv3m<<<dim3(2, 1024), blk, 0, stream>>>(y2p, wf3h, wf3l, scale2, shift2, c3b, y3p, sums3);
  k_bn_finalize<<<1, 128, 0, stream>>>(sums3, bn3g, bn3b, scale3, shift3, 128, 1.f / 229376.f);

  // expert/shared weight preps (y2p region is dead now)
  k_wprepG<<<dim3(4096), blk, 0, stream>>>(ew1, ewf1, 512, 256, 1048576L);
  k_wprepG<<<dim3(4096), blk, 0, stream>>>(ew2, ewf2, 256, 512, 1048576L);
  k_wprepG<<<dim3(256), blk, 0, stream>>>(sw1, swf1, 256, 256, 65536L);
  k_wprepG<<<dim3(256), blk, 0, stream>>>(sw2, swf2, 256, 256, 65536L);

  k_projm<<<dim3(16, 32), blk, 0, stream>>>(y3p, wfph, wfpl, scale3, shift3, part);
  k_lnred<<<dim3(1024), blk, 0, stream>>>(part, projb, lng, lnb, hbuf, hbufb);

  k_router<<<dim3(1024), dim3(64), 0, stream>>>(hbuf, rw, ebias, wtsb, idxb, pm, zsum);

  // experts (dense) + shared, plain bf16 MFMA
  k_gemmb<<<dim3(16, 2, 8), blk, 0, stream>>>(hbufb, 0L, 256, ewf1, 32, eb1, 512,
                                              (void*)hid, 524288L, 512, 1, 1);
  k_gemmb<<<dim3(16, 1, 8), blk, 0, stream>>>(hid, 524288L, 512, ewf2, 16, eb2, 256,
                                              (void*)eoutB, 262144L, 256, 0, 0);
  k_gemmb<<<dim3(16, 1, 1), blk, 0, stream>>>(hbufb, 0L, 256, swf1, 16, sb1, 0,
                                              (void*)sh1b, 0L, 256, 1, 1);
  k_gemmb<<<dim3(16, 1, 1), blk, 0, stream>>>(sh1b, 0L, 256, swf2, 16, sb2, 0,
                                              (void*)shB, 0L, 256, 0, 0);

  k_combine_ln<<<dim3(1024), blk, 0, stream>>>(eoutB, shB, wtsb, idxb, mlng, mlnb, out);
  k_losses<<<1, 64, 0, stream>>>(pm, zsum, out);
}

// Round 11
// 773.926 us; speedup vs baseline: 1.7758x; 1.0438x over previous
//
#include <hip/hip_runtime.h>
#include <hip/hip_bf16.h>
#include <math.h>

typedef unsigned short u16;
typedef unsigned int u32;
typedef __attribute__((ext_vector_type(8))) short bf16x8;
typedef __attribute__((ext_vector_type(4))) float f32x4;

#define DEV __device__ __forceinline__

DEV float gelu_f(float x) { return 0.5f * x * (1.0f + erff(x * 0.70710678118654752f)); }
DEV u16 f2bf(float f) { u32 u = __builtin_bit_cast(u32, f); u = (u + 0x7FFFu + ((u >> 16) & 1u)) >> 16; return (u16)u; }
DEV float bf2f(u16 h) { return __builtin_bit_cast(float, (u32)h << 16); }
DEV u32 fbits(float f) { return __builtin_bit_cast(u32, f); }
DEV float ubits(u32 u) { return __builtin_bit_cast(float, u); }
// packed format: p = hi_u16 | (lo_u16 << 16), v ~= bf(hi) + bf(lo), trunc split (2^-16)
DEV u32 psplit(float v) {
  u32 u = fbits(v);
  float lo = v - ubits(u & 0xFFFF0000u);
  return (u >> 16) | (fbits(lo) & 0xFFFF0000u);
}
DEV float punp(u32 p) { return ubits(p << 16) + ubits(p & 0xFFFF0000u); }
// 3-term split product: a*b ~= ah*bh + ah*bl + al*bh
DEV f32x4 mfma3(bf16x8 ah, bf16x8 al, bf16x8 bh, bf16x8 bl, f32x4 c) {
  c = __builtin_amdgcn_mfma_f32_16x16x32_bf16(al, bh, c, 0, 0, 0);
  c = __builtin_amdgcn_mfma_f32_16x16x32_bf16(ah, bl, c, 0, 0, 0);
  c = __builtin_amdgcn_mfma_f32_16x16x32_bf16(ah, bh, c, 0, 0, 0);
  return c;
}

// ---------------- zero stats ----------------
__global__ void k_zero(float* p, int n) {
  int i = blockIdx.x * blockDim.x + threadIdx.x;
  if (i < n) p[i] = 0.f;
}

// ---------------- conv weight frag preps ----------------
__global__ void k_wprep1(const float* __restrict__ w, u16* __restrict__ wh, u16* __restrict__ wl) {
  int idx = blockIdx.x * 256 + threadIdx.x; if (idx >= 8192) return;
  int j = idx & 7, lane = (idx >> 3) & 63, s = (idx >> 9) & 7, oct = idx >> 12;
  int oc = oct * 16 + (lane & 15);
  int kl = ((lane >> 4) << 3) + j;
  int kw = kl >> 2, c = kl & 3, kh = s;
  float v = w[((oc * 4 + c) * 8 + kh) * 8 + kw];
  u16 h = f2bf(v); wh[idx] = h; wl[idx] = f2bf(v - bf2f(h));
}
__global__ void k_wprep2(const float* __restrict__ w, u16* __restrict__ wh, u16* __restrict__ wl) {
  int idx = blockIdx.x * 256 + threadIdx.x; if (idx >= 32768) return;
  int j = idx & 7, lane = (idx >> 3) & 63, s = (idx >> 9) & 15, oct = idx >> 13;
  int oc = oct * 16 + (lane & 15);
  int k = s * 32 + ((lane >> 4) << 3) + j;
  int kh = k >> 7, kw = (k >> 5) & 3, c = k & 31;
  float v = w[((oc * 32 + c) * 4 + kh) * 4 + kw];
  u16 h = f2bf(v); wh[idx] = h; wl[idx] = f2bf(v - bf2f(h));
}
__global__ void k_wprep3(const float* __restrict__ w, u16* __restrict__ wh, u16* __restrict__ wl) {
  int idx = blockIdx.x * 256 + threadIdx.x; if (idx >= 73728) return;
  int j = idx & 7, lane = (idx >> 3) & 63, rest = idx >> 9;
  int s = rest % 18, oct = rest / 18;
  int oc = oct * 16 + (lane & 15);
  int k = s * 32 + ((lane >> 4) << 3) + j;
  int kh = k / 192, r = k - kh * 192;
  int kw = r >> 6, c = r & 63;
  float v = w[((oc * 64 + c) * 3 + kh) * 3 + kw];
  u16 h = f2bf(v); wh[idx] = h; wl[idx] = f2bf(v - bf2f(h));
}
// proj weight prep, LDS-transpose tiled
__global__ __launch_bounds__(256) void k_wprepP(const float* __restrict__ w,
    u16* __restrict__ wh, u16* __restrict__ wl)
{
  __shared__ float tile[16][4][225];
  int q = blockIdx.x, oct = blockIdx.y, tid = threadIdx.x;
  for (int i = tid; i < 3584; i += 256) {
    int n = i / 224, rem = i % 224, e = rem / 56, f4 = rem % 56;
    float4 v = *(const float4*)(w + (long)(oct * 16 + n) * 28672 + (4 * q + e) * 224 + f4 * 4);
    tile[n][e][f4 * 4 + 0] = v.x; tile[n][e][f4 * 4 + 1] = v.y;
    tile[n][e][f4 * 4 + 2] = v.z; tile[n][e][f4 * 4 + 3] = v.w;
  }
  __syncthreads();
  int g = (q >> 1) & 3, j0 = 4 * (q & 1), sgb = q >> 3;
  for (int o = tid; o < 3584; o += 256) {
    int pix = o >> 4, ln = o & 15;
    u16 hs[4], ls[4];
#pragma unroll
    for (int e = 0; e < 4; ++e) {
      float v = tile[ln][e][pix];
      u16 h = f2bf(v); hs[e] = h; ls[e] = f2bf(v - bf2f(h));
    }
    long base = (((long)oct * 896 + pix * 4 + sgb) * 64 + g * 16 + ln) * 8 + j0;
    *(uint2*)(wh + base) = make_uint2((u32)hs[0] | ((u32)hs[1] << 16), (u32)hs[2] | ((u32)hs[3] << 16));
    *(uint2*)(wl + base) = make_uint2((u32)ls[0] | ((u32)ls[1] << 16), (u32)ls[2] | ((u32)ls[3] << 16));
  }
}
// generic plain-bf16 frag prep for expert/shared weights W[Z][N][K]
__global__ void k_wprepG(const float* __restrict__ w, u16* __restrict__ wf,
                         int N, int K, long total)
{
  long idx = (long)blockIdx.x * 256 + threadIdx.x; if (idx >= total) return;
  int j = (int)(idx & 7); int lane = (int)((idx >> 3) & 63); long rest = idx >> 9;
  int kn = K >> 5;
  int s = (int)(rest % kn); long rest2 = rest / kn;
  int noct = N >> 4;
  int oct = (int)(rest2 % noct); int z = (int)(rest2 / noct);
  int n = oct * 16 + (lane & 15);
  int k = s * 32 + ((lane >> 4) << 3) + j;
  wf[idx] = f2bf(w[((long)z * N + n) * K + k]);
}

// ---------------- conv1 MFMA + fused bucketed BN1 stats ----------------
__global__ __launch_bounds__(256, 3) void k_conv1m(const float* __restrict__ x,
    const u16* __restrict__ wfh, const u16* __restrict__ wfl,
    const float* __restrict__ bias, u32* __restrict__ y1p, float* __restrict__ sums)
{
  __shared__ __align__(16) u16 sin0[12800], sin1[12800];   // [20 rows][160 cols][4 c]
  __shared__ float bs1[32], bs2[32];
  int ohp = blockIdx.x, b = blockIdx.y, tid = threadIdx.x;
  int row0 = ohp * 16;
  if (tid < 32) { bs1[tid] = 0.f; bs2[tid] = 0.f; }
  for (int i = tid; i < 1600; i += 256) {
    int cp = i / 800, rem = i - cp * 800, r = rem / 40, q = rem - r * 40;
    int grow = row0 + r;
    float4 v0 = make_float4(0.f, 0.f, 0.f, 0.f), v1 = v0;
    if (grow < 144) {
      long base = ((long)b * 4 + 2 * cp) * 23040 + (long)grow * 160 + q * 4;
      v0 = *(const float4*)(x + base);
      v1 = *(const float4*)(x + base + 23040);
    }
    const float* a0 = (const float*)&v0;
    const float* a1 = (const float*)&v1;
#pragma unroll
    for (int m = 0; m < 4; ++m) {
      float f0 = a0[m], f1 = a1[m];
      u32 u0 = fbits(f0), u1 = fbits(f1);
      u32 hh = (u0 >> 16) | (u1 & 0xFFFF0000u);
      float l0 = f0 - ubits(u0 & 0xFFFF0000u);
      float l1 = f1 - ubits(u1 & 0xFFFF0000u);
      u32 ll = (fbits(l0) >> 16) | (fbits(l1) & 0xFFFF0000u);
      int col = q * 4 + m;
      int idx = r * 320 + col * 2 + cp;
      idx ^= ((col >> 4) & 3) << 2;   // swizzle
      ((u32*)sin0)[idx] = hh;
      ((u32*)sin1)[idx] = ll;
    }
  }
  __syncthreads();
  int w = tid >> 6, lane = tid & 63, g = lane >> 4, ln = lane & 15;
  int ohls[3], owcs[3];
#pragma unroll
  for (int jj = 0; jj < 3; ++jj) {
    int j = w + 4 * jj;
    ohls[jj] = j / 3;
    int owc = (j % 3) * 16 + ln; if (owc > 38) owc = 38;
    owcs[jj] = owc;
  }
  f32x4 z4 = {0.f, 0.f, 0.f, 0.f};
  f32x4 acc[3][2];
#pragma unroll
  for (int jj = 0; jj < 3; ++jj) { acc[jj][0] = z4; acc[jj][1] = z4; }
#pragma unroll
  for (int kh = 0; kh < 8; ++kh) {
    bf16x8 bh0 = *(const bf16x8*)&wfh[kh * 512 + lane * 8];
    bf16x8 bl0 = *(const bf16x8*)&wfl[kh * 512 + lane * 8];
    bf16x8 bh1 = *(const bf16x8*)&wfh[4096 + kh * 512 + lane * 8];
    bf16x8 bl1 = *(const bf16x8*)&wfl[4096 + kh * 512 + lane * 8];
#pragma unroll
    for (int jj = 0; jj < 3; ++jj) {
      int col = owcs[jj] * 4 + g * 2;
      int off = (4 * ohls[jj] + kh) * 640 + col * 4;
      off ^= ((col >> 4) & 3) << 3;   // swizzle
      bf16x8 ah = *(const bf16x8*)&sin0[off];
      bf16x8 al = *(const bf16x8*)&sin1[off];
      acc[jj][0] = mfma3(ah, al, bh0, bl0, acc[jj][0]);
      acc[jj][1] = mfma3(ah, al, bh1, bl1, acc[jj][1]);
    }
  }
  float s1[2] = {0.f, 0.f}, s2[2] = {0.f, 0.f};
#pragma unroll
  for (int jj = 0; jj < 3; ++jj) {
    int j = w + 4 * jj;
    int ohl = j / 3, owt = j % 3;
    int oh = 4 * ohp + ohl;
    if (oh >= 35) continue;
#pragma unroll
    for (int oct = 0; oct < 2; ++oct) {
      int oc = oct * 16 + ln;
      float bv = bias[oc];
#pragma unroll
      for (int r = 0; r < 4; ++r) {
        int owo = owt * 16 + g * 4 + r;
        if (owo < 39) {
          long oi = ((long)b * 1365 + oh * 39 + owo) * 32 + oc;
          float v = acc[jj][oct][r] + bv;
          y1p[oi] = psplit(v);
          s1[oct] += v; s2[oct] += v * v;
        }
      }
    }
  }
#pragma unroll
  for (int o = 16; o <= 32; o <<= 1) {
    s1[0] += __shfl_xor(s1[0], o); s1[1] += __shfl_xor(s1[1], o);
    s2[0] += __shfl_xor(s2[0], o); s2[1] += __shfl_xor(s2[1], o);
  }
  if (g == 0) {
    atomicAdd(&bs1[ln], s1[0]); atomicAdd(&bs1[16 + ln], s1[1]);
    atomicAdd(&bs2[ln], s2[0]); atomicAdd(&bs2[16 + ln], s2[1]);
  }
  __syncthreads();
  int bkt = b & 7;
  if (tid < 32) {
    atomicAdd(&sums[bkt * 64 + tid], bs1[tid]);
    atomicAdd(&sums[bkt * 64 + 32 + tid], bs2[tid]);
  }
}

// ---------------- conv2 MFMA (fused BN1+GELU staging, bucketed BN2 stats) ----------------
__global__ __launch_bounds__(256, 3) void k_conv2m(const u32* __restrict__ y1p,
    const u16* __restrict__ wfh, const u16* __restrict__ wfl,
    const float* __restrict__ scale, const float* __restrict__ shift,
    const float* __restrict__ bias, u32* __restrict__ y2p, float* __restrict__ sums)
{
  __shared__ __align__(16) u16 sin0[12480], sin1[12480];  // [10 rows][39 cols][32 c]
  __shared__ float sc[32], shf[32];
  __shared__ float bs1[64], bs2[64];
  int ohq = blockIdx.x, b = blockIdx.y, tid = threadIdx.x;
  if (tid < 32) { sc[tid] = scale[tid]; shf[tid] = shift[tid]; }
  if (tid < 64) { bs1[tid] = 0.f; bs2[tid] = 0.f; }
  __syncthreads();
  long sb = ((long)b * 1365 + (long)ohq * 312) * 32;
  const uint4* srcP = (const uint4*)(y1p + sb);
  for (int i = tid; i < 3120; i += 256) {
    uint4 p4 = srcP[i];
    int cb = (i & 7) * 4;
    u32 hw[2], lw[2];
    u32 pe[4] = { p4.x, p4.y, p4.z, p4.w };
#pragma unroll
    for (int half = 0; half < 2; ++half) {
      float va = punp(pe[half * 2 + 0]);
      float vb = punp(pe[half * 2 + 1]);
      float aa = gelu_f(va * sc[cb + half * 2 + 0] + shf[cb + half * 2 + 0]);
      float ab = gelu_f(vb * sc[cb + half * 2 + 1] + shf[cb + half * 2 + 1]);
      u32 ua = fbits(aa), ub = fbits(ab);
      float la = aa - ubits(ua & 0xFFFF0000u);
      float lb = ab - ubits(ub & 0xFFFF0000u);
      hw[half] = (ua >> 16) | (ub & 0xFFFF0000u);
      lw[half] = (fbits(la) >> 16) | (fbits(lb) & 0xFFFF0000u);
    }
    int iw = i ^ (((i >> 4) & 7) << 1);   // swizzle
    ((uint2*)sin0)[iw] = make_uint2(hw[0], hw[1]);
    ((uint2*)sin1)[iw] = make_uint2(lw[0], lw[1]);
  }
  __syncthreads();
  int w = tid >> 6, lane = tid & 63, g = lane >> 4, ln = lane & 15;
  int oct = w;
  int rowb[5], colb[5];
#pragma unroll
  for (int j = 0; j < 5; ++j) {
    int p = j * 16 + ln; if (p > 71) p = 71;
    int ohl = p / 18, ow = p - 18 * ohl;
    rowb[j] = 2 * ohl; colb[j] = 2 * ow;
  }
  f32x4 z4 = {0.f, 0.f, 0.f, 0.f};
  f32x4 acc[5];
#pragma unroll
  for (int j = 0; j < 5; ++j) acc[j] = z4;
#pragma unroll
  for (int s = 0; s < 16; ++s) {
    int kh = s >> 2, kw = s & 3;
    bf16x8 bh = *(const bf16x8*)&wfh[oct * 8192 + s * 512 + lane * 8];
    bf16x8 bl = *(const bf16x8*)&wfl[oct * 8192 + s * 512 + lane * 8];
#pragma unroll
    for (int j = 0; j < 5; ++j) {
      int colpix = (rowb[j] + kh) * 39 + colb[j] + kw;
      int off = colpix * 32 + g * 8;
      off ^= ((colpix >> 1) & 7) << 3;   // swizzle
      bf16x8 ah = *(const bf16x8*)&sin0[off];
      bf16x8 al = *(const bf16x8*)&sin1[off];
      acc[j] = mfma3(ah, al, bh, bl, acc[j]);
    }
  }
  int oc = oct * 16 + ln;
  float bv = bias[oc];
  float s1 = 0.f, s2 = 0.f;
#pragma unroll
  for (int j = 0; j < 5; ++j) {
#pragma unroll
    for (int r = 0; r < 4; ++r) {
      int po = j * 16 + g * 4 + r;
      if (po < 72) {
        long oi = ((long)b * 288 + (long)ohq * 72 + po) * 64 + oc;
        float v = acc[j][r] + bv;
        y2p[oi] = psplit(v);
        s1 += v; s2 += v * v;
      }
    }
  }
#pragma unroll
  for (int o = 16; o <= 32; o <<= 1) { s1 += __shfl_xor(s1, o); s2 += __shfl_xor(s2, o); }
  if (g == 0) { atomicAdd(&bs1[oc], s1); atomicAdd(&bs2[oc], s2); }
  __syncthreads();
  int bkt = b & 7;
  if (tid < 64) {
    atomicAdd(&sums[bkt * 128 + tid], bs1[tid]);
    atomicAdd(&sums[bkt * 128 + 64 + tid], bs2[tid]);
  }
}

// ---------------- conv3 MFMA (fused BN2+GELU staging, bucketed BN3 stats) ----------------
__global__ __launch_bounds__(256, 3) void k_conv3m(const u32* __restrict__ y2p,
    const u16* __restrict__ wfh, const u16* __restrict__ wfl,
    const float* __restrict__ scale, const float* __restrict__ shift,
    const float* __restrict__ bias, u32* __restrict__ y3p, float* __restrict__ sums)
{
  __shared__ __align__(16) u16 sin0[10368], sin1[10368];  // [9 rows][18 cols][64 c]
  __shared__ float sc[64], shf[64];
  __shared__ float bs1[128], bs2[128];
  int hh = blockIdx.x, b = blockIdx.y, tid = threadIdx.x;
  if (tid < 64) { sc[tid] = scale[tid]; shf[tid] = shift[tid]; }
  if (tid < 128) { bs1[tid] = 0.f; bs2[tid] = 0.f; }
  __syncthreads();
  long sb = ((long)b * 288 + (long)hh * 126) * 64;
  const uint4* srcP = (const uint4*)(y2p + sb);
  for (int i = tid; i < 2592; i += 256) {
    uint4 p4 = srcP[i];
    int cb = (i & 15) * 4;
    u32 hw[2], lw[2];
    u32 pe[4] = { p4.x, p4.y, p4.z, p4.w };
#pragma unroll
    for (int half = 0; half < 2; ++half) {
      float va = punp(pe[half * 2 + 0]);
      float vb = punp(pe[half * 2 + 1]);
      float aa = gelu_f(va * sc[cb + half * 2 + 0] + shf[cb + half * 2 + 0]);
      float ab = gelu_f(vb * sc[cb + half * 2 + 1] + shf[cb + half * 2 + 1]);
      u32 ua = fbits(aa), ub = fbits(ab);
      float la = aa - ubits(ua & 0xFFFF0000u);
      float lb = ab - ubits(ub & 0xFFFF0000u);
      hw[half] = (ua >> 16) | (ub & 0xFFFF0000u);
      lw[half] = (fbits(la) >> 16) | (fbits(lb) & 0xFFFF0000u);
    }
    int iw = i ^ (((i >> 4) & 7) << 1);   // swizzle
    ((uint2*)sin0)[iw] = make_uint2(hw[0], hw[1]);
    ((uint2*)sin1)[iw] = make_uint2(lw[0], lw[1]);
  }
  __syncthreads();
  int w = tid >> 6, lane = tid & 63, g = lane >> 4, ln = lane & 15;
  int oct0 = w * 2;
  f32x4 z4 = {0.f, 0.f, 0.f, 0.f};
  f32x4 acc[7][2];
#pragma unroll
  for (int j = 0; j < 7; ++j) { acc[j][0] = z4; acc[j][1] = z4; }
#pragma unroll 6
  for (int s = 0; s < 18; ++s) {
    const int kh = s / 6, rm = s % 6;
    const int kw = rm >> 1, ch = rm & 1;
    bf16x8 bh0 = *(const bf16x8*)&wfh[oct0 * 9216 + s * 512 + lane * 8];
    bf16x8 bl0 = *(const bf16x8*)&wfl[oct0 * 9216 + s * 512 + lane * 8];
    bf16x8 bh1 = *(const bf16x8*)&wfh[(oct0 + 1) * 9216 + s * 512 + lane * 8];
    bf16x8 bl1 = *(const bf16x8*)&wfl[(oct0 + 1) * 9216 + s * 512 + lane * 8];
#pragma unroll
    for (int j = 0; j < 7; ++j) {
      int colpix = (j + kh) * 18 + ln + kw;
      int off = colpix * 64 + ch * 32 + g * 8;
      off ^= (colpix & 7) << 3;   // swizzle
      bf16x8 ah = *(const bf16x8*)&sin0[off];
      bf16x8 al = *(const bf16x8*)&sin1[off];
      acc[j][0] = mfma3(ah, al, bh0, bl0, acc[j][0]);
      acc[j][1] = mfma3(ah, al, bh1, bl1, acc[j][1]);
    }
  }
  float s1[2] = {0.f, 0.f}, s2[2] = {0.f, 0.f};
#pragma unroll
  for (int j = 0; j < 7; ++j) {
#pragma unroll
    for (int o2 = 0; o2 < 2; ++o2) {
      int oc = (oct0 + o2) * 16 + ln;
      float bv = bias[oc];
#pragma unroll
      for (int r = 0; r < 4; ++r) {
        int owo = g * 4 + r;
        long oi = ((long)b * 224 + (hh * 7 + j) * 16 + owo) * 128 + oc;
        float v = acc[j][o2][r] + bv;
        y3p[oi] = psplit(v);
        s1[o2] += v; s2[o2] += v * v;
      }
    }
  }
#pragma unroll
  for (int o = 16; o <= 32; o <<= 1) {
    s1[0] += __shfl_xor(s1[0], o); s1[1] += __shfl_xor(s1[1], o);
    s2[0] += __shfl_xor(s2[0], o); s2[1] += __shfl_xor(s2[1], o);
  }
  if (g == 0) {
    atomicAdd(&bs1[oct0 * 16 + ln], s1[0]); atomicAdd(&bs1[(oct0 + 1) * 16 + ln], s1[1]);
    atomicAdd(&bs2[oct0 * 16 + ln], s2[0]); atomicAdd(&bs2[(oct0 + 1) * 16 + ln], s2[1]);
  }
  __syncthreads();
  int bkt = b & 7;
  if (tid < 128) {
    atomicAdd(&sums[bkt * 256 + tid], bs1[tid]);
    atomicAdd(&sums[bkt * 256 + 128 + tid], bs2[tid]);
  }
}

// ---------------- BN finalize over 8 buckets ----------------
__global__ void k_bn_finalize(const float* __restrict__ sums, const float* __restrict__ g,
    const float* __restrict__ b, float* __restrict__ scale, float* __restrict__ shift,
    int C, float invN)
{
  int c = threadIdx.x;
  if (c < C) {
    float s1 = 0.f, s2 = 0.f;
#pragma unroll
    for (int k = 0; k < 8; ++k) {
      s1 += sums[k * 2 * C + c];
      s2 += sums[k * 2 * C + C + c];
    }
    float m = s1 * invN;
    float var = s2 * invN - m * m;
    float sc = g[c] * rsqrtf(var + 1e-5f);
    scale[c] = sc;
    shift[c] = b[c] - m * sc;
  }
}

// ---------------- proj MFMA split-K, 128-token M-tile (fused BN3+GELU on A-staging) ----------------
__global__ __launch_bounds__(256, 2) void k_projm(const u32* __restrict__ y3p,
    const u16* __restrict__ bh_g, const u16* __restrict__ bl_g,
    const float* __restrict__ scale, const float* __restrict__ shift,
    float* __restrict__ part)
{
  __shared__ __align__(16) u16 Ah[4096], Al[4096];   // [128 tok][32 k]
  __shared__ __align__(16) u16 Bh[8192], Bl[8192];   // [16 oct][512]
  __shared__ float sc3[128], sh3[128];
  int m0 = blockIdx.x * 128, by = blockIdx.y, tid = threadIdx.x;
  int w = tid >> 6, lane = tid & 63, g = lane >> 4, ln = lane & 15;
  if (tid < 128) { sc3[tid] = scale[tid]; sh3[tid] = shift[tid]; }
  f32x4 z4 = {0.f, 0.f, 0.f, 0.f};
  f32x4 acc[2][16];
#pragma unroll
  for (int p = 0; p < 2; ++p)
#pragma unroll
    for (int o = 0; o < 16; ++o) acc[p][o] = z4;
  for (int ks = 0; ks < 28; ++ks) {
    __syncthreads();
    long k0 = ((long)by * 28 + ks) * 32;
    int cbase = (int)(k0 & 127);
#pragma unroll
    for (int ii = 0; ii < 4; ++ii) {
      int i = tid + ii * 256;
      int row = i >> 3, q = i & 7;
      uint4 p4 = *((const uint4*)(y3p + (long)(m0 + row) * 28672 + k0) + q);
      u32 pe[4] = { p4.x, p4.y, p4.z, p4.w };
      int c0 = cbase + q * 4;
      u16 hs[4], ls[4];
#pragma unroll
      for (int j = 0; j < 4; ++j) {
        float v = punp(pe[j]);
        float a = gelu_f(v * sc3[c0 + j] + sh3[c0 + j]);
        u32 ua = fbits(a);
        float la = a - ubits(ua & 0xFFFF0000u);
        hs[j] = (u16)(ua >> 16);
        ls[j] = (u16)(fbits(la) >> 16);
      }
      ((uint2*)Ah)[i] = make_uint2((u32)hs[0] | ((u32)hs[1] << 16), (u32)hs[2] | ((u32)hs[3] << 16));
      ((uint2*)Al)[i] = make_uint2((u32)ls[0] | ((u32)ls[1] << 16), (u32)ls[2] | ((u32)ls[3] << 16));
    }
    int ksg = by * 28 + ks;
#pragma unroll
    for (int ii = 0; ii < 8; ++ii) {
      int i = tid + ii * 256;
      int arr = i >> 10, idx = i & 1023, oct = idx >> 6, r2 = idx & 63;
      const u16* src = arr ? bl_g : bh_g;
      u16* dst = arr ? Bl : Bh;
      ((uint4*)dst)[idx] = *((const uint4*)(src + ((long)oct * 896 + ksg) * 512) + r2);
    }
    __syncthreads();
    bf16x8 a_h[2], a_l[2];
#pragma unroll
    for (int pt = 0; pt < 2; ++pt) {
      int off = ((2 * w + pt) * 16 + ln) * 32 + g * 8;
      a_h[pt] = *(const bf16x8*)&Ah[off];
      a_l[pt] = *(const bf16x8*)&Al[off];
    }
#pragma unroll
    for (int oct = 0; oct < 16; ++oct) {
      bf16x8 bh = *(const bf16x8*)&Bh[oct * 512 + lane * 8];
      bf16x8 bl = *(const bf16x8*)&Bl[oct * 512 + lane * 8];
#pragma unroll
      for (int pt = 0; pt < 2; ++pt)
        acc[pt][oct] = mfma3(a_h[pt], a_l[pt], bh, bl, acc[pt][oct]);
    }
  }
#pragma unroll
  for (int pt = 0; pt < 2; ++pt)
#pragma unroll
    for (int oct = 0; oct < 16; ++oct) {
      int oc = oct * 16 + ln;
#pragma unroll
      for (int r = 0; r < 4; ++r) {
        int tok = m0 + (2 * w + pt) * 16 + g * 4 + r;
        part[((long)by * 1024 + tok) * 256 + oc] = acc[pt][oct][r];
      }
    }
}

// ---------------- split-K reduce + bias + LN + GELU ----------------
__global__ __launch_bounds__(256) void k_lnred(const float* __restrict__ part,
    const float* __restrict__ pb, const float* __restrict__ g, const float* __restrict__ be,
    float* __restrict__ h, u16* __restrict__ hb)
{
  int b = blockIdx.x, d = threadIdx.x;
  float s = pb[d];
#pragma unroll
  for (int ks = 0; ks < 32; ++ks) s += part[((long)ks * 1024 + b) * 256 + d];
  __shared__ float red[4];
  float t = s;
  for (int o = 32; o; o >>= 1) t += __shfl_xor(t, o);
  if ((d & 63) == 0) red[d >> 6] = t;
  __syncthreads();
  float mean = (red[0] + red[1] + red[2] + red[3]) * (1.f / 256.f);
  __syncthreads();
  float dv = s - mean;
  t = dv * dv;
  for (int o = 32; o; o >>= 1) t += __shfl_xor(t, o);
  if ((d & 63) == 0) red[d >> 6] = t;
  __syncthreads();
  float var = (red[0] + red[1] + red[2] + red[3]) * (1.f / 256.f);
  float hv = gelu_f(g[d] * dv * rsqrtf(var + 1e-5f) + be[d]);
  h[b * 256 + d] = hv;
  hb[b * 256 + d] = f2bf(hv);
}

// ---------------- generic plain-bf16 MFMA GEMM ----------------
__global__ __launch_bounds__(256, 2) void k_gemmb(const u16* __restrict__ A, long aZ, int K,
    const u16* __restrict__ Bf, int noct_tot,
    const float* __restrict__ bias, int biasZ,
    void* __restrict__ C, long cZ, int ldc, int outbf, int act)
{
  __shared__ __align__(16) u16 As[2048];
  __shared__ __align__(16) u16 Bs[8192];
  int m0 = blockIdx.x * 64, nb = blockIdx.y, z = blockIdx.z, tid = threadIdx.x;
  int w = tid >> 6, lane = tid & 63, g = lane >> 4, ln = lane & 15;
  const u16* Az = A + (long)z * aZ;
  int kn = K >> 5;
  f32x4 z4 = {0.f, 0.f, 0.f, 0.f};
  f32x4 acc[16];
#pragma unroll
  for (int o = 0; o < 16; ++o) acc[o] = z4;
  for (int ks = 0; ks < kn; ++ks) {
    __syncthreads();
    {
      int row = tid >> 2, q = tid & 3;
      ((uint4*)As)[tid] = *((const uint4*)(Az + (long)(m0 + row) * K + ks * 32) + q);
    }
#pragma unroll
    for (int ii = 0; ii < 4; ++ii) {
      int i = tid + ii * 256;
      int oct = i >> 6, r2 = i & 63;
      const u16* src = Bf + (((long)z * noct_tot + nb * 16 + oct) * kn + ks) * 512;
      ((uint4*)Bs)[i] = ((const uint4*)src)[r2];
    }
    __syncthreads();
    bf16x8 a = *(const bf16x8*)&As[(w * 16 + ln) * 32 + g * 8];
#pragma unroll
    for (int oct = 0; oct < 16; ++oct) {
      bf16x8 bb = *(const bf16x8*)&Bs[oct * 512 + lane * 8];
      acc[oct] = __builtin_amdgcn_mfma_f32_16x16x32_bf16(a, bb, acc[oct], 0, 0, 0);
    }
  }
#pragma unroll
  for (int oct = 0; oct < 16; ++oct) {
    int n = nb * 256 + oct * 16 + ln;
    float bv = bias[z * biasZ + n];
#pragma unroll
    for (int r = 0; r < 4; ++r) {
      int tok = m0 + w * 16 + g * 4 + r;
      float v = acc[oct][r] + bv;
      if (act) v = gelu_f(v);
      long off = (long)z * cZ + (long)tok * ldc + n;
      if (outbf) ((u16*)C)[off] = f2bf(v);
      else ((float*)C)[off] = v;
    }
  }
}

// ---------------- router ----------------
__global__ __launch_bounds__(64) void k_router(const float* __restrict__ h,
    const float* __restrict__ rw, const float* __restrict__ eb,
    float* __restrict__ wts, int* __restrict__ idx,
    float* __restrict__ pm_sum, float* __restrict__ z_sum)
{
  int b = blockIdx.x, lane = threadIdx.x;
  float4 hv = *(const float4*)(h + b * 256 + lane * 4);
  float logit[8];
#pragma unroll
  for (int e = 0; e < 8; ++e) {
    float4 wv = *(const float4*)(rw + e * 256 + lane * 4);
    float p = hv.x * wv.x + hv.y * wv.y + hv.z * wv.z + hv.w * wv.w;
    for (int o = 32; o; o >>= 1) p += __shfl_xor(p, o);
    logit[e] = p + eb[e];
  }
  float mx = logit[0];
#pragma unroll
  for (int e = 1; e < 8; ++e) mx = fmaxf(mx, logit[e]);
  float pr[8]; float se = 0.f;
#pragma unroll
  for (int e = 0; e < 8; ++e) { pr[e] = expf(logit[e] - mx); se += pr[e]; }
  float inv = 1.f / se;
#pragma unroll
  for (int e = 0; e < 8; ++e) pr[e] *= inv;
  int i0 = 0; float v0 = pr[0];
#pragma unroll
  for (int e = 1; e < 8; ++e) if (pr[e] > v0) { v0 = pr[e]; i0 = e; }
  int i1 = -1; float v1 = -1.f;
#pragma unroll
  for (int e = 0; e < 8; ++e) if (e != i0 && pr[e] > v1) { v1 = pr[e]; i1 = e; }
  if (lane == 0) {
    float ssum = v0 + v1 + 1e-8f;
    wts[2 * b] = v0 / ssum; wts[2 * b + 1] = v1 / ssum;
    idx[2 * b] = i0; idx[2 * b + 1] = i1;
    float zz = 0.f;
#pragma unroll
    for (int e = 0; e < 8; ++e) zz += logit[e] * logit[e];
    atomicAdd(z_sum, zz);
  }
  if (lane < 8) atomicAdd(&pm_sum[lane], pr[lane]);
}

// ---------------- combine + 0.5*shared + final LN ----------------
__global__ __launch_bounds__(256) void k_combine_ln(const float* __restrict__ eout,
    const float* __restrict__ sharedB, const float* __restrict__ wts, const int* __restrict__ idx,
    const float* __restrict__ g, const float* __restrict__ bb, float* __restrict__ out)
{
  int b = blockIdx.x, d = threadIdx.x;
  float w0 = wts[2 * b], w1 = wts[2 * b + 1];
  int i0 = idx[2 * b], i1 = idx[2 * b + 1];
  float val = w0 * eout[(long)i0 * 262144 + b * 256 + d]
            + w1 * eout[(long)i1 * 262144 + b * 256 + d]
            + 0.5f * sharedB[b * 256 + d];
  __shared__ float red[4];
  float s = val;
  for (int o = 32; o; o >>= 1) s += __shfl_xor(s, o);
  if ((d & 63) == 0) red[d >> 6] = s;
  __syncthreads();
  float mean = (red[0] + red[1] + red[2] + red[3]) * (1.f / 256.f);
  __syncthreads();
  float dv = val - mean;
  s = dv * dv;
  for (int o = 32; o; o >>= 1) s += __shfl_xor(s, o);
  if ((d & 63) == 0) red[d >> 6] = s;
  __syncthreads();
  float var = (red[0] + red[1] + red[2] + red[3]) * (1.f / 256.f);
  out[b * 256 + d] = g[d] * dv * rsqrtf(var + 1e-5f) + bb[d];
}

// ---------------- aux losses ----------------
__global__ void k_losses(const float* __restrict__ pm_sum, const float* __restrict__ z_sum,
                         float* __restrict__ out)
{
  if (threadIdx.x == 0 && blockIdx.x == 0) {
    float lb = 0.f;
    for (int e = 0; e < 8; ++e) {
      float pm = pm_sum[e] * (1.f / 1024.f);
      float dd = pm - 0.125f;
      lb += dd * dd;
    }
    out[262144] = lb * 8.f;
    out[262145] = z_sum[0] * (1.f / 8192.f) * 0.001f;
  }
}

extern "C" void kernel_launch(void* const* d_in, const int* in_sizes, int n_in,
                              void* d_out, int out_size, void* d_ws, size_t ws_size,
                              hipStream_t stream)
{
  const float* x     = (const float*)d_in[0];
  const float* c1w   = (const float*)d_in[1];
  const float* c1b   = (const float*)d_in[2];
  const float* bn1g  = (const float*)d_in[3];
  const float* bn1b  = (const float*)d_in[4];
  const float* c2w   = (const float*)d_in[5];
  const float* c2b   = (const float*)d_in[6];
  const float* bn2g  = (const float*)d_in[7];
  const float* bn2b  = (const float*)d_in[8];
  const float* c3w   = (const float*)d_in[9];
  const float* c3b   = (const float*)d_in[10];
  const float* bn3g  = (const float*)d_in[11];
  const float* bn3b  = (const float*)d_in[12];
  const float* projw = (const float*)d_in[13];
  const float* projb = (const float*)d_in[14];
  const float* lng   = (const float*)d_in[15];
  const float* lnb   = (const float*)d_in[16];
  const float* rw    = (const float*)d_in[17];
  const float* ebias = (const float*)d_in[18];
  const float* ew1   = (const float*)d_in[19];
  const float* eb1   = (const float*)d_in[20];
  const float* ew2   = (const float*)d_in[21];
  const float* eb2   = (const float*)d_in[22];
  const float* sw1   = (const float*)d_in[23];
  const float* sb1   = (const float*)d_in[24];
  const float* sw2   = (const float*)d_in[25];
  const float* sb2   = (const float*)d_in[26];
  const float* mlng  = (const float*)d_in[27];
  const float* mlnb  = (const float*)d_in[28];
  float* out = (float*)d_out;

  char* W = (char*)d_ws;
  u32* y1p = (u32*)(W + 0);              // 178,913,280 B
  u32* y2p = (u32*)(W + 178913280L);     // 75,497,472 B
  u32* y3p = (u32*)(W + 0);              // 117,440,512 B (alias dead y1)
  u16* wfph = (u16*)(W + 254410752L);
  u16* wfpl = (u16*)(W + 269090816L);
  u16* wf1h = (u16*)(W + 283770880L);
  u16* wf1l = (u16*)(W + 283787264L);
  u16* wf2h = (u16*)(W + 283803648L);
  u16* wf2l = (u16*)(W + 283869184L);
  u16* wf3h = (u16*)(W + 283934720L);
  u16* wf3l = (u16*)(W + 284082176L);
  float* stats = (float*)(W + 284229632L);  // 4096 floats
  float* wtsb  = (float*)(W + 284246016L);
  int*   idxb  = (int*)(W + 284254208L);
  float* hbuf  = (float*)(W + 284262400L);
  float* shB   = (float*)(W + 286359552L);
  // tail region inside the y2p span — all used only after conv3m completes
  float* part  = (float*)(W + 178913280L);  // 33,554,432 B
  u16* hid     = (u16*)(W + 212467712L);    // 8,388,608 B
  u16* ewf1    = (u16*)(W + 220856320L);    // 2,097,152 B
  u16* ewf2    = (u16*)(W + 222953472L);    // 2,097,152 B
  u16* swf1    = (u16*)(W + 225050624L);    // 131,072 B
  u16* swf2    = (u16*)(W + 225181696L);    // 131,072 B
  float* eoutB = (float*)(W + 225312768L);  // 8,388,608 B
  u16* hbufb   = (u16*)(W + 233701376L);    // 524,288 B
  u16* sh1b    = (u16*)(W + 234225664L);    // 524,288 B

  // stats layout: buckets then finals
  float* sums1 = stats;               // 8 x 64
  float* sums2 = stats + 512;         // 8 x 128
  float* sums3 = stats + 1536;        // 8 x 256
  float* scale1 = stats + 3584; float* shift1 = stats + 3616;
  float* scale2 = stats + 3648; float* shift2 = stats + 3712;
  float* scale3 = stats + 3776; float* shift3 = stats + 3904;
  float* pm    = stats + 4032;  float* zsum  = stats + 4040;

  dim3 blk(256);
  k_zero<<<dim3(16), blk, 0, stream>>>(stats, 4096);
  k_wprep1<<<dim3(32), blk, 0, stream>>>(c1w, wf1h, wf1l);
  k_wprep2<<<dim3(128), blk, 0, stream>>>(c2w, wf2h, wf2l);
  k_wprep3<<<dim3(288), blk, 0, stream>>>(c3w, wf3h, wf3l);
  k_wprepP<<<dim3(32, 16), blk, 0, stream>>>(projw, wfph, wfpl);

  k_conv1m<<<dim3(9, 1024), blk, 0, stream>>>(x, wf1h, wf1l, c1b, y1p, sums1);
  k_bn_finalize<<<1, 32, 0, stream>>>(sums1, bn1g, bn1b, scale1, shift1, 32, 1.f / 1397760.f);

  k_conv2m<<<dim3(4, 1024), blk, 0, stream>>>(y1p, wf2h, wf2l, scale1, shift1, c2b, y2p, sums2);
  k_bn_finalize<<<1, 64, 0, stream>>>(sums2, bn2g, bn2b, scale2, shift2, 64, 1.f / 294912.f);

  k_conv3m<<<dim3(2, 1024), blk, 0, stream>>>(y2p, wf3h, wf3l, scale2, shift2, c3b, y3p, sums3);
  k_bn_finalize<<<1, 128, 0, stream>>>(sums3, bn3g, bn3b, scale3, shift3, 128, 1.f / 229376.f);

  // expert/shared weight preps (y2p region is dead now)
  k_wprepG<<<dim3(4096), blk, 0, stream>>>(ew1, ewf1, 512, 256, 1048576L);
  k_wprepG<<<dim3(4096), blk, 0, stream>>>(ew2, ewf2, 256, 512, 1048576L);
  k_wprepG<<<dim3(256), blk, 0, stream>>>(sw1, swf1, 256, 256, 65536L);
  k_wprepG<<<dim3(256), blk, 0, stream>>>(sw2, swf2, 256, 256, 65536L);

  k_projm<<<dim3(8, 32), blk, 0, stream>>>(y3p, wfph, wfpl, scale3, shift3, part);
  k_lnred<<<dim3(1024), blk, 0, stream>>>(part, projb, lng, lnb, hbuf, hbufb);

  k_router<<<dim3(1024), dim3(64), 0, stream>>>(hbuf, rw, ebias, wtsb, idxb, pm, zsum);

  // experts (dense) + shared, plain bf16 MFMA
  k_gemmb<<<dim3(16, 2, 8), blk, 0, stream>>>(hbufb, 0L, 256, ewf1, 32, eb1, 512,
                                              (void*)hid, 524288L, 512, 1, 1);
  k_gemmb<<<dim3(16, 1, 8), blk, 0, stream>>>(hid, 524288L, 512, ewf2, 16, eb2, 256,
                                              (void*)eoutB, 262144L, 256, 0, 0);
  k_gemmb<<<dim3(16, 1, 1), blk, 0, stream>>>(hbufb, 0L, 256, swf1, 16, sb1, 0,
                                              (void*)sh1b, 0L, 256, 1, 1);
  k_gemmb<<<dim3(16, 1, 1), blk, 0, stream>>>(sh1b, 0L, 256, swf2, 16, sb2, 0,
                                              (void*)shB, 0L, 256, 0, 0);

  k_combine_ln<<<dim3(1024), blk, 0, stream>>>(eoutB, shB, wtsb, idxb, mlng, mlnb, out);
  k_losses<<<1, 64, 0, stream>>>(pm, zsum, out);
}

// Round 12
// 712.693 us; speedup vs baseline: 1.9284x; 1.0859x over previous
//
#include <hip/hip_runtime.h>
#include <hip/hip_bf16.h>
#include <math.h>

typedef unsigned short u16;
typedef unsigned int u32;
typedef __attribute__((ext_vector_type(8))) short bf16x8;
typedef __attribute__((ext_vector_type(4))) float f32x4;

#define DEV __device__ __forceinline__

DEV float gelu_f(float x) { return 0.5f * x * (1.0f + erff(x * 0.70710678118654752f)); }
DEV u16 f2bf(float f) { u32 u = __builtin_bit_cast(u32, f); u = (u + 0x7FFFu + ((u >> 16) & 1u)) >> 16; return (u16)u; }
DEV float bf2f(u16 h) { return __builtin_bit_cast(float, (u32)h << 16); }
DEV u32 fbits(float f) { return __builtin_bit_cast(u32, f); }
DEV float ubits(u32 u) { return __builtin_bit_cast(float, u); }
DEV u32 psplit(float v) {
  u32 u = fbits(v);
  float lo = v - ubits(u & 0xFFFF0000u);
  return (u >> 16) | (fbits(lo) & 0xFFFF0000u);
}
DEV float punp(u32 p) { return ubits(p << 16) + ubits(p & 0xFFFF0000u); }
DEV f32x4 mfma3(bf16x8 ah, bf16x8 al, bf16x8 bh, bf16x8 bl, f32x4 c) {
  c = __builtin_amdgcn_mfma_f32_16x16x32_bf16(al, bh, c, 0, 0, 0);
  c = __builtin_amdgcn_mfma_f32_16x16x32_bf16(ah, bl, c, 0, 0, 0);
  c = __builtin_amdgcn_mfma_f32_16x16x32_bf16(ah, bh, c, 0, 0, 0);
  return c;
}

// ---------------- zero stats ----------------
__global__ void k_zero(float* p, int n) {
  int i = blockIdx.x * blockDim.x + threadIdx.x;
  if (i < n) p[i] = 0.f;
}

// ---------------- conv weight frag preps ----------------
__global__ void k_wprep1(const float* __restrict__ w, u16* __restrict__ wh, u16* __restrict__ wl) {
  int idx = blockIdx.x * 256 + threadIdx.x; if (idx >= 8192) return;
  int j = idx & 7, lane = (idx >> 3) & 63, s = (idx >> 9) & 7, oct = idx >> 12;
  int oc = oct * 16 + (lane & 15);
  int kl = ((lane >> 4) << 3) + j;
  int kw = kl >> 2, c = kl & 3, kh = s;
  float v = w[((oc * 4 + c) * 8 + kh) * 8 + kw];
  u16 h = f2bf(v); wh[idx] = h; wl[idx] = f2bf(v - bf2f(h));
}
__global__ void k_wprep2(const float* __restrict__ w, u16* __restrict__ wh, u16* __restrict__ wl) {
  int idx = blockIdx.x * 256 + threadIdx.x; if (idx >= 32768) return;
  int j = idx & 7, lane = (idx >> 3) & 63, s = (idx >> 9) & 15, oct = idx >> 13;
  int oc = oct * 16 + (lane & 15);
  int k = s * 32 + ((lane >> 4) << 3) + j;
  int kh = k >> 7, kw = (k >> 5) & 3, c = k & 31;
  float v = w[((oc * 32 + c) * 4 + kh) * 4 + kw];
  u16 h = f2bf(v); wh[idx] = h; wl[idx] = f2bf(v - bf2f(h));
}
__global__ void k_wprep3(const float* __restrict__ w, u16* __restrict__ wh, u16* __restrict__ wl) {
  int idx = blockIdx.x * 256 + threadIdx.x; if (idx >= 73728) return;
  int j = idx & 7, lane = (idx >> 3) & 63, rest = idx >> 9;
  int s = rest % 18, oct = rest / 18;
  int oc = oct * 16 + (lane & 15);
  int k = s * 32 + ((lane >> 4) << 3) + j;
  int kh = k / 192, r = k - kh * 192;
  int kw = r >> 6, c = r & 63;
  float v = w[((oc * 64 + c) * 3 + kh) * 3 + kw];
  u16 h = f2bf(v); wh[idx] = h; wl[idx] = f2bf(v - bf2f(h));
}
// proj weight prep, LDS-transpose tiled
__global__ __launch_bounds__(256) void k_wprepP(const float* __restrict__ w,
    u16* __restrict__ wh, u16* __restrict__ wl)
{
  __shared__ float tile[16][4][225];
  int q = blockIdx.x, oct = blockIdx.y, tid = threadIdx.x;
  for (int i = tid; i < 3584; i += 256) {
    int n = i / 224, rem = i % 224, e = rem / 56, f4 = rem % 56;
    float4 v = *(const float4*)(w + (long)(oct * 16 + n) * 28672 + (4 * q + e) * 224 + f4 * 4);
    tile[n][e][f4 * 4 + 0] = v.x; tile[n][e][f4 * 4 + 1] = v.y;
    tile[n][e][f4 * 4 + 2] = v.z; tile[n][e][f4 * 4 + 3] = v.w;
  }
  __syncthreads();
  int g = (q >> 1) & 3, j0 = 4 * (q & 1), sgb = q >> 3;
  for (int o = tid; o < 3584; o += 256) {
    int pix = o >> 4, ln = o & 15;
    u16 hs[4], ls[4];
#pragma unroll
    for (int e = 0; e < 4; ++e) {
      float v = tile[ln][e][pix];
      u16 h = f2bf(v); hs[e] = h; ls[e] = f2bf(v - bf2f(h));
    }
    long base = (((long)oct * 896 + pix * 4 + sgb) * 64 + g * 16 + ln) * 8 + j0;
    *(uint2*)(wh + base) = make_uint2((u32)hs[0] | ((u32)hs[1] << 16), (u32)hs[2] | ((u32)hs[3] << 16));
    *(uint2*)(wl + base) = make_uint2((u32)ls[0] | ((u32)ls[1] << 16), (u32)ls[2] | ((u32)ls[3] << 16));
  }
}
// generic plain-bf16 frag prep for expert/shared weights W[Z][N][K]
__global__ void k_wprepG(const float* __restrict__ w, u16* __restrict__ wf,
                         int N, int K, long total)
{
  long idx = (long)blockIdx.x * 256 + threadIdx.x; if (idx >= total) return;
  int j = (int)(idx & 7); int lane = (int)((idx >> 3) & 63); long rest = idx >> 9;
  int kn = K >> 5;
  int s = (int)(rest % kn); long rest2 = rest / kn;
  int noct = N >> 4;
  int oct = (int)(rest2 % noct); int z = (int)(rest2 / noct);
  int n = oct * 16 + (lane & 15);
  int k = s * 32 + ((lane >> 4) << 3) + j;
  wf[idx] = f2bf(w[((long)z * N + n) * K + k]);
}

// ---------------- conv1 staging element processing ----------------
DEV void c1_store(u16* sin0, u16* sin1, int i, float4 v0, float4 v1) {
  const float* a0 = (const float*)&v0;
  const float* a1 = (const float*)&v1;
  int cp = i / 800, rem = i - cp * 800, r = rem / 40, q = rem - r * 40;
#pragma unroll
  for (int m = 0; m < 4; ++m) {
    float f0 = a0[m], f1 = a1[m];
    u32 u0 = fbits(f0), u1 = fbits(f1);
    u32 hh = (u0 >> 16) | (u1 & 0xFFFF0000u);
    float l0 = f0 - ubits(u0 & 0xFFFF0000u);
    float l1 = f1 - ubits(u1 & 0xFFFF0000u);
    u32 ll = (fbits(l0) >> 16) | (fbits(l1) & 0xFFFF0000u);
    int col = q * 4 + m;
    int idx = r * 320 + col * 2 + cp;
    idx ^= ((col >> 4) & 3) << 2;   // swizzle
    ((u32*)sin0)[idx] = hh;
    ((u32*)sin1)[idx] = ll;
  }
}

// ---------------- conv1 MFMA + fused bucketed BN1 stats ----------------
__global__ __launch_bounds__(256, 3) void k_conv1m(const float* __restrict__ x,
    const u16* __restrict__ wfh, const u16* __restrict__ wfl,
    const float* __restrict__ bias, u32* __restrict__ y1p, float* __restrict__ sums)
{
  __shared__ __align__(16) u16 sin0[12800], sin1[12800];   // [20 rows][160 cols][4 c]
  __shared__ float bs1[32], bs2[32];
  int ohp = blockIdx.x, b = blockIdx.y, tid = threadIdx.x;
  int row0 = ohp * 16;
  if (tid < 32) { bs1[tid] = 0.f; bs2[tid] = 0.f; }
  // pipelined staging: issue all 6 uniform loads, then process, then tail
  {
    float4 v0r[6], v1r[6];
#pragma unroll
    for (int it = 0; it < 6; ++it) {
      int i = tid + it * 256;
      int cp = i / 800, rem = i - cp * 800, r = rem / 40, q = rem - r * 40;
      int grow = row0 + r;
      float4 z = make_float4(0.f, 0.f, 0.f, 0.f);
      v0r[it] = z; v1r[it] = z;
      if (grow < 144) {
        long base = ((long)b * 4 + 2 * cp) * 23040 + (long)grow * 160 + q * 4;
        v0r[it] = *(const float4*)(x + base);
        v1r[it] = *(const float4*)(x + base + 23040);
      }
    }
#pragma unroll
    for (int it = 0; it < 6; ++it)
      c1_store(sin0, sin1, tid + it * 256, v0r[it], v1r[it]);
    if (tid < 64) {
      int i = 1536 + tid;
      int cp = i / 800, rem = i - cp * 800, r = rem / 40, q = rem - r * 40;
      int grow = row0 + r;
      float4 v0 = make_float4(0.f, 0.f, 0.f, 0.f), v1 = v0;
      if (grow < 144) {
        long base = ((long)b * 4 + 2 * cp) * 23040 + (long)grow * 160 + q * 4;
        v0 = *(const float4*)(x + base);
        v1 = *(const float4*)(x + base + 23040);
      }
      c1_store(sin0, sin1, i, v0, v1);
    }
  }
  __syncthreads();
  int w = tid >> 6, lane = tid & 63, g = lane >> 4, ln = lane & 15;
  int ohls[3], owcs[3];
#pragma unroll
  for (int jj = 0; jj < 3; ++jj) {
    int j = w + 4 * jj;
    ohls[jj] = j / 3;
    int owc = (j % 3) * 16 + ln; if (owc > 38) owc = 38;
    owcs[jj] = owc;
  }
  f32x4 z4 = {0.f, 0.f, 0.f, 0.f};
  f32x4 acc[3][2];
#pragma unroll
  for (int jj = 0; jj < 3; ++jj) { acc[jj][0] = z4; acc[jj][1] = z4; }
#pragma unroll
  for (int kh = 0; kh < 8; ++kh) {
    bf16x8 bh0 = *(const bf16x8*)&wfh[kh * 512 + lane * 8];
    bf16x8 bl0 = *(const bf16x8*)&wfl[kh * 512 + lane * 8];
    bf16x8 bh1 = *(const bf16x8*)&wfh[4096 + kh * 512 + lane * 8];
    bf16x8 bl1 = *(const bf16x8*)&wfl[4096 + kh * 512 + lane * 8];
#pragma unroll
    for (int jj = 0; jj < 3; ++jj) {
      int col = owcs[jj] * 4 + g * 2;
      int off = (4 * ohls[jj] + kh) * 640 + col * 4;
      off ^= ((col >> 4) & 3) << 3;   // swizzle
      bf16x8 ah = *(const bf16x8*)&sin0[off];
      bf16x8 al = *(const bf16x8*)&sin1[off];
      acc[jj][0] = mfma3(ah, al, bh0, bl0, acc[jj][0]);
      acc[jj][1] = mfma3(ah, al, bh1, bl1, acc[jj][1]);
    }
  }
  float s1[2] = {0.f, 0.f}, s2[2] = {0.f, 0.f};
#pragma unroll
  for (int jj = 0; jj < 3; ++jj) {
    int j = w + 4 * jj;
    int ohl = j / 3, owt = j % 3;
    int oh = 4 * ohp + ohl;
    if (oh >= 35) continue;
#pragma unroll
    for (int oct = 0; oct < 2; ++oct) {
      int oc = oct * 16 + ln;
      float bv = bias[oc];
#pragma unroll
      for (int r = 0; r < 4; ++r) {
        int owo = owt * 16 + g * 4 + r;
        if (owo < 39) {
          long oi = ((long)b * 1365 + oh * 39 + owo) * 32 + oc;
          float v = acc[jj][oct][r] + bv;
          y1p[oi] = psplit(v);
          s1[oct] += v; s2[oct] += v * v;
        }
      }
    }
  }
#pragma unroll
  for (int o = 16; o <= 32; o <<= 1) {
    s1[0] += __shfl_xor(s1[0], o); s1[1] += __shfl_xor(s1[1], o);
    s2[0] += __shfl_xor(s2[0], o); s2[1] += __shfl_xor(s2[1], o);
  }
  if (g == 0) {
    atomicAdd(&bs1[ln], s1[0]); atomicAdd(&bs1[16 + ln], s1[1]);
    atomicAdd(&bs2[ln], s2[0]); atomicAdd(&bs2[16 + ln], s2[1]);
  }
  __syncthreads();
  int bkt = b & 7;
  if (tid < 32) {
    atomicAdd(&sums[bkt * 64 + tid], bs1[tid]);
    atomicAdd(&sums[bkt * 64 + 32 + tid], bs2[tid]);
  }
}

// ---------------- BN+GELU staging element processing (conv2/conv3) ----------------
DEV void bn_store(u16* sin0, u16* sin1, int i, uint4 p4, int cbmask,
                  const float* sc, const float* shf) {
  int cb = (i & cbmask) * 4;
  u32 hw[2], lw[2];
  u32 pe[4] = { p4.x, p4.y, p4.z, p4.w };
#pragma unroll
  for (int half = 0; half < 2; ++half) {
    float va = punp(pe[half * 2 + 0]);
    float vb = punp(pe[half * 2 + 1]);
    float aa = gelu_f(va * sc[cb + half * 2 + 0] + shf[cb + half * 2 + 0]);
    float ab = gelu_f(vb * sc[cb + half * 2 + 1] + shf[cb + half * 2 + 1]);
    u32 ua = fbits(aa), ub = fbits(ab);
    float la = aa - ubits(ua & 0xFFFF0000u);
    float lb = ab - ubits(ub & 0xFFFF0000u);
    hw[half] = (ua >> 16) | (ub & 0xFFFF0000u);
    lw[half] = (fbits(la) >> 16) | (fbits(lb) & 0xFFFF0000u);
  }
  int iw = i ^ (((i >> 4) & 7) << 1);   // swizzle
  ((uint2*)sin0)[iw] = make_uint2(hw[0], hw[1]);
  ((uint2*)sin1)[iw] = make_uint2(lw[0], lw[1]);
}

// ---------------- conv2 MFMA (pipelined BN1+GELU staging, bucketed BN2 stats) ----------------
__global__ __launch_bounds__(256, 3) void k_conv2m(const u32* __restrict__ y1p,
    const u16* __restrict__ wfh, const u16* __restrict__ wfl,
    const float* __restrict__ scale, const float* __restrict__ shift,
    const float* __restrict__ bias, u32* __restrict__ y2p, float* __restrict__ sums)
{
  __shared__ __align__(16) u16 sin0[12480], sin1[12480];  // [10 rows][39 cols][32 c]
  __shared__ float sc[32], shf[32];
  __shared__ float bs1[64], bs2[64];
  int ohq = blockIdx.x, b = blockIdx.y, tid = threadIdx.x;
  if (tid < 32) { sc[tid] = scale[tid]; shf[tid] = shift[tid]; }
  if (tid < 64) { bs1[tid] = 0.f; bs2[tid] = 0.f; }
  __syncthreads();
  long sb = ((long)b * 1365 + (long)ohq * 312) * 32;
  const uint4* srcP = (const uint4*)(y1p + sb);
  {
    uint4 pr[12];
#pragma unroll
    for (int it = 0; it < 12; ++it) pr[it] = srcP[tid + it * 256];
#pragma unroll
    for (int it = 0; it < 12; ++it) bn_store(sin0, sin1, tid + it * 256, pr[it], 7, sc, shf);
    if (tid < 48) {
      int i = 3072 + tid;
      bn_store(sin0, sin1, i, srcP[i], 7, sc, shf);
    }
  }
  __syncthreads();
  int w = tid >> 6, lane = tid & 63, g = lane >> 4, ln = lane & 15;
  int oct = w;
  int rowb[5], colb[5];
#pragma unroll
  for (int j = 0; j < 5; ++j) {
    int p = j * 16 + ln; if (p > 71) p = 71;
    int ohl = p / 18, ow = p - 18 * ohl;
    rowb[j] = 2 * ohl; colb[j] = 2 * ow;
  }
  f32x4 z4 = {0.f, 0.f, 0.f, 0.f};
  f32x4 acc[5];
#pragma unroll
  for (int j = 0; j < 5; ++j) acc[j] = z4;
#pragma unroll
  for (int s = 0; s < 16; ++s) {
    int kh = s >> 2, kw = s & 3;
    bf16x8 bh = *(const bf16x8*)&wfh[oct * 8192 + s * 512 + lane * 8];
    bf16x8 bl = *(const bf16x8*)&wfl[oct * 8192 + s * 512 + lane * 8];
#pragma unroll
    for (int j = 0; j < 5; ++j) {
      int colpix = (rowb[j] + kh) * 39 + colb[j] + kw;
      int off = colpix * 32 + g * 8;
      off ^= ((colpix >> 1) & 7) << 3;   // swizzle
      bf16x8 ah = *(const bf16x8*)&sin0[off];
      bf16x8 al = *(const bf16x8*)&sin1[off];
      acc[j] = mfma3(ah, al, bh, bl, acc[j]);
    }
  }
  int oc = oct * 16 + ln;
  float bv = bias[oc];
  float s1 = 0.f, s2 = 0.f;
#pragma unroll
  for (int j = 0; j < 5; ++j) {
#pragma unroll
    for (int r = 0; r < 4; ++r) {
      int po = j * 16 + g * 4 + r;
      if (po < 72) {
        long oi = ((long)b * 288 + (long)ohq * 72 + po) * 64 + oc;
        float v = acc[j][r] + bv;
        y2p[oi] = psplit(v);
        s1 += v; s2 += v * v;
      }
    }
  }
#pragma unroll
  for (int o = 16; o <= 32; o <<= 1) { s1 += __shfl_xor(s1, o); s2 += __shfl_xor(s2, o); }
  if (g == 0) { atomicAdd(&bs1[oc], s1); atomicAdd(&bs2[oc], s2); }
  __syncthreads();
  int bkt = b & 7;
  if (tid < 64) {
    atomicAdd(&sums[bkt * 128 + tid], bs1[tid]);
    atomicAdd(&sums[bkt * 128 + 64 + tid], bs2[tid]);
  }
}

// ---------------- conv3 MFMA (pipelined BN2+GELU staging, bucketed BN3 stats) ----------------
__global__ __launch_bounds__(256, 3) void k_conv3m(const u32* __restrict__ y2p,
    const u16* __restrict__ wfh, const u16* __restrict__ wfl,
    const float* __restrict__ scale, const float* __restrict__ shift,
    const float* __restrict__ bias, u32* __restrict__ y3p, float* __restrict__ sums)
{
  __shared__ __align__(16) u16 sin0[10368], sin1[10368];  // [9 rows][18 cols][64 c]
  __shared__ float sc[64], shf[64];
  __shared__ float bs1[128], bs2[128];
  int hh = blockIdx.x, b = blockIdx.y, tid = threadIdx.x;
  if (tid < 64) { sc[tid] = scale[tid]; shf[tid] = shift[tid]; }
  if (tid < 128) { bs1[tid] = 0.f; bs2[tid] = 0.f; }
  __syncthreads();
  long sb = ((long)b * 288 + (long)hh * 126) * 64;
  const uint4* srcP = (const uint4*)(y2p + sb);
  {
    uint4 pr[10];
#pragma unroll
    for (int it = 0; it < 10; ++it) pr[it] = srcP[tid + it * 256];
#pragma unroll
    for (int it = 0; it < 10; ++it) bn_store(sin0, sin1, tid + it * 256, pr[it], 15, sc, shf);
    if (tid < 32) {
      int i = 2560 + tid;
      bn_store(sin0, sin1, i, srcP[i], 15, sc, shf);
    }
  }
  __syncthreads();
  int w = tid >> 6, lane = tid & 63, g = lane >> 4, ln = lane & 15;
  int oct0 = w * 2;
  f32x4 z4 = {0.f, 0.f, 0.f, 0.f};
  f32x4 acc[7][2];
#pragma unroll
  for (int j = 0; j < 7; ++j) { acc[j][0] = z4; acc[j][1] = z4; }
#pragma unroll 6
  for (int s = 0; s < 18; ++s) {
    const int kh = s / 6, rm = s % 6;
    const int kw = rm >> 1, ch = rm & 1;
    bf16x8 bh0 = *(const bf16x8*)&wfh[oct0 * 9216 + s * 512 + lane * 8];
    bf16x8 bl0 = *(const bf16x8*)&wfl[oct0 * 9216 + s * 512 + lane * 8];
    bf16x8 bh1 = *(const bf16x8*)&wfh[(oct0 + 1) * 9216 + s * 512 + lane * 8];
    bf16x8 bl1 = *(const bf16x8*)&wfl[(oct0 + 1) * 9216 + s * 512 + lane * 8];
#pragma unroll
    for (int j = 0; j < 7; ++j) {
      int colpix = (j + kh) * 18 + ln + kw;
      int off = colpix * 64 + ch * 32 + g * 8;
      off ^= (colpix & 7) << 3;   // swizzle
      bf16x8 ah = *(const bf16x8*)&sin0[off];
      bf16x8 al = *(const bf16x8*)&sin1[off];
      acc[j][0] = mfma3(ah, al, bh0, bl0, acc[j][0]);
      acc[j][1] = mfma3(ah, al, bh1, bl1, acc[j][1]);
    }
  }
  float s1[2] = {0.f, 0.f}, s2[2] = {0.f, 0.f};
#pragma unroll
  for (int j = 0; j < 7; ++j) {
#pragma unroll
    for (int o2 = 0; o2 < 2; ++o2) {
      int oc = (oct0 + o2) * 16 + ln;
      float bv = bias[oc];
#pragma unroll
      for (int r = 0; r < 4; ++r) {
        int owo = g * 4 + r;
        long oi = ((long)b * 224 + (hh * 7 + j) * 16 + owo) * 128 + oc;
        float v = acc[j][o2][r] + bv;
        y3p[oi] = psplit(v);
        s1[o2] += v; s2[o2] += v * v;
      }
    }
  }
#pragma unroll
  for (int o = 16; o <= 32; o <<= 1) {
    s1[0] += __shfl_xor(s1[0], o); s1[1] += __shfl_xor(s1[1], o);
    s2[0] += __shfl_xor(s2[0], o); s2[1] += __shfl_xor(s2[1], o);
  }
  if (g == 0) {
    atomicAdd(&bs1[oct0 * 16 + ln], s1[0]); atomicAdd(&bs1[(oct0 + 1) * 16 + ln], s1[1]);
    atomicAdd(&bs2[oct0 * 16 + ln], s2[0]); atomicAdd(&bs2[(oct0 + 1) * 16 + ln], s2[1]);
  }
  __syncthreads();
  int bkt = b & 7;
  if (tid < 128) {
    atomicAdd(&sums[bkt * 256 + tid], bs1[tid]);
    atomicAdd(&sums[bkt * 256 + 128 + tid], bs2[tid]);
  }
}

// ---------------- BN finalize over 8 buckets ----------------
__global__ void k_bn_finalize(const float* __restrict__ sums, const float* __restrict__ g,
    const float* __restrict__ b, float* __restrict__ scale, float* __restrict__ shift,
    int C, float invN)
{
  int c = threadIdx.x;
  if (c < C) {
    float s1 = 0.f, s2 = 0.f;
#pragma unroll
    for (int k = 0; k < 8; ++k) {
      s1 += sums[k * 2 * C + c];
      s2 += sums[k * 2 * C + C + c];
    }
    float m = s1 * invN;
    float var = s2 * invN - m * m;
    float sc = g[c] * rsqrtf(var + 1e-5f);
    scale[c] = sc;
    shift[c] = b[c] - m * sc;
  }
}

// ---------------- proj MFMA split-K, 128-token M-tile (fused BN3+GELU on A-staging) ----------------
__global__ __launch_bounds__(256, 2) void k_projm(const u32* __restrict__ y3p,
    const u16* __restrict__ bh_g, const u16* __restrict__ bl_g,
    const float* __restrict__ scale, const float* __restrict__ shift,
    float* __restrict__ part)
{
  __shared__ __align__(16) u16 Ah[4096], Al[4096];   // [128 tok][32 k]
  __shared__ __align__(16) u16 Bh[8192], Bl[8192];   // [16 oct][512]
  __shared__ float sc3[128], sh3[128];
  int m0 = blockIdx.x * 128, by = blockIdx.y, tid = threadIdx.x;
  int w = tid >> 6, lane = tid & 63, g = lane >> 4, ln = lane & 15;
  if (tid < 128) { sc3[tid] = scale[tid]; sh3[tid] = shift[tid]; }
  f32x4 z4 = {0.f, 0.f, 0.f, 0.f};
  f32x4 acc[2][16];
#pragma unroll
  for (int p = 0; p < 2; ++p)
#pragma unroll
    for (int o = 0; o < 16; ++o) acc[p][o] = z4;
  for (int ks = 0; ks < 28; ++ks) {
    __syncthreads();
    long k0 = ((long)by * 28 + ks) * 32;
    int cbase = (int)(k0 & 127);
#pragma unroll
    for (int ii = 0; ii < 4; ++ii) {
      int i = tid + ii * 256;
      int row = i >> 3, q = i & 7;
      uint4 p4 = *((const uint4*)(y3p + (long)(m0 + row) * 28672 + k0) + q);
      u32 pe[4] = { p4.x, p4.y, p4.z, p4.w };
      int c0 = cbase + q * 4;
      u16 hs[4], ls[4];
#pragma unroll
      for (int j = 0; j < 4; ++j) {
        float v = punp(pe[j]);
        float a = gelu_f(v * sc3[c0 + j] + sh3[c0 + j]);
        u32 ua = fbits(a);
        float la = a - ubits(ua & 0xFFFF0000u);
        hs[j] = (u16)(ua >> 16);
        ls[j] = (u16)(fbits(la) >> 16);
      }
      ((uint2*)Ah)[i] = make_uint2((u32)hs[0] | ((u32)hs[1] << 16), (u32)hs[2] | ((u32)hs[3] << 16));
      ((uint2*)Al)[i] = make_uint2((u32)ls[0] | ((u32)ls[1] << 16), (u32)ls[2] | ((u32)ls[3] << 16));
    }
    int ksg = by * 28 + ks;
#pragma unroll
    for (int ii = 0; ii < 8; ++ii) {
      int i = tid + ii * 256;
      int arr = i >> 10, idx = i & 1023, oct = idx >> 6, r2 = idx & 63;
      const u16* src = arr ? bl_g : bh_g;
      u16* dst = arr ? Bl : Bh;
      ((uint4*)dst)[idx] = *((const uint4*)(src + ((long)oct * 896 + ksg) * 512) + r2);
    }
    __syncthreads();
    bf16x8 a_h[2], a_l[2];
#pragma unroll
    for (int pt = 0; pt < 2; ++pt) {
      int off = ((2 * w + pt) * 16 + ln) * 32 + g * 8;
      a_h[pt] = *(const bf16x8*)&Ah[off];
      a_l[pt] = *(const bf16x8*)&Al[off];
    }
#pragma unroll
    for (int oct = 0; oct < 16; ++oct) {
      bf16x8 bh = *(const bf16x8*)&Bh[oct * 512 + lane * 8];
      bf16x8 bl = *(const bf16x8*)&Bl[oct * 512 + lane * 8];
#pragma unroll
      for (int pt = 0; pt < 2; ++pt)
        acc[pt][oct] = mfma3(a_h[pt], a_l[pt], bh, bl, acc[pt][oct]);
    }
  }
#pragma unroll
  for (int pt = 0; pt < 2; ++pt)
#pragma unroll
    for (int oct = 0; oct < 16; ++oct) {
      int oc = oct * 16 + ln;
#pragma unroll
      for (int r = 0; r < 4; ++r) {
        int tok = m0 + (2 * w + pt) * 16 + g * 4 + r;
        part[((long)by * 1024 + tok) * 256 + oc] = acc[pt][oct][r];
      }
    }
}

// ---------------- split-K reduce + bias + LN + GELU ----------------
__global__ __launch_bounds__(256) void k_lnred(const float* __restrict__ part,
    const float* __restrict__ pb, const float* __restrict__ g, const float* __restrict__ be,
    float* __restrict__ h, u16* __restrict__ hb)
{
  int b = blockIdx.x, d = threadIdx.x;
  float s = pb[d];
#pragma unroll
  for (int ks = 0; ks < 32; ++ks) s += part[((long)ks * 1024 + b) * 256 + d];
  __shared__ float red[4];
  float t = s;
  for (int o = 32; o; o >>= 1) t += __shfl_xor(t, o);
  if ((d & 63) == 0) red[d >> 6] = t;
  __syncthreads();
  float mean = (red[0] + red[1] + red[2] + red[3]) * (1.f / 256.f);
  __syncthreads();
  float dv = s - mean;
  t = dv * dv;
  for (int o = 32; o; o >>= 1) t += __shfl_xor(t, o);
  if ((d & 63) == 0) red[d >> 6] = t;
  __syncthreads();
  float var = (red[0] + red[1] + red[2] + red[3]) * (1.f / 256.f);
  float hv = gelu_f(g[d] * dv * rsqrtf(var + 1e-5f) + be[d]);
  h[b * 256 + d] = hv;
  hb[b * 256 + d] = f2bf(hv);
}

// ---------------- generic plain-bf16 MFMA GEMM ----------------
__global__ __launch_bounds__(256, 2) void k_gemmb(const u16* __restrict__ A, long aZ, int K,
    const u16* __restrict__ Bf, int noct_tot,
    const float* __restrict__ bias, int biasZ,
    void* __restrict__ C, long cZ, int ldc, int outbf, int act)
{
  __shared__ __align__(16) u16 As[2048];
  __shared__ __align__(16) u16 Bs[8192];
  int m0 = blockIdx.x * 64, nb = blockIdx.y, z = blockIdx.z, tid = threadIdx.x;
  int w = tid >> 6, lane = tid & 63, g = lane >> 4, ln = lane & 15;
  const u16* Az = A + (long)z * aZ;
  int kn = K >> 5;
  f32x4 z4 = {0.f, 0.f, 0.f, 0.f};
  f32x4 acc[16];
#pragma unroll
  for (int o = 0; o < 16; ++o) acc[o] = z4;
  for (int ks = 0; ks < kn; ++ks) {
    __syncthreads();
    {
      int row = tid >> 2, q = tid & 3;
      ((uint4*)As)[tid] = *((const uint4*)(Az + (long)(m0 + row) * K + ks * 32) + q);
    }
#pragma unroll
    for (int ii = 0; ii < 4; ++ii) {
      int i = tid + ii * 256;
      int oct = i >> 6, r2 = i & 63;
      const u16* src = Bf + (((long)z * noct_tot + nb * 16 + oct) * kn + ks) * 512;
      ((uint4*)Bs)[i] = ((const uint4*)src)[r2];
    }
    __syncthreads();
    bf16x8 a = *(const bf16x8*)&As[(w * 16 + ln) * 32 + g * 8];
#pragma unroll
    for (int oct = 0; oct < 16; ++oct) {
      bf16x8 bb = *(const bf16x8*)&Bs[oct * 512 + lane * 8];
      acc[oct] = __builtin_amdgcn_mfma_f32_16x16x32_bf16(a, bb, acc[oct], 0, 0, 0);
    }
  }
#pragma unroll
  for (int oct = 0; oct < 16; ++oct) {
    int n = nb * 256 + oct * 16 + ln;
    float bv = bias[z * biasZ + n];
#pragma unroll
    for (int r = 0; r < 4; ++r) {
      int tok = m0 + w * 16 + g * 4 + r;
      float v = acc[oct][r] + bv;
      if (act) v = gelu_f(v);
      long off = (long)z * cZ + (long)tok * ldc + n;
      if (outbf) ((u16*)C)[off] = f2bf(v);
      else ((float*)C)[off] = v;
    }
  }
}

// ---------------- router ----------------
__global__ __launch_bounds__(64) void k_router(const float* __restrict__ h,
    const float* __restrict__ rw, const float* __restrict__ eb,
    float* __restrict__ wts, int* __restrict__ idx,
    float* __restrict__ pm_sum, float* __restrict__ z_sum)
{
  int b = blockIdx.x, lane = threadIdx.x;
  float4 hv = *(const float4*)(h + b * 256 + lane * 4);
  float logit[8];
#pragma unroll
  for (int e = 0; e < 8; ++e) {
    float4 wv = *(const float4*)(rw + e * 256 + lane * 4);
    float p = hv.x * wv.x + hv.y * wv.y + hv.z * wv.z + hv.w * wv.w;
    for (int o = 32; o; o >>= 1) p += __shfl_xor(p, o);
    logit[e] = p + eb[e];
  }
  float mx = logit[0];
#pragma unroll
  for (int e = 1; e < 8; ++e) mx = fmaxf(mx, logit[e]);
  float pr[8]; float se = 0.f;
#pragma unroll
  for (int e = 0; e < 8; ++e) { pr[e] = expf(logit[e] - mx); se += pr[e]; }
  float inv = 1.f / se;
#pragma unroll
  for (int e = 0; e < 8; ++e) pr[e] *= inv;
  int i0 = 0; float v0 = pr[0];
#pragma unroll
  for (int e = 1; e < 8; ++e) if (pr[e] > v0) { v0 = pr[e]; i0 = e; }
  int i1 = -1; float v1 = -1.f;
#pragma unroll
  for (int e = 0; e < 8; ++e) if (e != i0 && pr[e] > v1) { v1 = pr[e]; i1 = e; }
  if (lane == 0) {
    float ssum = v0 + v1 + 1e-8f;
    wts[2 * b] = v0 / ssum; wts[2 * b + 1] = v1 / ssum;
    idx[2 * b] = i0; idx[2 * b + 1] = i1;
    float zz = 0.f;
#pragma unroll
    for (int e = 0; e < 8; ++e) zz += logit[e] * logit[e];
    atomicAdd(z_sum, zz);
  }
  if (lane < 8) atomicAdd(&pm_sum[lane], pr[lane]);
}

// ---------------- combine + 0.5*shared + final LN ----------------
__global__ __launch_bounds__(256) void k_combine_ln(const float* __restrict__ eout,
    const float* __restrict__ sharedB, const float* __restrict__ wts, const int* __restrict__ idx,
    const float* __restrict__ g, const float* __restrict__ bb, float* __restrict__ out)
{
  int b = blockIdx.x, d = threadIdx.x;
  float w0 = wts[2 * b], w1 = wts[2 * b + 1];
  int i0 = idx[2 * b], i1 = idx[2 * b + 1];
  float val = w0 * eout[(long)i0 * 262144 + b * 256 + d]
            + w1 * eout[(long)i1 * 262144 + b * 256 + d]
            + 0.5f * sharedB[b * 256 + d];
  __shared__ float red[4];
  float s = val;
  for (int o = 32; o; o >>= 1) s += __shfl_xor(s, o);
  if ((d & 63) == 0) red[d >> 6] = s;
  __syncthreads();
  float mean = (red[0] + red[1] + red[2] + red[3]) * (1.f / 256.f);
  __syncthreads();
  float dv = val - mean;
  s = dv * dv;
  for (int o = 32; o; o >>= 1) s += __shfl_xor(s, o);
  if ((d & 63) == 0) red[d >> 6] = s;
  __syncthreads();
  float var = (red[0] + red[1] + red[2] + red[3]) * (1.f / 256.f);
  out[b * 256 + d] = g[d] * dv * rsqrtf(var + 1e-5f) + bb[d];
}

// ---------------- aux losses ----------------
__global__ void k_losses(const float* __restrict__ pm_sum, const float* __restrict__ z_sum,
                         float* __restrict__ out)
{
  if (threadIdx.x == 0 && blockIdx.x == 0) {
    float lb = 0.f;
    for (int e = 0; e < 8; ++e) {
      float pm = pm_sum[e] * (1.f / 1024.f);
      float dd = pm - 0.125f;
      lb += dd * dd;
    }
    out[262144] = lb * 8.f;
    out[262145] = z_sum[0] * (1.f / 8192.f) * 0.001f;
  }
}

extern "C" void kernel_launch(void* const* d_in, const int* in_sizes, int n_in,
                              void* d_out, int out_size, void* d_ws, size_t ws_size,
                              hipStream_t stream)
{
  const float* x     = (const float*)d_in[0];
  const float* c1w   = (const float*)d_in[1];
  const float* c1b   = (const float*)d_in[2];
  const float* bn1g  = (const float*)d_in[3];
  const float* bn1b  = (const float*)d_in[4];
  const float* c2w   = (const float*)d_in[5];
  const float* c2b   = (const float*)d_in[6];
  const float* bn2g  = (const float*)d_in[7];
  const float* bn2b  = (const float*)d_in[8];
  const float* c3w   = (const float*)d_in[9];
  const float* c3b   = (const float*)d_in[10];
  const float* bn3g  = (const float*)d_in[11];
  const float* bn3b  = (const float*)d_in[12];
  const float* projw = (const float*)d_in[13];
  const float* projb = (const float*)d_in[14];
  const float* lng   = (const float*)d_in[15];
  const float* lnb   = (const float*)d_in[16];
  const float* rw    = (const float*)d_in[17];
  const float* ebias = (const float*)d_in[18];
  const float* ew1   = (const float*)d_in[19];
  const float* eb1   = (const float*)d_in[20];
  const float* ew2   = (const float*)d_in[21];
  const float* eb2   = (const float*)d_in[22];
  const float* sw1   = (const float*)d_in[23];
  const float* sb1   = (const float*)d_in[24];
  const float* sw2   = (const float*)d_in[25];
  const float* sb2   = (const float*)d_in[26];
  const float* mlng  = (const float*)d_in[27];
  const float* mlnb  = (const float*)d_in[28];
  float* out = (float*)d_out;

  char* W = (char*)d_ws;
  u32* y1p = (u32*)(W + 0);              // 178,913,280 B
  u32* y2p = (u32*)(W + 178913280L);     // 75,497,472 B
  u32* y3p = (u32*)(W + 0);              // 117,440,512 B (alias dead y1)
  u16* wfph = (u16*)(W + 254410752L);
  u16* wfpl = (u16*)(W + 269090816L);
  u16* wf1h = (u16*)(W + 283770880L);
  u16* wf1l = (u16*)(W + 283787264L);
  u16* wf2h = (u16*)(W + 283803648L);
  u16* wf2l = (u16*)(W + 283869184L);
  u16* wf3h = (u16*)(W + 283934720L);
  u16* wf3l = (u16*)(W + 284082176L);
  float* stats = (float*)(W + 284229632L);  // 4096 floats
  float* wtsb  = (float*)(W + 284246016L);
  int*   idxb  = (int*)(W + 284254208L);
  float* hbuf  = (float*)(W + 284262400L);
  float* shB   = (float*)(W + 286359552L);
  // tail region inside the y2p span — all used only after conv3m completes
  float* part  = (float*)(W + 178913280L);  // 33,554,432 B
  u16* hid     = (u16*)(W + 212467712L);    // 8,388,608 B
  u16* ewf1    = (u16*)(W + 220856320L);    // 2,097,152 B
  u16* ewf2    = (u16*)(W + 222953472L);    // 2,097,152 B
  u16* swf1    = (u16*)(W + 225050624L);    // 131,072 B
  u16* swf2    = (u16*)(W + 225181696L);    // 131,072 B
  float* eoutB = (float*)(W + 225312768L);  // 8,388,608 B
  u16* hbufb   = (u16*)(W + 233701376L);    // 524,288 B
  u16* sh1b    = (u16*)(W + 234225664L);    // 524,288 B

  float* sums1 = stats;               // 8 x 64
  float* sums2 = stats + 512;         // 8 x 128
  float* sums3 = stats + 1536;        // 8 x 256
  float* scale1 = stats + 3584; float* shift1 = stats + 3616;
  float* scale2 = stats + 3648; float* shift2 = stats + 3712;
  float* scale3 = stats + 3776; float* shift3 = stats + 3904;
  float* pm    = stats + 4032;  float* zsum  = stats + 4040;

  dim3 blk(256);
  k_zero<<<dim3(16), blk, 0, stream>>>(stats, 4096);
  k_wprep1<<<dim3(32), blk, 0, stream>>>(c1w, wf1h, wf1l);
  k_wprep2<<<dim3(128), blk, 0, stream>>>(c2w, wf2h, wf2l);
  k_wprep3<<<dim3(288), blk, 0, stream>>>(c3w, wf3h, wf3l);
  k_wprepP<<<dim3(32, 16), blk, 0, stream>>>(projw, wfph, wfpl);

  k_conv1m<<<dim3(9, 1024), blk, 0, stream>>>(x, wf1h, wf1l, c1b, y1p, sums1);
  k_bn_finalize<<<1, 32, 0, stream>>>(sums1, bn1g, bn1b, scale1, shift1, 32, 1.f / 1397760.f);

  k_conv2m<<<dim3(4, 1024), blk, 0, stream>>>(y1p, wf2h, wf2l, scale1, shift1, c2b, y2p, sums2);
  k_bn_finalize<<<1, 64, 0, stream>>>(sums2, bn2g, bn2b, scale2, shift2, 64, 1.f / 294912.f);

  k_conv3m<<<dim3(2, 1024), blk, 0, stream>>>(y2p, wf3h, wf3l, scale2, shift2, c3b, y3p, sums3);
  k_bn_finalize<<<1, 128, 0, stream>>>(sums3, bn3g, bn3b, scale3, shift3, 128, 1.f / 229376.f);

  // expert/shared weight preps (y2p region is dead now)
  k_wprepG<<<dim3(4096), blk, 0, stream>>>(ew1, ewf1, 512, 256, 1048576L);
  k_wprepG<<<dim3(4096), blk, 0, stream>>>(ew2, ewf2, 256, 512, 1048576L);
  k_wprepG<<<dim3(256), blk, 0, stream>>>(sw1, swf1, 256, 256, 65536L);
  k_wprepG<<<dim3(256), blk, 0, stream>>>(sw2, swf2, 256, 256, 65536L);

  k_projm<<<dim3(8, 32), blk, 0, stream>>>(y3p, wfph, wfpl, scale3, shift3, part);
  k_lnred<<<dim3(1024), blk, 0, stream>>>(part, projb, lng, lnb, hbuf, hbufb);

  k_router<<<dim3(1024), dim3(64), 0, stream>>>(hbuf, rw, ebias, wtsb, idxb, pm, zsum);

  // experts (dense) + shared, plain bf16 MFMA
  k_gemmb<<<dim3(16, 2, 8), blk, 0, stream>>>(hbufb, 0L, 256, ewf1, 32, eb1, 512,
                                              (void*)hid, 524288L, 512, 1, 1);
  k_gemmb<<<dim3(16, 1, 8), blk, 0, stream>>>(hid, 524288L, 512, ewf2, 16, eb2, 256,
                                              (void*)eoutB, 262144L, 256, 0, 0);
  k_gemmb<<<dim3(16, 1, 1), blk, 0, stream>>>(hbufb, 0L, 256, swf1, 16, sb1, 0,
                                              (void*)sh1b, 0L, 256, 1, 1);
  k_gemmb<<<dim3(16, 1, 1), blk, 0, stream>>>(sh1b, 0L, 256, swf2, 16, sb2, 0,
                                              (void*)shB, 0L, 256, 0, 0);

  k_combine_ln<<<dim3(1024), blk, 0, stream>>>(eoutB, shB, wtsb, idxb, mlng, mlnb, out);
  k_losses<<<1, 64, 0, stream>>>(pm, zsum, out);
}

// Round 13
// 698.365 us; speedup vs baseline: 1.9680x; 1.0205x over previous
//
#include <hip/hip_runtime.h>
#include <hip/hip_bf16.h>
#include <math.h>

typedef unsigned short u16;
typedef unsigned int u32;
typedef __attribute__((ext_vector_type(8))) short bf16x8;
typedef __attribute__((ext_vector_type(4))) float f32x4;

#define DEV __device__ __forceinline__

DEV float gelu_f(float x) { return 0.5f * x * (1.0f + erff(x * 0.70710678118654752f)); }
DEV u16 f2bf(float f) { u32 u = __builtin_bit_cast(u32, f); u = (u + 0x7FFFu + ((u >> 16) & 1u)) >> 16; return (u16)u; }
DEV float bf2f(u16 h) { return __builtin_bit_cast(float, (u32)h << 16); }
DEV u32 fbits(float f) { return __builtin_bit_cast(u32, f); }
DEV float ubits(u32 u) { return __builtin_bit_cast(float, u); }
DEV u32 psplit(float v) {
  u32 u = fbits(v);
  float lo = v - ubits(u & 0xFFFF0000u);
  return (u >> 16) | (fbits(lo) & 0xFFFF0000u);
}
DEV float punp(u32 p) { return ubits(p << 16) + ubits(p & 0xFFFF0000u); }
DEV f32x4 mfma3(bf16x8 ah, bf16x8 al, bf16x8 bh, bf16x8 bl, f32x4 c) {
  c = __builtin_amdgcn_mfma_f32_16x16x32_bf16(al, bh, c, 0, 0, 0);
  c = __builtin_amdgcn_mfma_f32_16x16x32_bf16(ah, bl, c, 0, 0, 0);
  c = __builtin_amdgcn_mfma_f32_16x16x32_bf16(ah, bh, c, 0, 0, 0);
  return c;
}
DEV void wprepG_elem(const float* __restrict__ w, u16* __restrict__ wf,
                     int N, int K, long idx) {
  int j = (int)(idx & 7); int lane = (int)((idx >> 3) & 63); long rest = idx >> 9;
  int kn = K >> 5;
  int s = (int)(rest % kn); long rest2 = rest / kn;
  int noct = N >> 4;
  int oct = (int)(rest2 % noct); int z = (int)(rest2 / noct);
  int n = oct * 16 + (lane & 15);
  int k = s * 32 + ((lane >> 4) << 3) + j;
  wf[idx] = f2bf(w[((long)z * N + n) * K + k]);
}

// ---------------- merged prep: zero stats + conv wpreps + expert/shared wpreps ----------------
__global__ __launch_bounds__(256) void k_prep(
    const float* __restrict__ c1w, u16* __restrict__ wf1h, u16* __restrict__ wf1l,
    const float* __restrict__ c2w, u16* __restrict__ wf2h, u16* __restrict__ wf2l,
    const float* __restrict__ c3w, u16* __restrict__ wf3h, u16* __restrict__ wf3l,
    const float* __restrict__ ew1, u16* __restrict__ ewf1,
    const float* __restrict__ ew2, u16* __restrict__ ewf2,
    const float* __restrict__ sw1, u16* __restrict__ swf1,
    const float* __restrict__ sw2, u16* __restrict__ swf2,
    float* __restrict__ stats)
{
  int bx = blockIdx.x, tid = threadIdx.x;
  if (bx < 16) { int i = bx * 256 + tid; if (i < 4096) stats[i] = 0.f; return; }
  bx -= 16;
  if (bx < 32) {  // conv1 weights
    int idx = bx * 256 + tid;
    int j = idx & 7, lane = (idx >> 3) & 63, s = (idx >> 9) & 7, oct = idx >> 12;
    int oc = oct * 16 + (lane & 15);
    int kl = ((lane >> 4) << 3) + j;
    int kw = kl >> 2, c = kl & 3, kh = s;
    float v = c1w[((oc * 4 + c) * 8 + kh) * 8 + kw];
    u16 h = f2bf(v); wf1h[idx] = h; wf1l[idx] = f2bf(v - bf2f(h));
    return;
  }
  bx -= 32;
  if (bx < 128) {  // conv2 weights
    int idx = bx * 256 + tid;
    int j = idx & 7, lane = (idx >> 3) & 63, s = (idx >> 9) & 15, oct = idx >> 13;
    int oc = oct * 16 + (lane & 15);
    int k = s * 32 + ((lane >> 4) << 3) + j;
    int kh = k >> 7, kw = (k >> 5) & 3, c = k & 31;
    float v = c2w[((oc * 32 + c) * 4 + kh) * 4 + kw];
    u16 h = f2bf(v); wf2h[idx] = h; wf2l[idx] = f2bf(v - bf2f(h));
    return;
  }
  bx -= 128;
  if (bx < 288) {  // conv3 weights
    int idx = bx * 256 + tid;
    if (idx >= 73728) return;
    int j = idx & 7, lane = (idx >> 3) & 63, rest = idx >> 9;
    int s = rest % 18, oct = rest / 18;
    int oc = oct * 16 + (lane & 15);
    int k = s * 32 + ((lane >> 4) << 3) + j;
    int kh = k / 192, r = k - kh * 192;
    int kw = r >> 6, c = r & 63;
    float v = c3w[((oc * 64 + c) * 3 + kh) * 3 + kw];
    u16 h = f2bf(v); wf3h[idx] = h; wf3l[idx] = f2bf(v - bf2f(h));
    return;
  }
  bx -= 288;
  if (bx < 4096) { wprepG_elem(ew1, ewf1, 512, 256, (long)bx * 256 + tid); return; }
  bx -= 4096;
  if (bx < 4096) { wprepG_elem(ew2, ewf2, 256, 512, (long)bx * 256 + tid); return; }
  bx -= 4096;
  if (bx < 256) { wprepG_elem(sw1, swf1, 256, 256, (long)bx * 256 + tid); return; }
  bx -= 256;
  wprepG_elem(sw2, swf2, 256, 256, (long)bx * 256 + tid);
}

// ---------------- proj weight prep, LDS-transpose tiled ----------------
__global__ __launch_bounds__(256) void k_wprepP(const float* __restrict__ w,
    u16* __restrict__ wh, u16* __restrict__ wl)
{
  __shared__ float tile[16][4][225];
  int q = blockIdx.x, oct = blockIdx.y, tid = threadIdx.x;
  for (int i = tid; i < 3584; i += 256) {
    int n = i / 224, rem = i % 224, e = rem / 56, f4 = rem % 56;
    float4 v = *(const float4*)(w + (long)(oct * 16 + n) * 28672 + (4 * q + e) * 224 + f4 * 4);
    tile[n][e][f4 * 4 + 0] = v.x; tile[n][e][f4 * 4 + 1] = v.y;
    tile[n][e][f4 * 4 + 2] = v.z; tile[n][e][f4 * 4 + 3] = v.w;
  }
  __syncthreads();
  int g = (q >> 1) & 3, j0 = 4 * (q & 1), sgb = q >> 3;
  for (int o = tid; o < 3584; o += 256) {
    int pix = o >> 4, ln = o & 15;
    u16 hs[4], ls[4];
#pragma unroll
    for (int e = 0; e < 4; ++e) {
      float v = tile[ln][e][pix];
      u16 h = f2bf(v); hs[e] = h; ls[e] = f2bf(v - bf2f(h));
    }
    long base = (((long)oct * 896 + pix * 4 + sgb) * 64 + g * 16 + ln) * 8 + j0;
    *(uint2*)(wh + base) = make_uint2((u32)hs[0] | ((u32)hs[1] << 16), (u32)hs[2] | ((u32)hs[3] << 16));
    *(uint2*)(wl + base) = make_uint2((u32)ls[0] | ((u32)ls[1] << 16), (u32)ls[2] | ((u32)ls[3] << 16));
  }
}

// ---------------- conv1 staging element processing ----------------
DEV void c1_store(u16* sin0, u16* sin1, int i, float4 v0, float4 v1) {
  const float* a0 = (const float*)&v0;
  const float* a1 = (const float*)&v1;
  int cp = i / 800, rem = i - cp * 800, r = rem / 40, q = rem - r * 40;
#pragma unroll
  for (int m = 0; m < 4; ++m) {
    float f0 = a0[m], f1 = a1[m];
    u32 u0 = fbits(f0), u1 = fbits(f1);
    u32 hh = (u0 >> 16) | (u1 & 0xFFFF0000u);
    float l0 = f0 - ubits(u0 & 0xFFFF0000u);
    float l1 = f1 - ubits(u1 & 0xFFFF0000u);
    u32 ll = (fbits(l0) >> 16) | (fbits(l1) & 0xFFFF0000u);
    int col = q * 4 + m;
    int idx = r * 320 + col * 2 + cp;
    idx ^= ((col >> 4) & 3) << 2;   // swizzle
    ((u32*)sin0)[idx] = hh;
    ((u32*)sin1)[idx] = ll;
  }
}

// ---------------- conv1 MFMA + fused bucketed BN1 stats ----------------
__global__ __launch_bounds__(256, 3) void k_conv1m(const float* __restrict__ x,
    const u16* __restrict__ wfh, const u16* __restrict__ wfl,
    const float* __restrict__ bias, u32* __restrict__ y1p, float* __restrict__ sums)
{
  __shared__ __align__(16) u16 sin0[12800], sin1[12800];   // [20 rows][160 cols][4 c]
  __shared__ float bs1[32], bs2[32];
  int ohp = blockIdx.x, b = blockIdx.y, tid = threadIdx.x;
  int row0 = ohp * 16;
  if (tid < 32) { bs1[tid] = 0.f; bs2[tid] = 0.f; }
  {
    float4 v0r[6], v1r[6];
#pragma unroll
    for (int it = 0; it < 6; ++it) {
      int i = tid + it * 256;
      int cp = i / 800, rem = i - cp * 800, r = rem / 40, q = rem - r * 40;
      int grow = row0 + r;
      float4 z = make_float4(0.f, 0.f, 0.f, 0.f);
      v0r[it] = z; v1r[it] = z;
      if (grow < 144) {
        long base = ((long)b * 4 + 2 * cp) * 23040 + (long)grow * 160 + q * 4;
        v0r[it] = *(const float4*)(x + base);
        v1r[it] = *(const float4*)(x + base + 23040);
      }
    }
#pragma unroll
    for (int it = 0; it < 6; ++it)
      c1_store(sin0, sin1, tid + it * 256, v0r[it], v1r[it]);
    if (tid < 64) {
      int i = 1536 + tid;
      int cp = i / 800, rem = i - cp * 800, r = rem / 40, q = rem - r * 40;
      int grow = row0 + r;
      float4 v0 = make_float4(0.f, 0.f, 0.f, 0.f), v1 = v0;
      if (grow < 144) {
        long base = ((long)b * 4 + 2 * cp) * 23040 + (long)grow * 160 + q * 4;
        v0 = *(const float4*)(x + base);
        v1 = *(const float4*)(x + base + 23040);
      }
      c1_store(sin0, sin1, i, v0, v1);
    }
  }
  __syncthreads();
  int w = tid >> 6, lane = tid & 63, g = lane >> 4, ln = lane & 15;
  int ohls[3], owcs[3];
#pragma unroll
  for (int jj = 0; jj < 3; ++jj) {
    int j = w + 4 * jj;
    ohls[jj] = j / 3;
    int owc = (j % 3) * 16 + ln; if (owc > 38) owc = 38;
    owcs[jj] = owc;
  }
  f32x4 z4 = {0.f, 0.f, 0.f, 0.f};
  f32x4 acc[3][2];
#pragma unroll
  for (int jj = 0; jj < 3; ++jj) { acc[jj][0] = z4; acc[jj][1] = z4; }
#pragma unroll
  for (int kh = 0; kh < 8; ++kh) {
    bf16x8 bh0 = *(const bf16x8*)&wfh[kh * 512 + lane * 8];
    bf16x8 bl0 = *(const bf16x8*)&wfl[kh * 512 + lane * 8];
    bf16x8 bh1 = *(const bf16x8*)&wfh[4096 + kh * 512 + lane * 8];
    bf16x8 bl1 = *(const bf16x8*)&wfl[4096 + kh * 512 + lane * 8];
#pragma unroll
    for (int jj = 0; jj < 3; ++jj) {
      int col = owcs[jj] * 4 + g * 2;
      int off = (4 * ohls[jj] + kh) * 640 + col * 4;
      off ^= ((col >> 4) & 3) << 3;   // swizzle
      bf16x8 ah = *(const bf16x8*)&sin0[off];
      bf16x8 al = *(const bf16x8*)&sin1[off];
      acc[jj][0] = mfma3(ah, al, bh0, bl0, acc[jj][0]);
      acc[jj][1] = mfma3(ah, al, bh1, bl1, acc[jj][1]);
    }
  }
  float s1[2] = {0.f, 0.f}, s2[2] = {0.f, 0.f};
#pragma unroll
  for (int jj = 0; jj < 3; ++jj) {
    int j = w + 4 * jj;
    int ohl = j / 3, owt = j % 3;
    int oh = 4 * ohp + ohl;
    if (oh >= 35) continue;
#pragma unroll
    for (int oct = 0; oct < 2; ++oct) {
      int oc = oct * 16 + ln;
      float bv = bias[oc];
#pragma unroll
      for (int r = 0; r < 4; ++r) {
        int owo = owt * 16 + g * 4 + r;
        if (owo < 39) {
          long oi = ((long)b * 1365 + oh * 39 + owo) * 32 + oc;
          float v = acc[jj][oct][r] + bv;
          y1p[oi] = psplit(v);
          s1[oct] += v; s2[oct] += v * v;
        }
      }
    }
  }
#pragma unroll
  for (int o = 16; o <= 32; o <<= 1) {
    s1[0] += __shfl_xor(s1[0], o); s1[1] += __shfl_xor(s1[1], o);
    s2[0] += __shfl_xor(s2[0], o); s2[1] += __shfl_xor(s2[1], o);
  }
  if (g == 0) {
    atomicAdd(&bs1[ln], s1[0]); atomicAdd(&bs1[16 + ln], s1[1]);
    atomicAdd(&bs2[ln], s2[0]); atomicAdd(&bs2[16 + ln], s2[1]);
  }
  __syncthreads();
  int bkt = b & 7;
  if (tid < 32) {
    atomicAdd(&sums[bkt * 64 + tid], bs1[tid]);
    atomicAdd(&sums[bkt * 64 + 32 + tid], bs2[tid]);
  }
}

// ---------------- BN+GELU staging element processing (conv2/conv3) ----------------
DEV void bn_store(u16* sin0, u16* sin1, int i, uint4 p4, int cbmask,
                  const float* sc, const float* shf) {
  int cb = (i & cbmask) * 4;
  u32 hw[2], lw[2];
  u32 pe[4] = { p4.x, p4.y, p4.z, p4.w };
#pragma unroll
  for (int half = 0; half < 2; ++half) {
    float va = punp(pe[half * 2 + 0]);
    float vb = punp(pe[half * 2 + 1]);
    float aa = gelu_f(va * sc[cb + half * 2 + 0] + shf[cb + half * 2 + 0]);
    float ab = gelu_f(vb * sc[cb + half * 2 + 1] + shf[cb + half * 2 + 1]);
    u32 ua = fbits(aa), ub = fbits(ab);
    float la = aa - ubits(ua & 0xFFFF0000u);
    float lb = ab - ubits(ub & 0xFFFF0000u);
    hw[half] = (ua >> 16) | (ub & 0xFFFF0000u);
    lw[half] = (fbits(la) >> 16) | (fbits(lb) & 0xFFFF0000u);
  }
  int iw = i ^ (((i >> 4) & 7) << 1);   // swizzle
  ((uint2*)sin0)[iw] = make_uint2(hw[0], hw[1]);
  ((uint2*)sin1)[iw] = make_uint2(lw[0], lw[1]);
}

// fused per-block BN finalize from bucketed sums (C channels, stride 2C per bucket)
DEV void bn_fin(const float* __restrict__ sums, const float* __restrict__ gg,
                const float* __restrict__ bb, float* sc, float* shf, int C, float invN, int tid) {
  if (tid < C) {
    float s1 = 0.f, s2 = 0.f;
#pragma unroll
    for (int k = 0; k < 8; ++k) {
      s1 += sums[k * 2 * C + tid];
      s2 += sums[k * 2 * C + C + tid];
    }
    float m = s1 * invN;
    float var = s2 * invN - m * m;
    float scv = gg[tid] * rsqrtf(var + 1e-5f);
    sc[tid] = scv;
    shf[tid] = bb[tid] - m * scv;
  }
}

// ---------------- conv2 MFMA (fused BN1 finalize+apply, bucketed BN2 stats) ----------------
__global__ __launch_bounds__(256, 3) void k_conv2m(const u32* __restrict__ y1p,
    const u16* __restrict__ wfh, const u16* __restrict__ wfl,
    const float* __restrict__ sumsP, const float* __restrict__ bng, const float* __restrict__ bnb,
    const float* __restrict__ bias, u32* __restrict__ y2p, float* __restrict__ sums)
{
  __shared__ __align__(16) u16 sin0[12480], sin1[12480];
  __shared__ float sc[32], shf[32];
  __shared__ float bs1[64], bs2[64];
  int ohq = blockIdx.x, b = blockIdx.y, tid = threadIdx.x;
  bn_fin(sumsP, bng, bnb, sc, shf, 32, 1.f / 1397760.f, tid);
  if (tid < 64) { bs1[tid] = 0.f; bs2[tid] = 0.f; }
  __syncthreads();
  long sb = ((long)b * 1365 + (long)ohq * 312) * 32;
  const uint4* srcP = (const uint4*)(y1p + sb);
  {
    uint4 pr[12];
#pragma unroll
    for (int it = 0; it < 12; ++it) pr[it] = srcP[tid + it * 256];
#pragma unroll
    for (int it = 0; it < 12; ++it) bn_store(sin0, sin1, tid + it * 256, pr[it], 7, sc, shf);
    if (tid < 48) {
      int i = 3072 + tid;
      bn_store(sin0, sin1, i, srcP[i], 7, sc, shf);
    }
  }
  __syncthreads();
  int w = tid >> 6, lane = tid & 63, g = lane >> 4, ln = lane & 15;
  int oct = w;
  int rowb[5], colb[5];
#pragma unroll
  for (int j = 0; j < 5; ++j) {
    int p = j * 16 + ln; if (p > 71) p = 71;
    int ohl = p / 18, ow = p - 18 * ohl;
    rowb[j] = 2 * ohl; colb[j] = 2 * ow;
  }
  f32x4 z4 = {0.f, 0.f, 0.f, 0.f};
  f32x4 acc[5];
#pragma unroll
  for (int j = 0; j < 5; ++j) acc[j] = z4;
#pragma unroll
  for (int s = 0; s < 16; ++s) {
    int kh = s >> 2, kw = s & 3;
    bf16x8 bh = *(const bf16x8*)&wfh[oct * 8192 + s * 512 + lane * 8];
    bf16x8 bl = *(const bf16x8*)&wfl[oct * 8192 + s * 512 + lane * 8];
#pragma unroll
    for (int j = 0; j < 5; ++j) {
      int colpix = (rowb[j] + kh) * 39 + colb[j] + kw;
      int off = colpix * 32 + g * 8;
      off ^= ((colpix >> 1) & 7) << 3;   // swizzle
      bf16x8 ah = *(const bf16x8*)&sin0[off];
      bf16x8 al = *(const bf16x8*)&sin1[off];
      acc[j] = mfma3(ah, al, bh, bl, acc[j]);
    }
  }
  int oc = oct * 16 + ln;
  float bv = bias[oc];
  float s1 = 0.f, s2 = 0.f;
#pragma unroll
  for (int j = 0; j < 5; ++j) {
#pragma unroll
    for (int r = 0; r < 4; ++r) {
      int po = j * 16 + g * 4 + r;
      if (po < 72) {
        long oi = ((long)b * 288 + (long)ohq * 72 + po) * 64 + oc;
        float v = acc[j][r] + bv;
        y2p[oi] = psplit(v);
        s1 += v; s2 += v * v;
      }
    }
  }
#pragma unroll
  for (int o = 16; o <= 32; o <<= 1) { s1 += __shfl_xor(s1, o); s2 += __shfl_xor(s2, o); }
  if (g == 0) { atomicAdd(&bs1[oc], s1); atomicAdd(&bs2[oc], s2); }
  __syncthreads();
  int bkt = b & 7;
  if (tid < 64) {
    atomicAdd(&sums[bkt * 128 + tid], bs1[tid]);
    atomicAdd(&sums[bkt * 128 + 64 + tid], bs2[tid]);
  }
}

// ---------------- conv3 MFMA (fused BN2 finalize+apply, bucketed BN3 stats) ----------------
__global__ __launch_bounds__(256, 3) void k_conv3m(const u32* __restrict__ y2p,
    const u16* __restrict__ wfh, const u16* __restrict__ wfl,
    const float* __restrict__ sumsP, const float* __restrict__ bng, const float* __restrict__ bnb,
    const float* __restrict__ bias, u32* __restrict__ y3p, float* __restrict__ sums)
{
  __shared__ __align__(16) u16 sin0[10368], sin1[10368];
  __shared__ float sc[64], shf[64];
  __shared__ float bs1[128], bs2[128];
  int hh = blockIdx.x, b = blockIdx.y, tid = threadIdx.x;
  bn_fin(sumsP, bng, bnb, sc, shf, 64, 1.f / 294912.f, tid);
  if (tid < 128) { bs1[tid] = 0.f; bs2[tid] = 0.f; }
  __syncthreads();
  long sb = ((long)b * 288 + (long)hh * 126) * 64;
  const uint4* srcP = (const uint4*)(y2p + sb);
  {
    uint4 pr[10];
#pragma unroll
    for (int it = 0; it < 10; ++it) pr[it] = srcP[tid + it * 256];
#pragma unroll
    for (int it = 0; it < 10; ++it) bn_store(sin0, sin1, tid + it * 256, pr[it], 15, sc, shf);
    if (tid < 32) {
      int i = 2560 + tid;
      bn_store(sin0, sin1, i, srcP[i], 15, sc, shf);
    }
  }
  __syncthreads();
  int w = tid >> 6, lane = tid & 63, g = lane >> 4, ln = lane & 15;
  int oct0 = w * 2;
  f32x4 z4 = {0.f, 0.f, 0.f, 0.f};
  f32x4 acc[7][2];
#pragma unroll
  for (int j = 0; j < 7; ++j) { acc[j][0] = z4; acc[j][1] = z4; }
#pragma unroll 6
  for (int s = 0; s < 18; ++s) {
    const int kh = s / 6, rm = s % 6;
    const int kw = rm >> 1, ch = rm & 1;
    bf16x8 bh0 = *(const bf16x8*)&wfh[oct0 * 9216 + s * 512 + lane * 8];
    bf16x8 bl0 = *(const bf16x8*)&wfl[oct0 * 9216 + s * 512 + lane * 8];
    bf16x8 bh1 = *(const bf16x8*)&wfh[(oct0 + 1) * 9216 + s * 512 + lane * 8];
    bf16x8 bl1 = *(const bf16x8*)&wfl[(oct0 + 1) * 9216 + s * 512 + lane * 8];
#pragma unroll
    for (int j = 0; j < 7; ++j) {
      int colpix = (j + kh) * 18 + ln + kw;
      int off = colpix * 64 + ch * 32 + g * 8;
      off ^= (colpix & 7) << 3;   // swizzle
      bf16x8 ah = *(const bf16x8*)&sin0[off];
      bf16x8 al = *(const bf16x8*)&sin1[off];
      acc[j][0] = mfma3(ah, al, bh0, bl0, acc[j][0]);
      acc[j][1] = mfma3(ah, al, bh1, bl1, acc[j][1]);
    }
  }
  float s1[2] = {0.f, 0.f}, s2[2] = {0.f, 0.f};
#pragma unroll
  for (int j = 0; j < 7; ++j) {
#pragma unroll
    for (int o2 = 0; o2 < 2; ++o2) {
      int oc = (oct0 + o2) * 16 + ln;
      float bv = bias[oc];
#pragma unroll
      for (int r = 0; r < 4; ++r) {
        int owo = g * 4 + r;
        long oi = ((long)b * 224 + (hh * 7 + j) * 16 + owo) * 128 + oc;
        float v = acc[j][o2][r] + bv;
        y3p[oi] = psplit(v);
        s1[o2] += v; s2[o2] += v * v;
      }
    }
  }
#pragma unroll
  for (int o = 16; o <= 32; o <<= 1) {
    s1[0] += __shfl_xor(s1[0], o); s1[1] += __shfl_xor(s1[1], o);
    s2[0] += __shfl_xor(s2[0], o); s2[1] += __shfl_xor(s2[1], o);
  }
  if (g == 0) {
    atomicAdd(&bs1[oct0 * 16 + ln], s1[0]); atomicAdd(&bs1[(oct0 + 1) * 16 + ln], s1[1]);
    atomicAdd(&bs2[oct0 * 16 + ln], s2[0]); atomicAdd(&bs2[(oct0 + 1) * 16 + ln], s2[1]);
  }
  __syncthreads();
  int bkt = b & 7;
  if (tid < 128) {
    atomicAdd(&sums[bkt * 256 + tid], bs1[tid]);
    atomicAdd(&sums[bkt * 256 + 128 + tid], bs2[tid]);
  }
}

// ---------------- proj MFMA split-K, 128-token M-tile (fused BN3 finalize + GELU staging) ----------------
__global__ __launch_bounds__(256, 2) void k_projm(const u32* __restrict__ y3p,
    const u16* __restrict__ bh_g, const u16* __restrict__ bl_g,
    const float* __restrict__ sumsP, const float* __restrict__ bng, const float* __restrict__ bnb,
    float* __restrict__ part)
{
  __shared__ __align__(16) u16 Ah[4096], Al[4096];
  __shared__ __align__(16) u16 Bh[8192], Bl[8192];
  __shared__ float sc3[128], sh3[128];
  int m0 = blockIdx.x * 128, by = blockIdx.y, tid = threadIdx.x;
  int w = tid >> 6, lane = tid & 63, g = lane >> 4, ln = lane & 15;
  bn_fin(sumsP, bng, bnb, sc3, sh3, 128, 1.f / 229376.f, tid);
  f32x4 z4 = {0.f, 0.f, 0.f, 0.f};
  f32x4 acc[2][16];
#pragma unroll
  for (int p = 0; p < 2; ++p)
#pragma unroll
    for (int o = 0; o < 16; ++o) acc[p][o] = z4;
  for (int ks = 0; ks < 28; ++ks) {
    __syncthreads();
    long k0 = ((long)by * 28 + ks) * 32;
    int cbase = (int)(k0 & 127);
#pragma unroll
    for (int ii = 0; ii < 4; ++ii) {
      int i = tid + ii * 256;
      int row = i >> 3, q = i & 7;
      uint4 p4 = *((const uint4*)(y3p + (long)(m0 + row) * 28672 + k0) + q);
      u32 pe[4] = { p4.x, p4.y, p4.z, p4.w };
      int c0 = cbase + q * 4;
      u16 hs[4], ls[4];
#pragma unroll
      for (int j = 0; j < 4; ++j) {
        float v = punp(pe[j]);
        float a = gelu_f(v * sc3[c0 + j] + sh3[c0 + j]);
        u32 ua = fbits(a);
        float la = a - ubits(ua & 0xFFFF0000u);
        hs[j] = (u16)(ua >> 16);
        ls[j] = (u16)(fbits(la) >> 16);
      }
      ((uint2*)Ah)[i] = make_uint2((u32)hs[0] | ((u32)hs[1] << 16), (u32)hs[2] | ((u32)hs[3] << 16));
      ((uint2*)Al)[i] = make_uint2((u32)ls[0] | ((u32)ls[1] << 16), (u32)ls[2] | ((u32)ls[3] << 16));
    }
    int ksg = by * 28 + ks;
#pragma unroll
    for (int ii = 0; ii < 8; ++ii) {
      int i = tid + ii * 256;
      int arr = i >> 10, idx = i & 1023, oct = idx >> 6, r2 = idx & 63;
      const u16* src = arr ? bl_g : bh_g;
      u16* dst = arr ? Bl : Bh;
      ((uint4*)dst)[idx] = *((const uint4*)(src + ((long)oct * 896 + ksg) * 512) + r2);
    }
    __syncthreads();
    bf16x8 a_h[2], a_l[2];
#pragma unroll
    for (int pt = 0; pt < 2; ++pt) {
      int off = ((2 * w + pt) * 16 + ln) * 32 + g * 8;
      a_h[pt] = *(const bf16x8*)&Ah[off];
      a_l[pt] = *(const bf16x8*)&Al[off];
    }
#pragma unroll
    for (int oct = 0; oct < 16; ++oct) {
      bf16x8 bh = *(const bf16x8*)&Bh[oct * 512 + lane * 8];
      bf16x8 bl = *(const bf16x8*)&Bl[oct * 512 + lane * 8];
#pragma unroll
      for (int pt = 0; pt < 2; ++pt)
        acc[pt][oct] = mfma3(a_h[pt], a_l[pt], bh, bl, acc[pt][oct]);
    }
  }
#pragma unroll
  for (int pt = 0; pt < 2; ++pt)
#pragma unroll
    for (int oct = 0; oct < 16; ++oct) {
      int oc = oct * 16 + ln;
#pragma unroll
      for (int r = 0; r < 4; ++r) {
        int tok = m0 + (2 * w + pt) * 16 + g * 4 + r;
        part[((long)by * 1024 + tok) * 256 + oc] = acc[pt][oct][r];
      }
    }
}

// ---------------- split-K reduce + bias + LN + GELU + fused router ----------------
__global__ __launch_bounds__(256) void k_lnred(const float* __restrict__ part,
    const float* __restrict__ pb, const float* __restrict__ g, const float* __restrict__ be,
    const float* __restrict__ rw, const float* __restrict__ eb,
    u16* __restrict__ hb, float* __restrict__ wts, int* __restrict__ idx,
    float* __restrict__ pm_sum, float* __restrict__ z_sum)
{
  int b = blockIdx.x, d = threadIdx.x;
  float s = pb[d];
#pragma unroll
  for (int ks = 0; ks < 32; ++ks) s += part[((long)ks * 1024 + b) * 256 + d];
  __shared__ float red[4];
  float t = s;
  for (int o = 32; o; o >>= 1) t += __shfl_xor(t, o);
  if ((d & 63) == 0) red[d >> 6] = t;
  __syncthreads();
  float mean = (red[0] + red[1] + red[2] + red[3]) * (1.f / 256.f);
  __syncthreads();
  float dv = s - mean;
  t = dv * dv;
  for (int o = 32; o; o >>= 1) t += __shfl_xor(t, o);
  if ((d & 63) == 0) red[d >> 6] = t;
  __syncthreads();
  float var = (red[0] + red[1] + red[2] + red[3]) * (1.f / 256.f);
  float hv = gelu_f(g[d] * dv * rsqrtf(var + 1e-5f) + be[d]);
  hb[b * 256 + d] = f2bf(hv);
  // fused router (identical fp32 math to the old k_router)
  __shared__ float lws[8][4];
  __shared__ float lgs[8];
  int w = d >> 6;
#pragma unroll
  for (int e = 0; e < 8; ++e) {
    float p = hv * rw[e * 256 + d];
    for (int o = 32; o; o >>= 1) p += __shfl_xor(p, o);
    if ((d & 63) == 0) lws[e][w] = p;
  }
  __syncthreads();
  if (d < 8) lgs[d] = lws[d][0] + lws[d][1] + lws[d][2] + lws[d][3] + eb[d];
  __syncthreads();
  float logit[8];
#pragma unroll
  for (int e = 0; e < 8; ++e) logit[e] = lgs[e];
  float mx = logit[0];
#pragma unroll
  for (int e = 1; e < 8; ++e) mx = fmaxf(mx, logit[e]);
  float pr[8]; float se = 0.f;
#pragma unroll
  for (int e = 0; e < 8; ++e) { pr[e] = expf(logit[e] - mx); se += pr[e]; }
  float inv = 1.f / se;
#pragma unroll
  for (int e = 0; e < 8; ++e) pr[e] *= inv;
  int i0 = 0; float v0 = pr[0];
#pragma unroll
  for (int e = 1; e < 8; ++e) if (pr[e] > v0) { v0 = pr[e]; i0 = e; }
  int i1 = -1; float v1 = -1.f;
#pragma unroll
  for (int e = 0; e < 8; ++e) if (e != i0 && pr[e] > v1) { v1 = pr[e]; i1 = e; }
  if (d == 0) {
    float ssum = v0 + v1 + 1e-8f;
    wts[2 * b] = v0 / ssum; wts[2 * b + 1] = v1 / ssum;
    idx[2 * b] = i0; idx[2 * b + 1] = i1;
    float zz = 0.f;
#pragma unroll
    for (int e = 0; e < 8; ++e) zz += logit[e] * logit[e];
    atomicAdd(z_sum, zz);
  }
  if (d < 8) atomicAdd(&pm_sum[d], pr[d]);
}

// ---------------- generic plain-bf16 MFMA GEMM ----------------
__global__ __launch_bounds__(256, 2) void k_gemmb(const u16* __restrict__ A, long aZ, int K,
    const u16* __restrict__ Bf, int noct_tot,
    const float* __restrict__ bias, int biasZ,
    void* __restrict__ C, long cZ, int ldc, int outbf, int act)
{
  __shared__ __align__(16) u16 As[2048];
  __shared__ __align__(16) u16 Bs[8192];
  int m0 = blockIdx.x * 64, nb = blockIdx.y, z = blockIdx.z, tid = threadIdx.x;
  int w = tid >> 6, lane = tid & 63, g = lane >> 4, ln = lane & 15;
  const u16* Az = A + (long)z * aZ;
  int kn = K >> 5;
  f32x4 z4 = {0.f, 0.f, 0.f, 0.f};
  f32x4 acc[16];
#pragma unroll
  for (int o = 0; o < 16; ++o) acc[o] = z4;
  for (int ks = 0; ks < kn; ++ks) {
    __syncthreads();
    {
      int row = tid >> 2, q = tid & 3;
      ((uint4*)As)[tid] = *((const uint4*)(Az + (long)(m0 + row) * K + ks * 32) + q);
    }
#pragma unroll
    for (int ii = 0; ii < 4; ++ii) {
      int i = tid + ii * 256;
      int oct = i >> 6, r2 = i & 63;
      const u16* src = Bf + (((long)z * noct_tot + nb * 16 + oct) * kn + ks) * 512;
      ((uint4*)Bs)[i] = ((const uint4*)src)[r2];
    }
    __syncthreads();
    bf16x8 a = *(const bf16x8*)&As[(w * 16 + ln) * 32 + g * 8];
#pragma unroll
    for (int oct = 0; oct < 16; ++oct) {
      bf16x8 bb = *(const bf16x8*)&Bs[oct * 512 + lane * 8];
      acc[oct] = __builtin_amdgcn_mfma_f32_16x16x32_bf16(a, bb, acc[oct], 0, 0, 0);
    }
  }
#pragma unroll
  for (int oct = 0; oct < 16; ++oct) {
    int n = nb * 256 + oct * 16 + ln;
    float bv = bias[z * biasZ + n];
#pragma unroll
    for (int r = 0; r < 4; ++r) {
      int tok = m0 + w * 16 + g * 4 + r;
      float v = acc[oct][r] + bv;
      if (act) v = gelu_f(v);
      long off = (long)z * cZ + (long)tok * ldc + n;
      if (outbf) ((u16*)C)[off] = f2bf(v);
      else ((float*)C)[off] = v;
    }
  }
}

// ---------------- combine + 0.5*shared + final LN + fused aux losses ----------------
__global__ __launch_bounds__(256) void k_combine_ln(const float* __restrict__ eout,
    const float* __restrict__ sharedB, const float* __restrict__ wts, const int* __restrict__ idx,
    const float* __restrict__ g, const float* __restrict__ bb,
    const float* __restrict__ pm_sum, const float* __restrict__ z_sum, float* __restrict__ out)
{
  int b = blockIdx.x, d = threadIdx.x;
  float w0 = wts[2 * b], w1 = wts[2 * b + 1];
  int i0 = idx[2 * b], i1 = idx[2 * b + 1];
  float val = w0 * eout[(long)i0 * 262144 + b * 256 + d]
            + w1 * eout[(long)i1 * 262144 + b * 256 + d]
            + 0.5f * sharedB[b * 256 + d];
  __shared__ float red[4];
  float s = val;
  for (int o = 32; o; o >>= 1) s += __shfl_xor(s, o);
  if ((d & 63) == 0) red[d >> 6] = s;
  __syncthreads();
  float mean = (red[0] + red[1] + red[2] + red[3]) * (1.f / 256.f);
  __syncthreads();
  float dv = val - mean;
  s = dv * dv;
  for (int o = 32; o; o >>= 1) s += __shfl_xor(s, o);
  if ((d & 63) == 0) red[d >> 6] = s;
  __syncthreads();
  float var = (red[0] + red[1] + red[2] + red[3]) * (1.f / 256.f);
  out[b * 256 + d] = g[d] * dv * rsqrtf(var + 1e-5f) + bb[d];
  if (b == 0 && d == 0) {
    float lb = 0.f;
    for (int e = 0; e < 8; ++e) {
      float pmv = pm_sum[e] * (1.f / 1024.f);
      float dd = pmv - 0.125f;
      lb += dd * dd;
    }
    out[262144] = lb * 8.f;
    out[262145] = z_sum[0] * (1.f / 8192.f) * 0.001f;
  }
}

extern "C" void kernel_launch(void* const* d_in, const int* in_sizes, int n_in,
                              void* d_out, int out_size, void* d_ws, size_t ws_size,
                              hipStream_t stream)
{
  const float* x     = (const float*)d_in[0];
  const float* c1w   = (const float*)d_in[1];
  const float* c1b   = (const float*)d_in[2];
  const float* bn1g  = (const float*)d_in[3];
  const float* bn1b  = (const float*)d_in[4];
  const float* c2w   = (const float*)d_in[5];
  const float* c2b   = (const float*)d_in[6];
  const float* bn2g  = (const float*)d_in[7];
  const float* bn2b  = (const float*)d_in[8];
  const float* c3w   = (const float*)d_in[9];
  const float* c3b   = (const float*)d_in[10];
  const float* bn3g  = (const float*)d_in[11];
  const float* bn3b  = (const float*)d_in[12];
  const float* projw = (const float*)d_in[13];
  const float* projb = (const float*)d_in[14];
  const float* lng   = (const float*)d_in[15];
  const float* lnb   = (const float*)d_in[16];
  const float* rw    = (const float*)d_in[17];
  const float* ebias = (const float*)d_in[18];
  const float* ew1   = (const float*)d_in[19];
  const float* eb1   = (const float*)d_in[20];
  const float* ew2   = (const float*)d_in[21];
  const float* eb2   = (const float*)d_in[22];
  const float* sw1   = (const float*)d_in[23];
  const float* sb1   = (const float*)d_in[24];
  const float* sw2   = (const float*)d_in[25];
  const float* sb2   = (const float*)d_in[26];
  const float* mlng  = (const float*)d_in[27];
  const float* mlnb  = (const float*)d_in[28];
  float* out = (float*)d_out;

  char* W = (char*)d_ws;
  u32* y1p = (u32*)(W + 0);              // 178,913,280 B
  u32* y2p = (u32*)(W + 178913280L);     // 75,497,472 B
  u32* y3p = (u32*)(W + 0);              // alias dead y1
  u16* wfph = (u16*)(W + 254410752L);
  u16* wfpl = (u16*)(W + 269090816L);
  u16* wf1h = (u16*)(W + 283770880L);
  u16* wf1l = (u16*)(W + 283787264L);
  u16* wf2h = (u16*)(W + 283803648L);
  u16* wf2l = (u16*)(W + 283869184L);
  u16* wf3h = (u16*)(W + 283934720L);
  u16* wf3l = (u16*)(W + 284082176L);
  float* stats = (float*)(W + 284229632L);  // 4096 floats
  float* wtsb  = (float*)(W + 284246016L);
  int*   idxb  = (int*)(W + 284254208L);
  float* shB   = (float*)(W + 286359552L);  // 1 MB
  // expert/shared frag buffers in tail (past shB, <= 292.2MB proven)
  u16* ewf1    = (u16*)(W + 287408128L);    // 2 MB
  u16* ewf2    = (u16*)(W + 289505280L);    // 2 MB
  u16* swf1    = (u16*)(W + 291602432L);    // 128 KB
  u16* swf2    = (u16*)(W + 291733504L);    // 128 KB (ends 291,864,576)
  // post-conv3 aliases inside dead y2p span
  float* part  = (float*)(W + 178913280L);  // 33.5 MB
  u16* hid     = (u16*)(W + 212467712L);    // 8.4 MB
  float* eoutB = (float*)(W + 225312768L);  // 8.4 MB
  u16* hbufb   = (u16*)(W + 233701376L);    // 512 KB
  u16* sh1b    = (u16*)(W + 234225664L);    // 512 KB

  float* sums1 = stats;               // 8 x 64
  float* sums2 = stats + 512;         // 8 x 128
  float* sums3 = stats + 1536;        // 8 x 256
  float* pm    = stats + 4032;  float* zsum  = stats + 4040;

  dim3 blk(256);
  k_prep<<<dim3(9168), blk, 0, stream>>>(c1w, wf1h, wf1l, c2w, wf2h, wf2l,
                                         c3w, wf3h, wf3l, ew1, ewf1, ew2, ewf2,
                                         sw1, swf1, sw2, swf2, stats);
  k_wprepP<<<dim3(32, 16), blk, 0, stream>>>(projw, wfph, wfpl);

  k_conv1m<<<dim3(9, 1024), blk, 0, stream>>>(x, wf1h, wf1l, c1b, y1p, sums1);
  k_conv2m<<<dim3(4, 1024), blk, 0, stream>>>(y1p, wf2h, wf2l, sums1, bn1g, bn1b, c2b, y2p, sums2);
  k_conv3m<<<dim3(2, 1024), blk, 0, stream>>>(y2p, wf3h, wf3l, sums2, bn2g, bn2b, c3b, y3p, sums3);

  k_projm<<<dim3(8, 32), blk, 0, stream>>>(y3p, wfph, wfpl, sums3, bn3g, bn3b, part);
  k_lnred<<<dim3(1024), blk, 0, stream>>>(part, projb, lng, lnb, rw, ebias,
                                          hbufb, wtsb, idxb, pm, zsum);

  k_gemmb<<<dim3(16, 2, 8), blk, 0, stream>>>(hbufb, 0L, 256, ewf1, 32, eb1, 512,
                                              (void*)hid, 524288L, 512, 1, 1);
  k_gemmb<<<dim3(16, 1, 8), blk, 0, stream>>>(hid, 524288L, 512, ewf2, 16, eb2, 256,
                                              (void*)eoutB, 262144L, 256, 0, 0);
  k_gemmb<<<dim3(16, 1, 1), blk, 0, stream>>>(hbufb, 0L, 256, swf1, 16, sb1, 0,
                                              (void*)sh1b, 0L, 256, 1, 1);
  k_gemmb<<<dim3(16, 1, 1), blk, 0, stream>>>(sh1b, 0L, 256, swf2, 16, sb2, 0,
                                              (void*)shB, 0L, 256, 0, 0);

  k_combine_ln<<<dim3(1024), blk, 0, stream>>>(eoutB, shB, wtsb, idxb, mlng, mlnb,
                                               pm, zsum, out);
}